// Round 5
// baseline (1738.202 us; speedup 1.0000x reference)
//
#include <hip/hip_runtime.h>
#include <hip/hip_bf16.h>
#include <cmath>

typedef __hip_bfloat16 bf16;
typedef __attribute__((ext_vector_type(8))) short short8;
typedef __attribute__((ext_vector_type(4))) float f32x4;
typedef unsigned int u32;
typedef __attribute__((address_space(3))) u32 lds_u32;
typedef const __attribute__((address_space(1))) u32 glob_u32;

#define BB 8
#define VV 321
#define SS 24
#define DD 256
#define HH 8
#define GG 10
#define KTOP 33
#define DFFN 1024
#define BV (BB*VV)            // 2568
#define BSEG (BB*SS)          // 192
#define NROWS (BV*SS)         // 61632
#define NE ((size_t)NROWS*DD) // 15777792
#define SCALE 0.17677669529663687f  // 1/sqrt(32)

enum { GF_GELU=1, GF_LOGRELU=2, GF_ABF16=4, GF_RBF16=8, GF_CBF16=16 };
enum { MF_GELU=1, MF_RF32=8, MF_CF32=16, MF_SPLIT=32 };

__device__ __forceinline__ float bf2f(bf16 x){ return __bfloat162float(x); }
__device__ __forceinline__ unsigned short f2bfbits(float f){
  bf16 h = __float2bfloat16(f);
  return *(unsigned short*)&h;
}
__device__ __forceinline__ float bfbits2f(unsigned int u){
  bf16 h; *(unsigned short*)&h = (unsigned short)u; return __bfloat162float(h);
}
__device__ __forceinline__ void ld4bf(const bf16* p, float* f){
  uint2 u = *(const uint2*)p;
  f[0]=bfbits2f(u.x&0xffff); f[1]=bfbits2f(u.x>>16);
  f[2]=bfbits2f(u.y&0xffff); f[3]=bfbits2f(u.y>>16);
}
__device__ __forceinline__ void st4bf(bf16* p, const float* f){
  uint2 u;
  u.x = (unsigned)f2bfbits(f[0]) | ((unsigned)f2bfbits(f[1])<<16);
  u.y = (unsigned)f2bfbits(f[2]) | ((unsigned)f2bfbits(f[3])<<16);
  *(uint2*)p = u;
}
// async 16B global -> LDS (wave-uniform LDS base + lane*16)
__device__ __forceinline__ void gl_lds16(const void* g, void* l){
  __builtin_amdgcn_global_load_lds((glob_u32*)g, (lds_u32*)l, 16, 0, 0);
}
#define SCHEDB() __builtin_amdgcn_sched_barrier(0)

// ---------------------------------------------------------------------------
// Weight prep: fp32 W[K][N] -> bf16 W^T[N][K] into pool. 32x32 tiles via LDS.
// ---------------------------------------------------------------------------
struct WPrep {
  const float* src[12];
  int K[12], N[12], dstoff[12], tileoff[13];
};

__global__ __launch_bounds__(256) void prep_w_k(WPrep p, bf16* __restrict__ pool)
{
  __shared__ float t[32][33];
  int b = blockIdx.x;
  int m = 0;
  while (b >= p.tileoff[m+1]) ++m;
  int tt = b - p.tileoff[m];
  int K = p.K[m], N = p.N[m];
  int nc = N >> 5;
  int tr = tt / nc, tc = tt % nc;
  const float* src = p.src[m];
  int tid = threadIdx.x;
  int r = tid >> 3, c = (tid & 7) * 4;
  float4 v = *(const float4*)&src[(size_t)(tr*32 + r)*N + tc*32 + c];
  t[r][c+0]=v.x; t[r][c+1]=v.y; t[r][c+2]=v.z; t[r][c+3]=v.w;
  __syncthreads();
  bf16* dst = pool + p.dstoff[m];
  size_t base = (size_t)(tc*32 + r)*K + tr*32 + c;
  #pragma unroll
  for (int i=0;i<4;++i) dst[base+i] = __float2bfloat16(t[c+i][r]);
}

// ---------------------------------------------------------------------------
// fp32 -> bf16 bulk convert (8 elems/thread)
// ---------------------------------------------------------------------------
__global__ __launch_bounds__(256) void f2b_k(const float* __restrict__ X, bf16* __restrict__ Y, size_t n)
{
  size_t i = ((size_t)blockIdx.x*256 + threadIdx.x)*8;
  if (i >= n) return;
  float4 a = *(const float4*)(X+i);
  float4 b = *(const float4*)(X+i+4);
  unsigned short v[8] = {f2bfbits(a.x),f2bfbits(a.y),f2bfbits(a.z),f2bfbits(a.w),
                         f2bfbits(b.x),f2bfbits(b.y),f2bfbits(b.z),f2bfbits(b.w)};
  *(uint4*)(Y+i) = *(uint4*)v;
}

// ---------------------------------------------------------------------------
// MFMA GEMM v4 (2-deep pipeline, COUNTED vmcnt): C = act(A@W + bias)(+res)
// A: bf16 [M][K]. Wt: bf16 [N][K] pre-transposed. bias fp32.
// K-loop per iteration (per wave, 4 global_load_lds per tile):
//   issue tile t+1 loads -> s_waitcnt vmcnt(4)  (tile t landed, t+1 IN FLIGHT
//   across the barrier) -> s_barrier -> ds_read+MFMA tile t -> s_barrier.
// Raw s_barrier (not __syncthreads) so the compiler's vmcnt(0) drain is NOT
// emitted; sched_barrier(0) pins issue/waitcnt/barrier order (rule 18).
// Buffer safety: barrier-2 of iter t ensures all waves finished reading
// buf[t&1] before iter t+1 issues tile t+2's writes into it.
// 128x128 tile, BK=32, 256 threads (4 waves), 4x4 16x16x32 MFMAs per wave.
// ---------------------------------------------------------------------------
__global__ __launch_bounds__(256) void mgemm_k(
    const bf16* __restrict__ Ap, const bf16* __restrict__ Wt,
    const float* __restrict__ bias0, const float* __restrict__ bias1,
    const float* __restrict__ bias2, const void* __restrict__ Rp,
    void* __restrict__ Cp, int M, int N, int K, int flags, size_t splitStride)
{
  __shared__ __align__(16) unsigned short As[2][128*32];
  __shared__ __align__(16) unsigned short Bs[2][128*32];
  int tid = threadIdx.x;
  int wave = tid >> 6, lane = tid & 63;
  int quad = lane >> 4, l16 = lane & 15;
  int wr = wave >> 1, wc = wave & 1;
  int m0 = blockIdx.y * 128, n0 = blockIdx.x * 128;

  f32x4 acc[4][4];
  #pragma unroll
  for (int i=0;i<4;++i)
    #pragma unroll
    for (int j=0;j<4;++j) acc[i][j] = (f32x4){0.f,0.f,0.f,0.f};

  // staging coords: wave w covers tile rows 32w..32w+31 (two 1KB chunks)
  int r0 = wave*32 + (lane>>2);            // chunk 0 row
  int r1 = r0 + 16;                        // chunk 1 row
  int kc = (lane&3)*8;                     // k elem offset within tile
  int gm0 = m0 + r0; if (gm0 >= M) gm0 = M-1;
  int gm1 = m0 + r1; if (gm1 >= M) gm1 = M-1;
  const bf16* gA0 = Ap + (size_t)gm0*K + kc;
  const bf16* gA1 = Ap + (size_t)gm1*K + kc;
  const bf16* gB0 = Wt + (size_t)(n0 + r0)*K + kc;
  const bf16* gB1 = Wt + (size_t)(n0 + r1)*K + kc;

  // prologue: issue tile 0 loads
  gl_lds16(gA0, &As[0][wave*1024]);
  gl_lds16(gA1, &As[0][wave*1024 + 512]);
  gl_lds16(gB0, &Bs[0][wave*1024]);
  gl_lds16(gB1, &Bs[0][wave*1024 + 512]);

  const int T = K >> 5;
  int cur = 0;
  for (int t = 0; t < T; ++t) {
    int k0 = t*32;
    if (t + 1 < T) {
      int nxt = cur ^ 1;
      gl_lds16(gA0 + k0 + 32, &As[nxt][wave*1024]);
      gl_lds16(gA1 + k0 + 32, &As[nxt][wave*1024 + 512]);
      gl_lds16(gB0 + k0 + 32, &Bs[nxt][wave*1024]);
      gl_lds16(gB1 + k0 + 32, &Bs[nxt][wave*1024 + 512]);
      SCHEDB();
      asm volatile("s_waitcnt vmcnt(4)" ::: "memory");  // tile t landed; t+1 in flight
    } else {
      SCHEDB();
      asm volatile("s_waitcnt vmcnt(0)" ::: "memory");  // last tile
    }
    SCHEDB();
    __builtin_amdgcn_s_barrier();                       // all waves' tile t landed
    SCHEDB();
    short8 a[4], b[4];
    #pragma unroll
    for (int i=0;i<4;++i)
      a[i] = *(const short8*)&As[cur][(wr*64 + i*16 + l16)*32 + quad*8];
    #pragma unroll
    for (int j=0;j<4;++j)
      b[j] = *(const short8*)&Bs[cur][(wc*64 + j*16 + l16)*32 + quad*8];
    #pragma unroll
    for (int i=0;i<4;++i)
      #pragma unroll
      for (int j=0;j<4;++j)
        acc[i][j] = __builtin_amdgcn_mfma_f32_16x16x32_bf16(a[i], b[j], acc[i][j], 0, 0, 0);
    SCHEDB();
    __builtin_amdgcn_s_barrier();                       // buf[cur] free for reuse
    SCHEDB();
    cur ^= 1;
  }
  SCHEDB();

  // ---- epilogue: D[row=quad*4+r][col=l16] per 16x16 tile ----
  #pragma unroll
  for (int i=0;i<4;++i) {
    int mbase = m0 + wr*64 + i*16 + quad*4;
    #pragma unroll
    for (int j=0;j<4;++j) {
      int n = n0 + wc*64 + j*16 + l16;
      float bv;
      if (flags & MF_SPLIT) {
        int sel = n >> 8;
        const float* bp = (sel==0) ? bias0 : (sel==1 ? bias1 : bias2);
        bv = bp[n & 255];
      } else bv = bias0[n];
      #pragma unroll
      for (int r=0;r<4;++r) {
        int mm = mbase + r;
        if (mm >= M) continue;
        float v = acc[i][j][r] + bv;
        if (flags & MF_GELU) v = 0.5f*v*(1.f + erff(v*0.70710678118654752f));
        if (Rp) {
          size_t ri = (size_t)mm*N + n;
          v += (flags & MF_RF32) ? ((const float*)Rp)[ri] : bf2f(((const bf16*)Rp)[ri]);
        }
        if (flags & MF_SPLIT) {
          size_t ci = (size_t)(n>>8)*splitStride + (size_t)mm*256 + (n & 255);
          ((bf16*)Cp)[ci] = __float2bfloat16(v);
        } else {
          size_t ci = (size_t)mm*N + n;
          if (flags & MF_CF32) ((float*)Cp)[ci] = v;
          else                 ((bf16*)Cp)[ci] = __float2bfloat16(v);
        }
      }
    }
  }
}

// ---------------------------------------------------------------------------
// Old fp32 VALU GEMM — tiny route GEMMs (M<=1920), fp32 in/out.
// ---------------------------------------------------------------------------
__global__ __launch_bounds__(256) void gemm_k(
    const void* __restrict__ Ap, const float* __restrict__ W,
    const float* __restrict__ bias, const void* __restrict__ Rp,
    void* __restrict__ Cp, int M, int N, int K, int flags)
{
  __shared__ float As[16][68];
  __shared__ float Ws[16][68];
  int tid = threadIdx.x;
  int tx = tid & 15, ty = tid >> 4;
  int m0 = blockIdx.y * 64, n0 = blockIdx.x * 64;
  float acc[4][4];
  #pragma unroll
  for (int i=0;i<4;i++)
    #pragma unroll
    for (int j=0;j<4;j++) acc[i][j]=0.f;

  for (int k0 = 0; k0 < K; k0 += 16) {
    #pragma unroll
    for (int i = 0; i < 4; ++i) {
      int idx = tid + i*256;
      int r = idx >> 4, c = idx & 15;
      int gr = m0 + r;
      float v = 0.f;
      if (gr < M) {
        size_t gi = (size_t)gr*K + (size_t)(k0 + c);
        v = (flags & GF_ABF16) ? bf2f(((const bf16*)Ap)[gi]) : ((const float*)Ap)[gi];
        if (flags & GF_LOGRELU) v = log1pf(fmaxf(v, 0.f));
      }
      As[c][r] = v;
    }
    #pragma unroll
    for (int i = 0; i < 4; ++i) {
      int idx = tid + i*256;
      int c = idx >> 6, j = idx & 63;
      Ws[c][j] = W[(size_t)(k0+c)*N + (size_t)(n0 + j)];
    }
    __syncthreads();
    #pragma unroll
    for (int k = 0; k < 16; ++k) {
      float a[4], b[4];
      #pragma unroll
      for (int i=0;i<4;i++) a[i] = As[k][ty*4+i];
      #pragma unroll
      for (int j=0;j<4;j++) b[j] = Ws[k][tx*4+j];
      #pragma unroll
      for (int i=0;i<4;i++)
        #pragma unroll
        for (int j=0;j<4;j++) acc[i][j] = fmaf(a[i], b[j], acc[i][j]);
    }
    __syncthreads();
  }
  #pragma unroll
  for (int i=0;i<4;i++) {
    int row = m0 + ty*4 + i;
    if (row >= M) continue;
    #pragma unroll
    for (int j=0;j<4;j++) {
      int col = n0 + tx*4 + j;
      float v = acc[i][j] + bias[col];
      if (flags & GF_GELU) v = 0.5f*v*(1.f + erff(v*0.70710678118654752f));
      if (Rp) {
        size_t ri = (size_t)row*N + col;
        v += (flags & GF_RBF16) ? bf2f(((const bf16*)Rp)[ri]) : ((const float*)Rp)[ri];
      }
      size_t ci = (size_t)row*N + col;
      if (flags & GF_CBF16) ((bf16*)Cp)[ci] = __float2bfloat16(v);
      else                  ((float*)Cp)[ci] = v;
    }
  }
}

// ---------------------------------------------------------------------------
// Temporal attention via MFMA. 4 waves/block, wave w owns pair p=bid*4+w
// (p = bv*8 + h). S=24 padded to 32, DH=32. In-place on Q.
// ---------------------------------------------------------------------------
__global__ __launch_bounds__(256) void attn1_k(bf16* __restrict__ Q,
                                               const bf16* __restrict__ Kb,
                                               const bf16* __restrict__ Vb)
{
  __shared__ __align__(16) unsigned short lds[4*4096];  // 32 KB
  int wave = threadIdx.x >> 6, lane = threadIdx.x & 63;
  int quad = lane >> 4, l16 = lane & 15;
  int p = blockIdx.x*4 + wave;          // bv*8 + h
  int bv = p >> 3, h = p & 7;
  const size_t base0 = ((size_t)bv*SS)*DD + h*32;

  int slab = wave*4096;
  int lQ = slab, lK = slab + 1024, lV = slab + 2048, lP = slab + 3072;

  // ---- stage Q,K,V (24 rows x 32 bf16 each) via global_load_lds w16 ----
  {
    int row0 = lane >> 2, c0 = (lane & 3)*8;          // it0: u = lane
    const bf16* gq = Q  + base0 + (size_t)row0*DD + c0;
    const bf16* gk = Kb + base0 + (size_t)row0*DD + c0;
    const bf16* gv = Vb + base0 + (size_t)row0*DD + c0;
    gl_lds16(gq, &lds[lQ]);
    gl_lds16(gk, &lds[lK]);
    gl_lds16(gv, &lds[lV]);
    if (lane < 32) {                                   // it1: u = 64+lane
      int row1 = 16 + (lane >> 2);
      const bf16* gq1 = Q  + base0 + (size_t)row1*DD + c0;
      const bf16* gk1 = Kb + base0 + (size_t)row1*DD + c0;
      const bf16* gv1 = Vb + base0 + (size_t)row1*DD + c0;
      gl_lds16(gq1, &lds[lQ + 512]);
      gl_lds16(gk1, &lds[lK + 512]);
      gl_lds16(gv1, &lds[lV + 512]);
    }
  }
  // zero V pad rows 24..31 (k-dim of PV MFMA must not contain NaN garbage)
  *(uint2*)&lds[lV + 768 + lane*4] = (uint2){0u,0u};

  asm volatile("s_waitcnt vmcnt(0)" ::: "memory");
  __builtin_amdgcn_sched_barrier(0);

  // ---- QK^T: 2x2 tiles of 16, K=32 ----
  short8 qa[2], kb[2];
  #pragma unroll
  for (int t=0;t<2;++t) {
    qa[t] = *(const short8*)&lds[lQ + (t*16 + l16)*32 + quad*8];
    kb[t] = *(const short8*)&lds[lK + (t*16 + l16)*32 + quad*8];
  }
  f32x4 scc[2][2];
  #pragma unroll
  for (int ti=0;ti<2;++ti)
    #pragma unroll
    for (int tj=0;tj<2;++tj)
      scc[ti][tj] = __builtin_amdgcn_mfma_f32_16x16x32_bf16(qa[ti], kb[tj],
                      (f32x4){0.f,0.f,0.f,0.f}, 0, 0, 0);
  // mask pad cols j=24..31 (tile tj=1, l16>=8) to -inf
  if (l16 >= 8) {
    scc[0][1] = (f32x4){-INFINITY,-INFINITY,-INFINITY,-INFINITY};
    scc[1][1] = (f32x4){-INFINITY,-INFINITY,-INFINITY,-INFINITY};
  }

  // ---- softmax over cols (row = quad*4+r+16*ti, cols across l16 x tj) ----
  #pragma unroll
  for (int ti=0;ti<2;++ti) {
    #pragma unroll
    for (int r=0;r<4;++r) {
      float mv = fmaxf(scc[ti][0][r], scc[ti][1][r]);
      #pragma unroll
      for (int off=1; off<16; off<<=1) mv = fmaxf(mv, __shfl_xor(mv, off));
      float e0 = expf((scc[ti][0][r]-mv)*SCALE);
      float e1 = expf((scc[ti][1][r]-mv)*SCALE);   // exp(-inf)=0 for pad cols
      float sm = e0 + e1;
      #pragma unroll
      for (int off=1; off<16; off<<=1) sm += __shfl_xor(sm, off);
      float inv = 1.f/sm;
      int row = ti*16 + quad*4 + r;
      lds[lP + row*32 + l16]      = f2bfbits(e0*inv);
      lds[lP + row*32 + 16 + l16] = f2bfbits(e1*inv);
    }
  }

  // ---- PV: O[24x32] = P[24x32pad] x V[32x32], 2x2 tiles ----
  f32x4 o[2][2];
  #pragma unroll
  for (int ti=0;ti<2;++ti) {
    short8 pa = *(const short8*)&lds[lP + (ti*16 + l16)*32 + quad*8];
    #pragma unroll
    for (int tn=0;tn<2;++tn) {
      unsigned short vt[8];
      #pragma unroll
      for (int e=0;e<8;++e) vt[e] = lds[lV + (quad*8+e)*32 + tn*16 + l16];
      short8 vb = *(short8*)vt;
      o[ti][tn] = __builtin_amdgcn_mfma_f32_16x16x32_bf16(pa, vb,
                    (f32x4){0.f,0.f,0.f,0.f}, 0, 0, 0);
    }
  }

  // ---- store (rows < 24 only), col = tn*16+l16 ----
  #pragma unroll
  for (int ti=0;ti<2;++ti) {
    #pragma unroll
    for (int r=0;r<4;++r) {
      int row = ti*16 + quad*4 + r;
      if (row < SS) {
        #pragma unroll
        for (int tn=0;tn<2;++tn)
          Q[base0 + (size_t)row*DD + tn*16 + l16] = __float2bfloat16(o[ti][tn][r]);
      }
    }
  }
}

// ---------------------------------------------------------------------------
// LayerNorm family
// ---------------------------------------------------------------------------
__global__ __launch_bounds__(256) void ln_k(const bf16* __restrict__ X, bf16* __restrict__ Y,
                                            const float* __restrict__ g, const float* __restrict__ b,
                                            int nrows)
{
  int row = blockIdx.x*4 + (threadIdx.x >> 6);
  int lane = threadIdx.x & 63;
  if (row >= nrows) return;
  const bf16* xr = X + (size_t)row*DD;
  int c = lane*4;
  float v0 = bf2f(xr[c+0]), v1 = bf2f(xr[c+1]), v2 = bf2f(xr[c+2]), v3 = bf2f(xr[c+3]);
  float s = v0+v1+v2+v3;
  #pragma unroll
  for (int off = 32; off; off >>= 1) s += __shfl_xor(s, off);
  float m = s * (1.f/256.f);
  float d0=v0-m, d1=v1-m, d2=v2-m, d3=v3-m;
  float q = d0*d0+d1*d1+d2*d2+d3*d3;
  #pragma unroll
  for (int off = 32; off; off >>= 1) q += __shfl_xor(q, off);
  float rstd = rsqrtf(q*(1.f/256.f) + 1e-5f);
  bf16* yr = Y + (size_t)row*DD;
  yr[c+0] = __float2bfloat16(d0*rstd*g[c+0] + b[c+0]);
  yr[c+1] = __float2bfloat16(d1*rstd*g[c+1] + b[c+1]);
  yr[c+2] = __float2bfloat16(d2*rstd*g[c+2] + b[c+2]);
  yr[c+3] = __float2bfloat16(d3*rstd*g[c+3] + b[c+3]);
}

// LN fused with (B,V,S,D)->(B,S,V,D) permute; also emits xl = log1p(relu(xd))
__global__ __launch_bounds__(256) void ln_t_k(const bf16* __restrict__ X, bf16* __restrict__ Y,
                                              bf16* __restrict__ Yl,
                                              const float* __restrict__ g, const float* __restrict__ b)
{
  int r1 = blockIdx.x*4 + (threadIdx.x >> 6);
  int lane = threadIdx.x & 63;
  if (r1 >= NROWS) return;
  const bf16* xr = X + (size_t)r1*DD;
  int c = lane*4;
  float v0 = bf2f(xr[c+0]), v1 = bf2f(xr[c+1]), v2 = bf2f(xr[c+2]), v3 = bf2f(xr[c+3]);
  float s = v0+v1+v2+v3;
  #pragma unroll
  for (int off = 32; off; off >>= 1) s += __shfl_xor(s, off);
  float m = s * (1.f/256.f);
  float d0=v0-m, d1=v1-m, d2=v2-m, d3=v3-m;
  float q = d0*d0+d1*d1+d2*d2+d3*d3;
  #pragma unroll
  for (int off = 32; off; off >>= 1) q += __shfl_xor(q, off);
  float rstd = rsqrtf(q*(1.f/256.f) + 1e-5f);
  int b_ = r1 / (VV*SS);
  int rem = r1 % (VV*SS);
  int v = rem / SS, ss = rem % SS;
  int r2 = (b_*SS + ss)*VV + v;
  float o0 = d0*rstd*g[c+0] + b[c+0];
  float o1 = d1*rstd*g[c+1] + b[c+1];
  float o2 = d2*rstd*g[c+2] + b[c+2];
  float o3 = d3*rstd*g[c+3] + b[c+3];
  bf16* yr = Y + (size_t)r2*DD;
  yr[c+0] = __float2bfloat16(o0);
  yr[c+1] = __float2bfloat16(o1);
  yr[c+2] = __float2bfloat16(o2);
  yr[c+3] = __float2bfloat16(o3);
  bf16* ylr = Yl + (size_t)r2*DD;
  ylr[c+0] = __float2bfloat16(log1pf(fmaxf(o0, 0.f)));
  ylr[c+1] = __float2bfloat16(log1pf(fmaxf(o1, 0.f)));
  ylr[c+2] = __float2bfloat16(log1pf(fmaxf(o2, 0.f)));
  ylr[c+3] = __float2bfloat16(log1pf(fmaxf(o3, 0.f)));
}

// Final LN + permute (B,S,V,D)->(B,V,S,D) + fp32 store
__global__ __launch_bounds__(256) void ln_out_k(const bf16* __restrict__ X, float* __restrict__ out,
                                                const float* __restrict__ g, const float* __restrict__ b)
{
  int row = blockIdx.x*4 + (threadIdx.x >> 6);
  int lane = threadIdx.x & 63;
  if (row >= NROWS) return;
  const bf16* xr = X + (size_t)row*DD;
  int c = lane*4;
  float v0 = bf2f(xr[c+0]), v1 = bf2f(xr[c+1]), v2 = bf2f(xr[c+2]), v3 = bf2f(xr[c+3]);
  float s = v0+v1+v2+v3;
  #pragma unroll
  for (int off = 32; off; off >>= 1) s += __shfl_xor(s, off);
  float m = s * (1.f/256.f);
  float d0=v0-m, d1=v1-m, d2=v2-m, d3=v3-m;
  float q = d0*d0+d1*d1+d2*d2+d3*d3;
  #pragma unroll
  for (int off = 32; off; off >>= 1) q += __shfl_xor(q, off);
  float rstd = rsqrtf(q*(1.f/256.f) + 1e-5f);
  int bs = row / VV, vv = row % VV;
  int bb = bs / SS, ss = bs % SS;
  float* op = out + (((size_t)bb*VV + vv)*SS + ss)*DD + c;
  op[0] = d0*rstd*g[c+0] + b[c+0];
  op[1] = d1*rstd*g[c+1] + b[c+1];
  op[2] = d2*rstd*g[c+2] + b[c+2];
  op[3] = d3*rstd*g[c+3] + b[c+3];
}

// ---------------------------------------------------------------------------
// Scores + top-33 (desc, ties -> lower index). One wave per (bs,h,g).
// ---------------------------------------------------------------------------
__global__ __launch_bounds__(64) void topk_k(const float* __restrict__ qS,
                                             const bf16* __restrict__ kS,
                                             int* __restrict__ idxOut)
{
  int bid = blockIdx.x;                // (bs*8+h)*10+g
  int g = bid % GG;
  int h = (bid / GG) % HH;
  int bs = bid / (GG*HH);
  int s = bs % SS;
  int lane = threadIdx.x;

  float qv[32];
  const float4* qp = (const float4*)(qS + ((size_t)(s*GG + g))*DD + h*32);
  #pragma unroll
  for (int e4 = 0; e4 < 8; ++e4) {
    float4 t = qp[e4];
    qv[e4*4+0]=t.x; qv[e4*4+1]=t.y; qv[e4*4+2]=t.z; qv[e4*4+3]=t.w;
  }

  float sc[6];
  #pragma unroll
  for (int j = 0; j < 6; ++j) {
    int v = lane + j*64;
    if (v < VV) {
      const uint4* kp = (const uint4*)(kS + ((size_t)bs*VV + v)*DD + h*32);
      float d = 0.f;
      #pragma unroll
      for (int cch = 0; cch < 4; ++cch) {
        uint4 u = kp[cch];
        const unsigned short* usp = (const unsigned short*)&u;
        #pragma unroll
        for (int e = 0; e < 8; ++e)
          d = fmaf(bfbits2f(usp[e]), qv[cch*8+e], d);
      }
      sc[j] = d * SCALE;
    } else sc[j] = -INFINITY;
  }

  for (int it = 0; it < KTOP; ++it) {
    float bv = sc[0]; int bj = 0;
    #pragma unroll
    for (int j = 1; j < 6; ++j) if (sc[j] > bv) { bv = sc[j]; bj = j; }
    int bi = lane + bj*64;
    #pragma unroll
    for (int off = 32; off; off >>= 1) {
      float ov = __shfl_down(bv, off);
      int   oi = __shfl_down(bi, off);
      if (ov > bv || (ov == bv && oi < bi)) { bv = ov; bi = oi; }
    }
    bi = __shfl(bi, 0);
    if (lane == 0) idxOut[(size_t)bid*KTOP + it] = bi;
    if ((bi & 63) == lane) {
      int jj = bi >> 6;
      #pragma unroll
      for (int j = 0; j < 6; ++j) if (jj == j) sc[j] = -INFINITY;
    }
  }
}

// ---------------------------------------------------------------------------
// Grouped conv + min/max/exp -> feat (bs,G,256) fp32
// ---------------------------------------------------------------------------
__global__ __launch_bounds__(256) void conv_k(const bf16* __restrict__ vS,
                                              const int* __restrict__ idx,
                                              const float* __restrict__ cw,
                                              const float* __restrict__ cb,
                                              float* __restrict__ feat)
{
  int bid = blockIdx.x;
  int bs = bid / GG, g = bid % GG;
  int tid = threadIdx.x;
  int h = tid >> 5, d = tid & 31;
  __shared__ float cws[KTOP];
  __shared__ int idl[HH][KTOP];
  __shared__ float ms[256];
  if (tid < KTOP) cws[tid] = cw[g*KTOP + tid];
  for (int i = tid; i < HH*KTOP; i += 256) {
    int hh = i / KTOP, k = i % KTOP;
    int ix = idx[(((size_t)bs*HH + hh)*GG + g)*KTOP + k];
    idl[hh][k] = (ix < 0) ? 0 : (ix >= VV ? VV-1 : ix);
  }
  __syncthreads();
  float acc = 0.f;
  #pragma unroll
  for (int k = 0; k < KTOP; ++k)
    acc += bf2f(vS[((size_t)bs*VV + idl[h][k])*DD + h*32 + d]) * cws[k];
  acc += cb[g];
  ms[tid] = acc;
  __syncthreads();
  float mn = acc, mx = acc;
  #pragma unroll
  for (int j = 0; j < 32; ++j) {
    float t = ms[h*32 + j];
    mn = fminf(mn, t); mx = fmaxf(mx, t);
  }
  float xn = expf((acc - mn) / fmaxf(mx - mn, 1e-6f));
  feat[((size_t)bs*GG + g)*DD + h*32 + d] = xn;
}

// ---------------------------------------------------------------------------
// Cross attention (route 2): 321 bf16 queries vs 10 fp32 keys per bs.
// ---------------------------------------------------------------------------
__global__ __launch_bounds__(256) void attn2_k(bf16* __restrict__ Q,
                                               const float* __restrict__ KR,
                                               const float* __restrict__ VR)
{
  int bs = blockIdx.x;
  int tid = threadIdx.x;
  __shared__ float kr[GG][DD], vr[GG][DD];
  for (int i = tid; i < GG*DD; i += 256) {
    int r = i >> 8, c = i & 255;
    kr[r][c] = KR[((size_t)bs*GG + r)*DD + c];
    vr[r][c] = VR[((size_t)bs*GG + r)*DD + c];
  }
  __syncthreads();
  for (int task = tid; task < VV*HH; task += 256) {
    int v = task >> 3, h = task & 7;
    bf16* qp = Q + ((size_t)bs*VV + v)*DD + h*32;
    float qr[32];
    #pragma unroll
    for (int d = 0; d < 32; ++d) qr[d] = bf2f(qp[d]);
    float sv[GG];
    float mx = -INFINITY;
    #pragma unroll
    for (int gi = 0; gi < GG; ++gi) {
      float dsum = 0.f;
      #pragma unroll
      for (int d = 0; d < 32; ++d) dsum += qr[d]*kr[gi][h*32+d];
      sv[gi] = dsum * SCALE;
      mx = fmaxf(mx, sv[gi]);
    }
    float ssum = 0.f;
    #pragma unroll
    for (int gi = 0; gi < GG; ++gi) { sv[gi] = expf(sv[gi]-mx); ssum += sv[gi]; }
    float inv = 1.f/ssum;
    float o[32];
    #pragma unroll
    for (int d = 0; d < 32; ++d) o[d] = 0.f;
    #pragma unroll
    for (int gi = 0; gi < GG; ++gi) {
      float p = sv[gi]*inv;
      #pragma unroll
      for (int d = 0; d < 32; ++d) o[d] += p*vr[gi][h*32+d];
    }
    #pragma unroll
    for (int d = 0; d < 32; ++d) qp[d] = __float2bfloat16(o[d]);
  }
}

// ---------------------------------------------------------------------------
extern "C" void kernel_launch(void* const* d_in, const int* in_sizes, int n_in,
                              void* d_out, int out_size, void* d_ws, size_t ws_size,
                              hipStream_t stream)
{
  const float* queries=(const float*)d_in[0];
  const float* t_wq=(const float*)d_in[1];  const float* t_bq=(const float*)d_in[2];
  const float* t_wk=(const float*)d_in[3];  const float* t_bk=(const float*)d_in[4];
  const float* t_wv=(const float*)d_in[5];  const float* t_bv=(const float*)d_in[6];
  const float* t_wo=(const float*)d_in[7];  const float* t_bo=(const float*)d_in[8];
  const float* s_wq=(const float*)d_in[9];  const float* s_bq=(const float*)d_in[10];
  const float* s_wk=(const float*)d_in[11]; const float* s_bk=(const float*)d_in[12];
  const float* s_wv=(const float*)d_in[13]; const float* s_bv=(const float*)d_in[14];
  const float* s_wo=(const float*)d_in[15]; const float* s_bo=(const float*)d_in[16];
  const float* cluster=(const float*)d_in[17];
  const float* conv_w=(const float*)d_in[18]; const float* conv_b=(const float*)d_in[19];
  const float* r_wq=(const float*)d_in[20]; const float* r_bq=(const float*)d_in[21];
  const float* r_wk=(const float*)d_in[22]; const float* r_bk=(const float*)d_in[23];
  const float* r_wv=(const float*)d_in[24]; const float* r_bv=(const float*)d_in[25];
  const float* r_wo=(const float*)d_in[26]; const float* r_bo=(const float*)d_in[27];
  const float* ln_t1_g=(const float*)d_in[28]; const float* ln_t1_b=(const float*)d_in[29];
  const float* ln_t2_g=(const float*)d_in[30]; const float* ln_t2_b=(const float*)d_in[31];
  const float* ln_d1_g=(const float*)d_in[32]; const float* ln_d1_b=(const float*)d_in[33];
  const float* ln_d2_g=(const float*)d_in[34]; const float* ln_d2_b=(const float*)d_in[35];
  const float* ft_w1=(const float*)d_in[36]; const float* ft_b1=(const float*)d_in[37];
  const float* ft_w2=(const float*)d_in[38]; const float* ft_b2=(const float*)d_in[39];
  const float* fd_w1=(const float*)d_in[40]; const float* fd_b1=(const float*)d_in[41];
  const float* fd_w2=(const float*)d_in[42]; const float* fd_b2=(const float*)d_in[43];

  // Workspace: 4 big bf16 buffers (126 MB) + W^T pool (3 MB) + smalls (~10 MB)
  bf16* Ab = (bf16*)d_ws;
  bf16* Bb = Ab + NE;
  bf16* Cb = Bb + NE;
  bf16* Db = Cb + NE;                       // queries-bf16 (route1) / xl (route2)
  bf16* WP = Db + NE;                       // 1572864 bf16
  float* QSf   = (float*)(WP + 1572864);
  float* FEATf = QSf + 240*256;
  float* ROUTEf= FEATf + 1920*256;
  float* KRf   = ROUTEf + 1920*256;
  float* VRf   = KRf + 1920*256;
  int*   IDXb  = (int*)(VRf + 1920*256);

  // ---- weight prep ----
  WPrep wp;
  const float* wsrc[12] = {t_wq,t_wk,t_wv,t_wo,s_wk,s_wv,r_wq,r_wo,ft_w1,ft_w2,fd_w1,fd_w2};
  int wK[12] = {256,256,256,256,256,256,256,256,256,1024,256,1024};
  int wN[12] = {256,256,256,256,256,256,256,256,1024,256,1024,256};
  int off = 0, toff = 0;
  for (int i=0;i<12;++i) {
    wp.src[i]=wsrc[i]; wp.K[i]=wK[i]; wp.N[i]=wN[i];
    wp.dstoff[i]=off; wp.tileoff[i]=toff;
    off += wK[i]*wN[i];
    toff += (wK[i]/32)*(wN[i]/32);
  }
  wp.tileoff[12]=toff;
  prep_w_k<<<toff, 256, 0, stream>>>(wp, WP);
  bf16* Wqkv=WP+wp.dstoff[0];               // [768][256]
  bf16* Wo=WP+wp.dstoff[3];
  bf16* Wskv=WP+wp.dstoff[4];               // [512][256]
  bf16* Wrq=WP+wp.dstoff[6]; bf16* Wro=WP+wp.dstoff[7];
  bf16* Wf1=WP+wp.dstoff[8]; bf16* Wf2=WP+wp.dstoff[9];
  bf16* Wd1=WP+wp.dstoff[10]; bf16* Wd2=WP+wp.dstoff[11];

  dim3 blk(256);
  const int STRIPE = NROWS/4;               // 15408
  dim3 gQKV(6, (NROWS+127)/128);
  dim3 gKV(4, (NROWS+127)/128);
  dim3 gBig(2, (NROWS+127)/128);
  dim3 gS1(8, (STRIPE+127)/128);
  dim3 gS2(2, (STRIPE+127)/128);
  dim3 gQ(4, 4);
  dim3 gSmall(4, 30);
  const int GCVT = (int)(NE/2048);          // 7704

  // ---- Route 1: temporal ----
  f2b_k<<<GCVT, blk, 0, stream>>>(queries, Db, NE);
  mgemm_k<<<gQKV, blk, 0, stream>>>(Db, Wqkv, t_bq, t_bk, t_bv, nullptr, Ab,
                                    NROWS, 768, 256, MF_SPLIT, NE);           // Q->Ab K->Bb V->Cb
  attn1_k<<<(BV*HH)/4, blk, 0, stream>>>(Ab, Bb, Cb);                         // O -> Ab
  mgemm_k<<<gBig, blk, 0, stream>>>(Ab, Wo, t_bo, nullptr, nullptr, queries, Bb,
                                    NROWS, 256, 256, MF_RF32, 0);
  ln_k<<<NROWS/4, blk, 0, stream>>>(Bb, Ab, ln_t1_g, ln_t1_b, NROWS);
  for (int st = 0; st < 4; ++st) {
    size_t ro = (size_t)st * STRIPE * DD;
    mgemm_k<<<gS1, blk, 0, stream>>>(Ab + ro, Wf1, ft_b1, nullptr, nullptr, nullptr, Cb,
                                     STRIPE, 1024, 256, MF_GELU, 0);
    mgemm_k<<<gS2, blk, 0, stream>>>(Cb, Wf2, ft_b2, nullptr, nullptr, Ab + ro, Bb + ro,
                                     STRIPE, 256, 1024, 0, 0);
  }
  ln_t_k<<<NROWS/4, blk, 0, stream>>>(Bb, Ab, Db, ln_t2_g, ln_t2_b);          // xd -> Ab, xl -> Db

  // ---- Route 2: dimensional ----
  mgemm_k<<<gKV, blk, 0, stream>>>(Db, Wskv, s_bk, s_bv, nullptr, nullptr, Bb,
                                   NROWS, 512, 256, MF_SPLIT, NE);            // kS->Bb vS->Cb
  gemm_k<<<gQ, blk, 0, stream>>>(cluster, s_wq, s_bq, nullptr, QSf, 240, 256, 256, 0);
  topk_k<<<BSEG*HH*GG, 64, 0, stream>>>(QSf, Bb, IDXb);
  conv_k<<<BSEG*GG, blk, 0, stream>>>(Cb, IDXb, conv_w, conv_b, FEATf);
  gemm_k<<<gSmall, blk, 0, stream>>>(FEATf, s_wo, s_bo, nullptr, ROUTEf, 1920, 256, 256, 0);
  gemm_k<<<gSmall, blk, 0, stream>>>(ROUTEf, r_wk, r_bk, nullptr, KRf, 1920, 256, 256, 0);
  gemm_k<<<gSmall, blk, 0, stream>>>(ROUTEf, r_wv, r_bv, nullptr, VRf, 1920, 256, 256, 0);
  mgemm_k<<<gBig, blk, 0, stream>>>(Ab, Wrq, r_bq, nullptr, nullptr, nullptr, Bb,
                                    NROWS, 256, 256, 0, 0);                   // qD -> Bb
  attn2_k<<<BSEG, blk, 0, stream>>>(Bb, KRf, VRf);                            // O -> Bb
  mgemm_k<<<gBig, blk, 0, stream>>>(Bb, Wro, r_bo, nullptr, nullptr, Ab, Cb,
                                    NROWS, 256, 256, 0, 0);                   // + xd -> Cb
  ln_k<<<NROWS/4, blk, 0, stream>>>(Cb, Ab, ln_d1_g, ln_d1_b, NROWS);
  for (int st = 0; st < 4; ++st) {
    size_t ro = (size_t)st * STRIPE * DD;
    mgemm_k<<<gS1, blk, 0, stream>>>(Ab + ro, Wd1, fd_b1, nullptr, nullptr, nullptr, Bb,
                                     STRIPE, 1024, 256, MF_GELU, 0);
    mgemm_k<<<gS2, blk, 0, stream>>>(Bb, Wd2, fd_b2, nullptr, nullptr, Ab + ro, Cb + ro,
                                     STRIPE, 256, 1024, 0, 0);
  }
  ln_out_k<<<NROWS/4, blk, 0, stream>>>(Cb, (float*)d_out, ln_d2_g, ln_d2_b);
}

// Round 7
// 1735.392 us; speedup vs baseline: 1.0016x; 1.0016x over previous
//
#include <hip/hip_runtime.h>
#include <hip/hip_bf16.h>
#include <cmath>

typedef __hip_bfloat16 bf16;
typedef __attribute__((ext_vector_type(8))) short short8;
typedef __attribute__((ext_vector_type(4))) float f32x4;
typedef unsigned int u32;
typedef __attribute__((address_space(3))) u32 lds_u32;
typedef const __attribute__((address_space(1))) u32 glob_u32;

#define BB 8
#define VV 321
#define SS 24
#define DD 256
#define HH 8
#define GG 10
#define KTOP 33
#define DFFN 1024
#define BV (BB*VV)            // 2568
#define BSEG (BB*SS)          // 192
#define NROWS (BV*SS)         // 61632
#define NE ((size_t)NROWS*DD) // 15777792
#define SCALE 0.17677669529663687f  // 1/sqrt(32)

enum { GF_GELU=1, GF_LOGRELU=2, GF_ABF16=4, GF_RBF16=8, GF_CBF16=16 };
enum { MF_GELU=1, MF_RF32=8, MF_CF32=16, MF_SPLIT=32 };

__device__ __forceinline__ float bf2f(bf16 x){ return __bfloat162float(x); }
__device__ __forceinline__ unsigned short f2bfbits(float f){
  bf16 h = __float2bfloat16(f);
  return *(unsigned short*)&h;
}
__device__ __forceinline__ float bfbits2f(unsigned int u){
  bf16 h; *(unsigned short*)&h = (unsigned short)u; return __bfloat162float(h);
}
__device__ __forceinline__ void ld4bf(const bf16* p, float* f){
  uint2 u = *(const uint2*)p;
  f[0]=bfbits2f(u.x&0xffff); f[1]=bfbits2f(u.x>>16);
  f[2]=bfbits2f(u.y&0xffff); f[3]=bfbits2f(u.y>>16);
}
__device__ __forceinline__ void st4bf(bf16* p, const float* f){
  uint2 u;
  u.x = (unsigned)f2bfbits(f[0]) | ((unsigned)f2bfbits(f[1])<<16);
  u.y = (unsigned)f2bfbits(f[2]) | ((unsigned)f2bfbits(f[3])<<16);
  *(uint2*)p = u;
}
// async 16B global -> LDS (wave-uniform LDS base + lane*16)
__device__ __forceinline__ void gl_lds16(const void* g, void* l){
  __builtin_amdgcn_global_load_lds((glob_u32*)g, (lds_u32*)l, 16, 0, 0);
}

// ---------------------------------------------------------------------------
// Weight prep: fp32 W[K][N] -> bf16 W^T[N][K] into pool. 32x32 tiles via LDS.
// ---------------------------------------------------------------------------
struct WPrep {
  const float* src[12];
  int K[12], N[12], dstoff[12], tileoff[13];
};

__global__ __launch_bounds__(256) void prep_w_k(WPrep p, bf16* __restrict__ pool)
{
  __shared__ float t[32][33];
  int b = blockIdx.x;
  int m = 0;
  while (b >= p.tileoff[m+1]) ++m;
  int tt = b - p.tileoff[m];
  int K = p.K[m], N = p.N[m];
  int nc = N >> 5;
  int tr = tt / nc, tc = tt % nc;
  const float* src = p.src[m];
  int tid = threadIdx.x;
  int r = tid >> 3, c = (tid & 7) * 4;
  float4 v = *(const float4*)&src[(size_t)(tr*32 + r)*N + tc*32 + c];
  t[r][c+0]=v.x; t[r][c+1]=v.y; t[r][c+2]=v.z; t[r][c+3]=v.w;
  __syncthreads();
  bf16* dst = pool + p.dstoff[m];
  size_t base = (size_t)(tc*32 + r)*K + tr*32 + c;
  #pragma unroll
  for (int i=0;i<4;++i) dst[base+i] = __float2bfloat16(t[c+i][r]);
}

// ---------------------------------------------------------------------------
// fp32 -> bf16 bulk convert (8 elems/thread)
// ---------------------------------------------------------------------------
__global__ __launch_bounds__(256) void f2b_k(const float* __restrict__ X, bf16* __restrict__ Y, size_t n)
{
  size_t i = ((size_t)blockIdx.x*256 + threadIdx.x)*8;
  if (i >= n) return;
  float4 a = *(const float4*)(X+i);
  float4 b = *(const float4*)(X+i+4);
  unsigned short v[8] = {f2bfbits(a.x),f2bfbits(a.y),f2bfbits(a.z),f2bfbits(a.w),
                         f2bfbits(b.x),f2bfbits(b.y),f2bfbits(b.z),f2bfbits(b.w)};
  *(uint4*)(Y+i) = *(uint4*)v;
}

// ---------------------------------------------------------------------------
// MFMA GEMM v5b: BK=64 (two 32-wide subtiles/step) + XCD-bijective swizzle,
// on the proven __syncthreads double-buffer skeleton (round-4 structure).
// Per K-step: issue next tile's 8 DMA loads into buf^1, compute current tile
// (16 ds_read + 32 MFMA), one __syncthreads (drains vmcnt; barrier).
// Halves barrier pairs vs BK=32. Subtile slabs keep 64B row stride.
// XCD swizzle (m204 bijective): consecutive linear ids (x-fast, same A-panel)
// land on one XCD's L2 -> A re-reads become L2 hits.
// K multiple of 64; M fringe: DMA row clamped, store guarded.
// ---------------------------------------------------------------------------
__global__ __launch_bounds__(256) void mgemm_k(
    const bf16* __restrict__ Ap, const bf16* __restrict__ Wt,
    const float* __restrict__ bias0, const float* __restrict__ bias1,
    const float* __restrict__ bias2, const void* __restrict__ Rp,
    void* __restrict__ Cp, int M, int N, int K, int flags, size_t splitStride)
{
  __shared__ __align__(16) unsigned short As[2][2][128*32];
  __shared__ __align__(16) unsigned short Bs[2][2][128*32];
  int tid = threadIdx.x;
  int wave = tid >> 6, lane = tid & 63;
  int quad = lane >> 4, l16 = lane & 15;
  int wr = wave >> 1, wc = wave & 1;

  // XCD-aware bijective remap (T1)
  int nwgx = gridDim.x;
  int nwg  = nwgx * gridDim.y;
  int b    = blockIdx.y * nwgx + blockIdx.x;
  int q8 = nwg >> 3, r8 = nwg & 7;
  int xcd = b & 7, slot = b >> 3;
  int wgid = (xcd < r8 ? xcd*(q8+1) : r8*(q8+1) + (xcd-r8)*q8) + slot;
  int m0 = (wgid / nwgx) * 128, n0 = (wgid % nwgx) * 128;

  f32x4 acc[4][4];
  #pragma unroll
  for (int i=0;i<4;++i)
    #pragma unroll
    for (int j=0;j<4;++j) acc[i][j] = (f32x4){0.f,0.f,0.f,0.f};

  // staging coords: wave w covers tile rows 32w..32w+31 (two 1KB chunks/subtile)
  int r0 = wave*32 + (lane>>2);            // chunk 0 row
  int r1 = r0 + 16;                        // chunk 1 row
  int kc = (lane&3)*8;                     // k elem offset within 32-subtile
  int gm0 = m0 + r0; if (gm0 >= M) gm0 = M-1;
  int gm1 = m0 + r1; if (gm1 >= M) gm1 = M-1;
  const bf16* gA0 = Ap + (size_t)gm0*K + kc;
  const bf16* gA1 = Ap + (size_t)gm1*K + kc;
  const bf16* gB0 = Wt + (size_t)(n0 + r0)*K + kc;
  const bf16* gB1 = Wt + (size_t)(n0 + r1)*K + kc;

  // prologue: stage tile 0 (both subtiles), barrier (drains vmcnt)
  #pragma unroll
  for (int s=0;s<2;++s) {
    gl_lds16(gA0 + s*32, &As[0][s][wave*1024]);
    gl_lds16(gA1 + s*32, &As[0][s][wave*1024 + 512]);
    gl_lds16(gB0 + s*32, &Bs[0][s][wave*1024]);
    gl_lds16(gB1 + s*32, &Bs[0][s][wave*1024 + 512]);
  }
  __syncthreads();

  const int T = K >> 6;                    // BK=64 steps
  int cur = 0;
  for (int t = 0; t < T; ++t) {
    int kn = (t + 1) * 64;
    if (t + 1 < T) {
      int nxt = cur ^ 1;
      #pragma unroll
      for (int s=0;s<2;++s) {
        gl_lds16(gA0 + kn + s*32, &As[nxt][s][wave*1024]);
        gl_lds16(gA1 + kn + s*32, &As[nxt][s][wave*1024 + 512]);
        gl_lds16(gB0 + kn + s*32, &Bs[nxt][s][wave*1024]);
        gl_lds16(gB1 + kn + s*32, &Bs[nxt][s][wave*1024 + 512]);
      }
    }
    #pragma unroll
    for (int s=0;s<2;++s) {
      short8 a[4], bb[4];
      #pragma unroll
      for (int i=0;i<4;++i)
        a[i] = *(const short8*)&As[cur][s][(wr*64 + i*16 + l16)*32 + quad*8];
      #pragma unroll
      for (int j=0;j<4;++j)
        bb[j] = *(const short8*)&Bs[cur][s][(wc*64 + j*16 + l16)*32 + quad*8];
      #pragma unroll
      for (int i=0;i<4;++i)
        #pragma unroll
        for (int j=0;j<4;++j)
          acc[i][j] = __builtin_amdgcn_mfma_f32_16x16x32_bf16(a[i], bb[j], acc[i][j], 0, 0, 0);
    }
    __syncthreads();   // drains vmcnt (next tile landed) + all reads of buf[cur] done
    cur ^= 1;
  }

  // ---- epilogue: D[row=quad*4+r][col=l16] per 16x16 tile ----
  #pragma unroll
  for (int i=0;i<4;++i) {
    int mbase = m0 + wr*64 + i*16 + quad*4;
    #pragma unroll
    for (int j=0;j<4;++j) {
      int n = n0 + wc*64 + j*16 + l16;
      float bv;
      if (flags & MF_SPLIT) {
        int sel = n >> 8;
        const float* bp = (sel==0) ? bias0 : (sel==1 ? bias1 : bias2);
        bv = bp[n & 255];
      } else bv = bias0[n];
      #pragma unroll
      for (int r=0;r<4;++r) {
        int mm = mbase + r;
        if (mm >= M) continue;
        float v = acc[i][j][r] + bv;
        if (flags & MF_GELU) v = 0.5f*v*(1.f + erff(v*0.70710678118654752f));
        if (Rp) {
          size_t ri = (size_t)mm*N + n;
          v += (flags & MF_RF32) ? ((const float*)Rp)[ri] : bf2f(((const bf16*)Rp)[ri]);
        }
        if (flags & MF_SPLIT) {
          size_t ci = (size_t)(n>>8)*splitStride + (size_t)mm*256 + (n & 255);
          ((bf16*)Cp)[ci] = __float2bfloat16(v);
        } else {
          size_t ci = (size_t)mm*N + n;
          if (flags & MF_CF32) ((float*)Cp)[ci] = v;
          else                 ((bf16*)Cp)[ci] = __float2bfloat16(v);
        }
      }
    }
  }
}

// ---------------------------------------------------------------------------
// Old fp32 VALU GEMM — tiny route GEMMs (M<=1920), fp32 in/out.
// ---------------------------------------------------------------------------
__global__ __launch_bounds__(256) void gemm_k(
    const void* __restrict__ Ap, const float* __restrict__ W,
    const float* __restrict__ bias, const void* __restrict__ Rp,
    void* __restrict__ Cp, int M, int N, int K, int flags)
{
  __shared__ float As[16][68];
  __shared__ float Ws[16][68];
  int tid = threadIdx.x;
  int tx = tid & 15, ty = tid >> 4;
  int m0 = blockIdx.y * 64, n0 = blockIdx.x * 64;
  float acc[4][4];
  #pragma unroll
  for (int i=0;i<4;i++)
    #pragma unroll
    for (int j=0;j<4;j++) acc[i][j]=0.f;

  for (int k0 = 0; k0 < K; k0 += 16) {
    #pragma unroll
    for (int i = 0; i < 4; ++i) {
      int idx = tid + i*256;
      int r = idx >> 4, c = idx & 15;
      int gr = m0 + r;
      float v = 0.f;
      if (gr < M) {
        size_t gi = (size_t)gr*K + (size_t)(k0 + c);
        v = (flags & GF_ABF16) ? bf2f(((const bf16*)Ap)[gi]) : ((const float*)Ap)[gi];
        if (flags & GF_LOGRELU) v = log1pf(fmaxf(v, 0.f));
      }
      As[c][r] = v;
    }
    #pragma unroll
    for (int i = 0; i < 4; ++i) {
      int idx = tid + i*256;
      int c = idx >> 6, j = idx & 63;
      Ws[c][j] = W[(size_t)(k0+c)*N + (size_t)(n0 + j)];
    }
    __syncthreads();
    #pragma unroll
    for (int k = 0; k < 16; ++k) {
      float a[4], b[4];
      #pragma unroll
      for (int i=0;i<4;i++) a[i] = As[k][ty*4+i];
      #pragma unroll
      for (int j=0;j<4;j++) b[j] = Ws[k][tx*4+j];
      #pragma unroll
      for (int i=0;i<4;i++)
        #pragma unroll
        for (int j=0;j<4;j++) acc[i][j] = fmaf(a[i], b[j], acc[i][j]);
    }
    __syncthreads();
  }
  #pragma unroll
  for (int i=0;i<4;i++) {
    int row = m0 + ty*4 + i;
    if (row >= M) continue;
    #pragma unroll
    for (int j=0;j<4;j++) {
      int col = n0 + tx*4 + j;
      float v = acc[i][j] + bias[col];
      if (flags & GF_GELU) v = 0.5f*v*(1.f + erff(v*0.70710678118654752f));
      if (Rp) {
        size_t ri = (size_t)row*N + col;
        v += (flags & GF_RBF16) ? bf2f(((const bf16*)Rp)[ri]) : ((const float*)Rp)[ri];
      }
      size_t ci = (size_t)row*N + col;
      if (flags & GF_CBF16) ((bf16*)Cp)[ci] = __float2bfloat16(v);
      else                  ((float*)Cp)[ci] = v;
    }
  }
}

// ---------------------------------------------------------------------------
// Temporal attention via MFMA. 4 waves/block, wave w owns pair p=bid*4+w
// (p = bv*8 + h). S=24 padded to 32, DH=32. In-place on Q.
// ---------------------------------------------------------------------------
__global__ __launch_bounds__(256) void attn1_k(bf16* __restrict__ Q,
                                               const bf16* __restrict__ Kb,
                                               const bf16* __restrict__ Vb)
{
  __shared__ __align__(16) unsigned short lds[4*4096];  // 32 KB
  int wave = threadIdx.x >> 6, lane = threadIdx.x & 63;
  int quad = lane >> 4, l16 = lane & 15;
  int p = blockIdx.x*4 + wave;          // bv*8 + h
  int bv = p >> 3, h = p & 7;
  const size_t base0 = ((size_t)bv*SS)*DD + h*32;

  int slab = wave*4096;
  int lQ = slab, lK = slab + 1024, lV = slab + 2048, lP = slab + 3072;

  // ---- stage Q,K,V (24 rows x 32 bf16 each) via global_load_lds w16 ----
  {
    int row0 = lane >> 2, c0 = (lane & 3)*8;          // it0: u = lane
    const bf16* gq = Q  + base0 + (size_t)row0*DD + c0;
    const bf16* gk = Kb + base0 + (size_t)row0*DD + c0;
    const bf16* gv = Vb + base0 + (size_t)row0*DD + c0;
    gl_lds16(gq, &lds[lQ]);
    gl_lds16(gk, &lds[lK]);
    gl_lds16(gv, &lds[lV]);
    if (lane < 32) {                                   // it1: u = 64+lane
      int row1 = 16 + (lane >> 2);
      const bf16* gq1 = Q  + base0 + (size_t)row1*DD + c0;
      const bf16* gk1 = Kb + base0 + (size_t)row1*DD + c0;
      const bf16* gv1 = Vb + base0 + (size_t)row1*DD + c0;
      gl_lds16(gq1, &lds[lQ + 512]);
      gl_lds16(gk1, &lds[lK + 512]);
      gl_lds16(gv1, &lds[lV + 512]);
    }
  }
  // zero V pad rows 24..31 (k-dim of PV MFMA must not contain NaN garbage)
  *(uint2*)&lds[lV + 768 + lane*4] = (uint2){0u,0u};

  asm volatile("s_waitcnt vmcnt(0)" ::: "memory");
  __builtin_amdgcn_sched_barrier(0);

  // ---- QK^T: 2x2 tiles of 16, K=32 ----
  short8 qa[2], kb[2];
  #pragma unroll
  for (int t=0;t<2;++t) {
    qa[t] = *(const short8*)&lds[lQ + (t*16 + l16)*32 + quad*8];
    kb[t] = *(const short8*)&lds[lK + (t*16 + l16)*32 + quad*8];
  }
  f32x4 scc[2][2];
  #pragma unroll
  for (int ti=0;ti<2;++ti)
    #pragma unroll
    for (int tj=0;tj<2;++tj)
      scc[ti][tj] = __builtin_amdgcn_mfma_f32_16x16x32_bf16(qa[ti], kb[tj],
                      (f32x4){0.f,0.f,0.f,0.f}, 0, 0, 0);
  // mask pad cols j=24..31 (tile tj=1, l16>=8) to -inf
  if (l16 >= 8) {
    scc[0][1] = (f32x4){-INFINITY,-INFINITY,-INFINITY,-INFINITY};
    scc[1][1] = (f32x4){-INFINITY,-INFINITY,-INFINITY,-INFINITY};
  }

  // ---- softmax over cols (row = quad*4+r+16*ti, cols across l16 x tj) ----
  #pragma unroll
  for (int ti=0;ti<2;++ti) {
    #pragma unroll
    for (int r=0;r<4;++r) {
      float mv = fmaxf(scc[ti][0][r], scc[ti][1][r]);
      #pragma unroll
      for (int off=1; off<16; off<<=1) mv = fmaxf(mv, __shfl_xor(mv, off));
      float e0 = expf((scc[ti][0][r]-mv)*SCALE);
      float e1 = expf((scc[ti][1][r]-mv)*SCALE);   // exp(-inf)=0 for pad cols
      float sm = e0 + e1;
      #pragma unroll
      for (int off=1; off<16; off<<=1) sm += __shfl_xor(sm, off);
      float inv = 1.f/sm;
      int row = ti*16 + quad*4 + r;
      lds[lP + row*32 + l16]      = f2bfbits(e0*inv);
      lds[lP + row*32 + 16 + l16] = f2bfbits(e1*inv);
    }
  }

  // ---- PV: O[24x32] = P[24x32pad] x V[32x32], 2x2 tiles ----
  f32x4 o[2][2];
  #pragma unroll
  for (int ti=0;ti<2;++ti) {
    short8 pa = *(const short8*)&lds[lP + (ti*16 + l16)*32 + quad*8];
    #pragma unroll
    for (int tn=0;tn<2;++tn) {
      unsigned short vt[8];
      #pragma unroll
      for (int e=0;e<8;++e) vt[e] = lds[lV + (quad*8+e)*32 + tn*16 + l16];
      short8 vb = *(short8*)vt;
      o[ti][tn] = __builtin_amdgcn_mfma_f32_16x16x32_bf16(pa, vb,
                    (f32x4){0.f,0.f,0.f,0.f}, 0, 0, 0);
    }
  }

  // ---- store (rows < 24 only), col = tn*16+l16 ----
  #pragma unroll
  for (int ti=0;ti<2;++ti) {
    #pragma unroll
    for (int r=0;r<4;++r) {
      int row = ti*16 + quad*4 + r;
      if (row < SS) {
        #pragma unroll
        for (int tn=0;tn<2;++tn)
          Q[base0 + (size_t)row*DD + tn*16 + l16] = __float2bfloat16(o[ti][tn][r]);
      }
    }
  }
}

// ---------------------------------------------------------------------------
// LayerNorm family
// ---------------------------------------------------------------------------
__global__ __launch_bounds__(256) void ln_k(const bf16* __restrict__ X, bf16* __restrict__ Y,
                                            const float* __restrict__ g, const float* __restrict__ b,
                                            int nrows)
{
  int row = blockIdx.x*4 + (threadIdx.x >> 6);
  int lane = threadIdx.x & 63;
  if (row >= nrows) return;
  const bf16* xr = X + (size_t)row*DD;
  int c = lane*4;
  float v0 = bf2f(xr[c+0]), v1 = bf2f(xr[c+1]), v2 = bf2f(xr[c+2]), v3 = bf2f(xr[c+3]);
  float s = v0+v1+v2+v3;
  #pragma unroll
  for (int off = 32; off; off >>= 1) s += __shfl_xor(s, off);
  float m = s * (1.f/256.f);
  float d0=v0-m, d1=v1-m, d2=v2-m, d3=v3-m;
  float q = d0*d0+d1*d1+d2*d2+d3*d3;
  #pragma unroll
  for (int off = 32; off; off >>= 1) q += __shfl_xor(q, off);
  float rstd = rsqrtf(q*(1.f/256.f) + 1e-5f);
  bf16* yr = Y + (size_t)row*DD;
  yr[c+0] = __float2bfloat16(d0*rstd*g[c+0] + b[c+0]);
  yr[c+1] = __float2bfloat16(d1*rstd*g[c+1] + b[c+1]);
  yr[c+2] = __float2bfloat16(d2*rstd*g[c+2] + b[c+2]);
  yr[c+3] = __float2bfloat16(d3*rstd*g[c+3] + b[c+3]);
}

// LN fused with (B,V,S,D)->(B,S,V,D) permute; also emits xl = log1p(relu(xd))
__global__ __launch_bounds__(256) void ln_t_k(const bf16* __restrict__ X, bf16* __restrict__ Y,
                                              bf16* __restrict__ Yl,
                                              const float* __restrict__ g, const float* __restrict__ b)
{
  int r1 = blockIdx.x*4 + (threadIdx.x >> 6);
  int lane = threadIdx.x & 63;
  if (r1 >= NROWS) return;
  const bf16* xr = X + (size_t)r1*DD;
  int c = lane*4;
  float v0 = bf2f(xr[c+0]), v1 = bf2f(xr[c+1]), v2 = bf2f(xr[c+2]), v3 = bf2f(xr[c+3]);
  float s = v0+v1+v2+v3;
  #pragma unroll
  for (int off = 32; off; off >>= 1) s += __shfl_xor(s, off);
  float m = s * (1.f/256.f);
  float d0=v0-m, d1=v1-m, d2=v2-m, d3=v3-m;
  float q = d0*d0+d1*d1+d2*d2+d3*d3;
  #pragma unroll
  for (int off = 32; off; off >>= 1) q += __shfl_xor(q, off);
  float rstd = rsqrtf(q*(1.f/256.f) + 1e-5f);
  int b_ = r1 / (VV*SS);
  int rem = r1 % (VV*SS);
  int v = rem / SS, ss = rem % SS;
  int r2 = (b_*SS + ss)*VV + v;
  float o0 = d0*rstd*g[c+0] + b[c+0];
  float o1 = d1*rstd*g[c+1] + b[c+1];
  float o2 = d2*rstd*g[c+2] + b[c+2];
  float o3 = d3*rstd*g[c+3] + b[c+3];
  bf16* yr = Y + (size_t)r2*DD;
  yr[c+0] = __float2bfloat16(o0);
  yr[c+1] = __float2bfloat16(o1);
  yr[c+2] = __float2bfloat16(o2);
  yr[c+3] = __float2bfloat16(o3);
  bf16* ylr = Yl + (size_t)r2*DD;
  ylr[c+0] = __float2bfloat16(log1pf(fmaxf(o0, 0.f)));
  ylr[c+1] = __float2bfloat16(log1pf(fmaxf(o1, 0.f)));
  ylr[c+2] = __float2bfloat16(log1pf(fmaxf(o2, 0.f)));
  ylr[c+3] = __float2bfloat16(log1pf(fmaxf(o3, 0.f)));
}

// Final LN + permute (B,S,V,D)->(B,V,S,D) + fp32 store
__global__ __launch_bounds__(256) void ln_out_k(const bf16* __restrict__ X, float* __restrict__ out,
                                                const float* __restrict__ g, const float* __restrict__ b)
{
  int row = blockIdx.x*4 + (threadIdx.x >> 6);
  int lane = threadIdx.x & 63;
  if (row >= NROWS) return;
  const bf16* xr = X + (size_t)row*DD;
  int c = lane*4;
  float v0 = bf2f(xr[c+0]), v1 = bf2f(xr[c+1]), v2 = bf2f(xr[c+2]), v3 = bf2f(xr[c+3]);
  float s = v0+v1+v2+v3;
  #pragma unroll
  for (int off = 32; off; off >>= 1) s += __shfl_xor(s, off);
  float m = s * (1.f/256.f);
  float d0=v0-m, d1=v1-m, d2=v2-m, d3=v3-m;
  float q = d0*d0+d1*d1+d2*d2+d3*d3;
  #pragma unroll
  for (int off = 32; off; off >>= 1) q += __shfl_xor(q, off);
  float rstd = rsqrtf(q*(1.f/256.f) + 1e-5f);
  int bs = row / VV, vv = row % VV;
  int bb = bs / SS, ss = bs % SS;
  float* op = out + (((size_t)bb*VV + vv)*SS + ss)*DD + c;
  op[0] = d0*rstd*g[c+0] + b[c+0];
  op[1] = d1*rstd*g[c+1] + b[c+1];
  op[2] = d2*rstd*g[c+2] + b[c+2];
  op[3] = d3*rstd*g[c+3] + b[c+3];
}

// ---------------------------------------------------------------------------
// Scores + top-33 (desc, ties -> lower index). One wave per (bs,h,g).
// ---------------------------------------------------------------------------
__global__ __launch_bounds__(64) void topk_k(const float* __restrict__ qS,
                                             const bf16* __restrict__ kS,
                                             int* __restrict__ idxOut)
{
  int bid = blockIdx.x;                // (bs*8+h)*10+g
  int g = bid % GG;
  int h = (bid / GG) % HH;
  int bs = bid / (GG*HH);
  int s = bs % SS;
  int lane = threadIdx.x;

  float qv[32];
  const float4* qp = (const float4*)(qS + ((size_t)(s*GG + g))*DD + h*32);
  #pragma unroll
  for (int e4 = 0; e4 < 8; ++e4) {
    float4 t = qp[e4];
    qv[e4*4+0]=t.x; qv[e4*4+1]=t.y; qv[e4*4+2]=t.z; qv[e4*4+3]=t.w;
  }

  float sc[6];
  #pragma unroll
  for (int j = 0; j < 6; ++j) {
    int v = lane + j*64;
    if (v < VV) {
      const uint4* kp = (const uint4*)(kS + ((size_t)bs*VV + v)*DD + h*32);
      float d = 0.f;
      #pragma unroll
      for (int cch = 0; cch < 4; ++cch) {
        uint4 u = kp[cch];
        const unsigned short* usp = (const unsigned short*)&u;
        #pragma unroll
        for (int e = 0; e < 8; ++e)
          d = fmaf(bfbits2f(usp[e]), qv[cch*8+e], d);
      }
      sc[j] = d * SCALE;
    } else sc[j] = -INFINITY;
  }

  for (int it = 0; it < KTOP; ++it) {
    float bv = sc[0]; int bj = 0;
    #pragma unroll
    for (int j = 1; j < 6; ++j) if (sc[j] > bv) { bv = sc[j]; bj = j; }
    int bi = lane + bj*64;
    #pragma unroll
    for (int off = 32; off; off >>= 1) {
      float ov = __shfl_down(bv, off);
      int   oi = __shfl_down(bi, off);
      if (ov > bv || (ov == bv && oi < bi)) { bv = ov; bi = oi; }
    }
    bi = __shfl(bi, 0);
    if (lane == 0) idxOut[(size_t)bid*KTOP + it] = bi;
    if ((bi & 63) == lane) {
      int jj = bi >> 6;
      #pragma unroll
      for (int j = 0; j < 6; ++j) if (jj == j) sc[j] = -INFINITY;
    }
  }
}

// ---------------------------------------------------------------------------
// Grouped conv + min/max/exp -> feat (bs,G,256) fp32
// ---------------------------------------------------------------------------
__global__ __launch_bounds__(256) void conv_k(const bf16* __restrict__ vS,
                                              const int* __restrict__ idx,
                                              const float* __restrict__ cw,
                                              const float* __restrict__ cb,
                                              float* __restrict__ feat)
{
  int bid = blockIdx.x;
  int bs = bid / GG, g = bid % GG;
  int tid = threadIdx.x;
  int h = tid >> 5, d = tid & 31;
  __shared__ float cws[KTOP];
  __shared__ int idl[HH][KTOP];
  __shared__ float ms[256];
  if (tid < KTOP) cws[tid] = cw[g*KTOP + tid];
  for (int i = tid; i < HH*KTOP; i += 256) {
    int hh = i / KTOP, k = i % KTOP;
    int ix = idx[(((size_t)bs*HH + hh)*GG + g)*KTOP + k];
    idl[hh][k] = (ix < 0) ? 0 : (ix >= VV ? VV-1 : ix);
  }
  __syncthreads();
  float acc = 0.f;
  #pragma unroll
  for (int k = 0; k < KTOP; ++k)
    acc += bf2f(vS[((size_t)bs*VV + idl[h][k])*DD + h*32 + d]) * cws[k];
  acc += cb[g];
  ms[tid] = acc;
  __syncthreads();
  float mn = acc, mx = acc;
  #pragma unroll
  for (int j = 0; j < 32; ++j) {
    float t = ms[h*32 + j];
    mn = fminf(mn, t); mx = fmaxf(mx, t);
  }
  float xn = expf((acc - mn) / fmaxf(mx - mn, 1e-6f));
  feat[((size_t)bs*GG + g)*DD + h*32 + d] = xn;
}

// ---------------------------------------------------------------------------
// Cross attention (route 2): 321 bf16 queries vs 10 fp32 keys per bs.
// ---------------------------------------------------------------------------
__global__ __launch_bounds__(256) void attn2_k(bf16* __restrict__ Q,
                                               const float* __restrict__ KR,
                                               const float* __restrict__ VR)
{
  int bs = blockIdx.x;
  int tid = threadIdx.x;
  __shared__ float kr[GG][DD], vr[GG][DD];
  for (int i = tid; i < GG*DD; i += 256) {
    int r = i >> 8, c = i & 255;
    kr[r][c] = KR[((size_t)bs*GG + r)*DD + c];
    vr[r][c] = VR[((size_t)bs*GG + r)*DD + c];
  }
  __syncthreads();
  for (int task = tid; task < VV*HH; task += 256) {
    int v = task >> 3, h = task & 7;
    bf16* qp = Q + ((size_t)bs*VV + v)*DD + h*32;
    float qr[32];
    #pragma unroll
    for (int d = 0; d < 32; ++d) qr[d] = bf2f(qp[d]);
    float sv[GG];
    float mx = -INFINITY;
    #pragma unroll
    for (int gi = 0; gi < GG; ++gi) {
      float dsum = 0.f;
      #pragma unroll
      for (int d = 0; d < 32; ++d) dsum += qr[d]*kr[gi][h*32+d];
      sv[gi] = dsum * SCALE;
      mx = fmaxf(mx, sv[gi]);
    }
    float ssum = 0.f;
    #pragma unroll
    for (int gi = 0; gi < GG; ++gi) { sv[gi] = expf(sv[gi]-mx); ssum += sv[gi]; }
    float inv = 1.f/ssum;
    float o[32];
    #pragma unroll
    for (int d = 0; d < 32; ++d) o[d] = 0.f;
    #pragma unroll
    for (int gi = 0; gi < GG; ++gi) {
      float p = sv[gi]*inv;
      #pragma unroll
      for (int d = 0; d < 32; ++d) o[d] += p*vr[gi][h*32+d];
    }
    #pragma unroll
    for (int d = 0; d < 32; ++d) qp[d] = __float2bfloat16(o[d]);
  }
}

// ---------------------------------------------------------------------------
extern "C" void kernel_launch(void* const* d_in, const int* in_sizes, int n_in,
                              void* d_out, int out_size, void* d_ws, size_t ws_size,
                              hipStream_t stream)
{
  const float* queries=(const float*)d_in[0];
  const float* t_wq=(const float*)d_in[1];  const float* t_bq=(const float*)d_in[2];
  const float* t_wk=(const float*)d_in[3];  const float* t_bk=(const float*)d_in[4];
  const float* t_wv=(const float*)d_in[5];  const float* t_bv=(const float*)d_in[6];
  const float* t_wo=(const float*)d_in[7];  const float* t_bo=(const float*)d_in[8];
  const float* s_wq=(const float*)d_in[9];  const float* s_bq=(const float*)d_in[10];
  const float* s_wk=(const float*)d_in[11]; const float* s_bk=(const float*)d_in[12];
  const float* s_wv=(const float*)d_in[13]; const float* s_bv=(const float*)d_in[14];
  const float* s_wo=(const float*)d_in[15]; const float* s_bo=(const float*)d_in[16];
  const float* cluster=(const float*)d_in[17];
  const float* conv_w=(const float*)d_in[18]; const float* conv_b=(const float*)d_in[19];
  const float* r_wq=(const float*)d_in[20]; const float* r_bq=(const float*)d_in[21];
  const float* r_wk=(const float*)d_in[22]; const float* r_bk=(const float*)d_in[23];
  const float* r_wv=(const float*)d_in[24]; const float* r_bv=(const float*)d_in[25];
  const float* r_wo=(const float*)d_in[26]; const float* r_bo=(const float*)d_in[27];
  const float* ln_t1_g=(const float*)d_in[28]; const float* ln_t1_b=(const float*)d_in[29];
  const float* ln_t2_g=(const float*)d_in[30]; const float* ln_t2_b=(const float*)d_in[31];
  const float* ln_d1_g=(const float*)d_in[32]; const float* ln_d1_b=(const float*)d_in[33];
  const float* ln_d2_g=(const float*)d_in[34]; const float* ln_d2_b=(const float*)d_in[35];
  const float* ft_w1=(const float*)d_in[36]; const float* ft_b1=(const float*)d_in[37];
  const float* ft_w2=(const float*)d_in[38]; const float* ft_b2=(const float*)d_in[39];
  const float* fd_w1=(const float*)d_in[40]; const float* fd_b1=(const float*)d_in[41];
  const float* fd_w2=(const float*)d_in[42]; const float* fd_b2=(const float*)d_in[43];

  // Workspace: 4 big bf16 buffers (126 MB) + W^T pool (3 MB) + smalls (~10 MB)
  bf16* Ab = (bf16*)d_ws;
  bf16* Bb = Ab + NE;
  bf16* Cb = Bb + NE;
  bf16* Db = Cb + NE;                       // queries-bf16 (route1) / xl (route2)
  bf16* WP = Db + NE;                       // 1572864 bf16
  float* QSf   = (float*)(WP + 1572864);
  float* FEATf = QSf + 240*256;
  float* ROUTEf= FEATf + 1920*256;
  float* KRf   = ROUTEf + 1920*256;
  float* VRf   = KRf + 1920*256;
  int*   IDXb  = (int*)(VRf + 1920*256);

  // ---- weight prep ----
  WPrep wp;
  const float* wsrc[12] = {t_wq,t_wk,t_wv,t_wo,s_wk,s_wv,r_wq,r_wo,ft_w1,ft_w2,fd_w1,fd_w2};
  int wK[12] = {256,256,256,256,256,256,256,256,256,1024,256,1024};
  int wN[12] = {256,256,256,256,256,256,256,256,1024,256,1024,256};
  int off = 0, toff = 0;
  for (int i=0;i<12;++i) {
    wp.src[i]=wsrc[i]; wp.K[i]=wK[i]; wp.N[i]=wN[i];
    wp.dstoff[i]=off; wp.tileoff[i]=toff;
    off += wK[i]*wN[i];
    toff += (wK[i]/32)*(wN[i]/32);
  }
  wp.tileoff[12]=toff;
  prep_w_k<<<toff, 256, 0, stream>>>(wp, WP);
  bf16* Wqkv=WP+wp.dstoff[0];               // [768][256]
  bf16* Wo=WP+wp.dstoff[3];
  bf16* Wskv=WP+wp.dstoff[4];               // [512][256]
  bf16* Wrq=WP+wp.dstoff[6]; bf16* Wro=WP+wp.dstoff[7];
  bf16* Wf1=WP+wp.dstoff[8]; bf16* Wf2=WP+wp.dstoff[9];
  bf16* Wd1=WP+wp.dstoff[10]; bf16* Wd2=WP+wp.dstoff[11];

  dim3 blk(256);
  const int STRIPE = NROWS/4;               // 15408
  dim3 gQKV(6, (NROWS+127)/128);
  dim3 gKV(4, (NROWS+127)/128);
  dim3 gBig(2, (NROWS+127)/128);
  dim3 gS1(8, (STRIPE+127)/128);
  dim3 gS2(2, (STRIPE+127)/128);
  dim3 gQ(4, 4);
  dim3 gSmall(4, 30);
  const int GCVT = (int)(NE/2048);          // 7704

  // ---- Route 1: temporal ----
  f2b_k<<<GCVT, blk, 0, stream>>>(queries, Db, NE);
  mgemm_k<<<gQKV, blk, 0, stream>>>(Db, Wqkv, t_bq, t_bk, t_bv, nullptr, Ab,
                                    NROWS, 768, 256, MF_SPLIT, NE);           // Q->Ab K->Bb V->Cb
  attn1_k<<<(BV*HH)/4, blk, 0, stream>>>(Ab, Bb, Cb);                         // O -> Ab
  mgemm_k<<<gBig, blk, 0, stream>>>(Ab, Wo, t_bo, nullptr, nullptr, queries, Bb,
                                    NROWS, 256, 256, MF_RF32, 0);
  ln_k<<<NROWS/4, blk, 0, stream>>>(Bb, Ab, ln_t1_g, ln_t1_b, NROWS);
  for (int st = 0; st < 4; ++st) {
    size_t ro = (size_t)st * STRIPE * DD;
    mgemm_k<<<gS1, blk, 0, stream>>>(Ab + ro, Wf1, ft_b1, nullptr, nullptr, nullptr, Cb,
                                     STRIPE, 1024, 256, MF_GELU, 0);
    mgemm_k<<<gS2, blk, 0, stream>>>(Cb, Wf2, ft_b2, nullptr, nullptr, Ab + ro, Bb + ro,
                                     STRIPE, 256, 1024, 0, 0);
  }
  ln_t_k<<<NROWS/4, blk, 0, stream>>>(Bb, Ab, Db, ln_t2_g, ln_t2_b);          // xd -> Ab, xl -> Db

  // ---- Route 2: dimensional ----
  mgemm_k<<<gKV, blk, 0, stream>>>(Db, Wskv, s_bk, s_bv, nullptr, nullptr, Bb,
                                   NROWS, 512, 256, MF_SPLIT, NE);            // kS->Bb vS->Cb
  gemm_k<<<gQ, blk, 0, stream>>>(cluster, s_wq, s_bq, nullptr, QSf, 240, 256, 256, 0);
  topk_k<<<BSEG*HH*GG, 64, 0, stream>>>(QSf, Bb, IDXb);
  conv_k<<<BSEG*GG, blk, 0, stream>>>(Cb, IDXb, conv_w, conv_b, FEATf);
  gemm_k<<<gSmall, blk, 0, stream>>>(FEATf, s_wo, s_bo, nullptr, ROUTEf, 1920, 256, 256, 0);
  gemm_k<<<gSmall, blk, 0, stream>>>(ROUTEf, r_wk, r_bk, nullptr, KRf, 1920, 256, 256, 0);
  gemm_k<<<gSmall, blk, 0, stream>>>(ROUTEf, r_wv, r_bv, nullptr, VRf, 1920, 256, 256, 0);
  mgemm_k<<<gBig, blk, 0, stream>>>(Ab, Wrq, r_bq, nullptr, nullptr, nullptr, Bb,
                                    NROWS, 256, 256, 0, 0);                   // qD -> Bb
  attn2_k<<<BSEG, blk, 0, stream>>>(Bb, KRf, VRf);                            // O -> Bb
  mgemm_k<<<gBig, blk, 0, stream>>>(Bb, Wro, r_bo, nullptr, nullptr, Ab, Cb,
                                    NROWS, 256, 256, 0, 0);                   // + xd -> Cb
  ln_k<<<NROWS/4, blk, 0, stream>>>(Cb, Ab, ln_d1_g, ln_d1_b, NROWS);
  for (int st = 0; st < 4; ++st) {
    size_t ro = (size_t)st * STRIPE * DD;
    mgemm_k<<<gS1, blk, 0, stream>>>(Ab + ro, Wd1, fd_b1, nullptr, nullptr, nullptr, Bb,
                                     STRIPE, 1024, 256, MF_GELU, 0);
    mgemm_k<<<gS2, blk, 0, stream>>>(Bb, Wd2, fd_b2, nullptr, nullptr, Ab + ro, Cb + ro,
                                     STRIPE, 256, 1024, 0, 0);
  }
  ln_out_k<<<NROWS/4, blk, 0, stream>>>(Cb, (float*)d_out, ln_d2_g, ln_d2_b);
}

// Round 8
// 1732.516 us; speedup vs baseline: 1.0033x; 1.0017x over previous
//
#include <hip/hip_runtime.h>
#include <hip/hip_bf16.h>
#include <cmath>

typedef __hip_bfloat16 bf16;
typedef __attribute__((ext_vector_type(8))) short short8;
typedef __attribute__((ext_vector_type(4))) float f32x4;
typedef unsigned int u32;
typedef __attribute__((address_space(3))) u32 lds_u32;
typedef const __attribute__((address_space(1))) u32 glob_u32;

#define BB 8
#define VV 321
#define SS 24
#define DD 256
#define HH 8
#define GG 10
#define KTOP 33
#define DFFN 1024
#define BV (BB*VV)            // 2568
#define BSEG (BB*SS)          // 192
#define NROWS (BV*SS)         // 61632
#define NE ((size_t)NROWS*DD) // 15777792
#define SCALE 0.17677669529663687f  // 1/sqrt(32)

enum { GF_GELU=1, GF_LOGRELU=2, GF_ABF16=4, GF_RBF16=8, GF_CBF16=16 };
enum { MF_GELU=1, MF_RF32=8, MF_CF32=16, MF_SPLIT=32 };

__device__ __forceinline__ float bf2f(bf16 x){ return __bfloat162float(x); }
__device__ __forceinline__ unsigned short f2bfbits(float f){
  bf16 h = __float2bfloat16(f);
  return *(unsigned short*)&h;
}
__device__ __forceinline__ float bfbits2f(unsigned int u){
  bf16 h; *(unsigned short*)&h = (unsigned short)u; return __bfloat162float(h);
}
__device__ __forceinline__ void ld4bf(const bf16* p, float* f){
  uint2 u = *(const uint2*)p;
  f[0]=bfbits2f(u.x&0xffff); f[1]=bfbits2f(u.x>>16);
  f[2]=bfbits2f(u.y&0xffff); f[3]=bfbits2f(u.y>>16);
}
__device__ __forceinline__ void st4bf(bf16* p, const float* f){
  uint2 u;
  u.x = (unsigned)f2bfbits(f[0]) | ((unsigned)f2bfbits(f[1])<<16);
  u.y = (unsigned)f2bfbits(f[2]) | ((unsigned)f2bfbits(f[3])<<16);
  *(uint2*)p = u;
}
// async 16B global -> LDS (wave-uniform LDS base + lane*16)
__device__ __forceinline__ void gl_lds16(const void* g, void* l){
  __builtin_amdgcn_global_load_lds((glob_u32*)g, (lds_u32*)l, 16, 0, 0);
}

// ---------------------------------------------------------------------------
// Weight prep: fp32 W[K][N] -> bf16 W^T[N][K] into pool. 32x32 tiles via LDS.
// ---------------------------------------------------------------------------
struct WPrep {
  const float* src[12];
  int K[12], N[12], dstoff[12], tileoff[13];
};

__global__ __launch_bounds__(256) void prep_w_k(WPrep p, bf16* __restrict__ pool)
{
  __shared__ float t[32][33];
  int b = blockIdx.x;
  int m = 0;
  while (b >= p.tileoff[m+1]) ++m;
  int tt = b - p.tileoff[m];
  int K = p.K[m], N = p.N[m];
  int nc = N >> 5;
  int tr = tt / nc, tc = tt % nc;
  const float* src = p.src[m];
  int tid = threadIdx.x;
  int r = tid >> 3, c = (tid & 7) * 4;
  float4 v = *(const float4*)&src[(size_t)(tr*32 + r)*N + tc*32 + c];
  t[r][c+0]=v.x; t[r][c+1]=v.y; t[r][c+2]=v.z; t[r][c+3]=v.w;
  __syncthreads();
  bf16* dst = pool + p.dstoff[m];
  size_t base = (size_t)(tc*32 + r)*K + tr*32 + c;
  #pragma unroll
  for (int i=0;i<4;++i) dst[base+i] = __float2bfloat16(t[c+i][r]);
}

// ---------------------------------------------------------------------------
// fp32 -> bf16 bulk convert (8 elems/thread)
// ---------------------------------------------------------------------------
__global__ __launch_bounds__(256) void f2b_k(const float* __restrict__ X, bf16* __restrict__ Y, size_t n)
{
  size_t i = ((size_t)blockIdx.x*256 + threadIdx.x)*8;
  if (i >= n) return;
  float4 a = *(const float4*)(X+i);
  float4 b = *(const float4*)(X+i+4);
  unsigned short v[8] = {f2bfbits(a.x),f2bfbits(a.y),f2bfbits(a.z),f2bfbits(a.w),
                         f2bfbits(b.x),f2bfbits(b.y),f2bfbits(b.z),f2bfbits(b.w)};
  *(uint4*)(Y+i) = *(uint4*)v;
}

// ---------------------------------------------------------------------------
// MFMA GEMM v6: BK=32 double-buffer (round-4 proven skeleton, 32 KB LDS)
// + XCD-bijective swizzle (round-7 proven: FETCH 95.8 -> 17.5 MB).
// Per K-step: issue next tile's 4 DMA loads into buf^1, compute current tile
// (8 ds_read + 16 MFMA), one __syncthreads (drains vmcnt; barrier).
// Clean A/B vs round-4: identical structure, swizzle only.
// ---------------------------------------------------------------------------
__global__ __launch_bounds__(256) void mgemm_k(
    const bf16* __restrict__ Ap, const bf16* __restrict__ Wt,
    const float* __restrict__ bias0, const float* __restrict__ bias1,
    const float* __restrict__ bias2, const void* __restrict__ Rp,
    void* __restrict__ Cp, int M, int N, int K, int flags, size_t splitStride)
{
  __shared__ __align__(16) unsigned short As[2][128*32];
  __shared__ __align__(16) unsigned short Bs[2][128*32];
  int tid = threadIdx.x;
  int wave = tid >> 6, lane = tid & 63;
  int quad = lane >> 4, l16 = lane & 15;
  int wr = wave >> 1, wc = wave & 1;

  // XCD-aware bijective remap (T1): consecutive linear ids (x-fast, same
  // A-panel) land on one XCD's L2 -> A re-reads become L2 hits.
  int nwgx = gridDim.x;
  int nwg  = nwgx * gridDim.y;
  int b    = blockIdx.y * nwgx + blockIdx.x;
  int q8 = nwg >> 3, r8 = nwg & 7;
  int xcd = b & 7, slot = b >> 3;
  int wgid = (xcd < r8 ? xcd*(q8+1) : r8*(q8+1) + (xcd-r8)*q8) + slot;
  int m0 = (wgid / nwgx) * 128, n0 = (wgid % nwgx) * 128;

  f32x4 acc[4][4];
  #pragma unroll
  for (int i=0;i<4;++i)
    #pragma unroll
    for (int j=0;j<4;++j) acc[i][j] = (f32x4){0.f,0.f,0.f,0.f};

  // staging coords: wave w covers tile rows 32w..32w+31 (two 1KB chunks)
  int r0 = wave*32 + (lane>>2);            // chunk 0 row
  int r1 = r0 + 16;                        // chunk 1 row
  int kc = (lane&3)*8;                     // k elem offset within tile
  int gm0 = m0 + r0; if (gm0 >= M) gm0 = M-1;
  int gm1 = m0 + r1; if (gm1 >= M) gm1 = M-1;
  const bf16* gA0 = Ap + (size_t)gm0*K + kc;
  const bf16* gA1 = Ap + (size_t)gm1*K + kc;
  const bf16* gB0 = Wt + (size_t)(n0 + r0)*K + kc;
  const bf16* gB1 = Wt + (size_t)(n0 + r1)*K + kc;

  // prologue: stage tile 0 into buf 0, barrier (drains vmcnt)
  gl_lds16(gA0, &As[0][wave*1024]);
  gl_lds16(gA1, &As[0][wave*1024 + 512]);
  gl_lds16(gB0, &Bs[0][wave*1024]);
  gl_lds16(gB1, &Bs[0][wave*1024 + 512]);
  __syncthreads();

  int cur = 0;
  for (int k0 = 0; k0 < K; k0 += 32) {
    // issue next tile's loads first (overlap HBM latency with compute below)
    if (k0 + 32 < K) {
      int nxt = cur ^ 1;
      gl_lds16(gA0 + k0 + 32, &As[nxt][wave*1024]);
      gl_lds16(gA1 + k0 + 32, &As[nxt][wave*1024 + 512]);
      gl_lds16(gB0 + k0 + 32, &Bs[nxt][wave*1024]);
      gl_lds16(gB1 + k0 + 32, &Bs[nxt][wave*1024 + 512]);
    }
    short8 a[4], bb[4];
    #pragma unroll
    for (int i=0;i<4;++i)
      a[i] = *(const short8*)&As[cur][(wr*64 + i*16 + l16)*32 + quad*8];
    #pragma unroll
    for (int j=0;j<4;++j)
      bb[j] = *(const short8*)&Bs[cur][(wc*64 + j*16 + l16)*32 + quad*8];
    #pragma unroll
    for (int i=0;i<4;++i)
      #pragma unroll
      for (int j=0;j<4;++j)
        acc[i][j] = __builtin_amdgcn_mfma_f32_16x16x32_bf16(a[i], bb[j], acc[i][j], 0, 0, 0);
    __syncthreads();   // drains vmcnt (next tile landed) + all reads of buf[cur] done
    cur ^= 1;
  }

  // ---- epilogue: D[row=quad*4+r][col=l16] per 16x16 tile ----
  #pragma unroll
  for (int i=0;i<4;++i) {
    int mbase = m0 + wr*64 + i*16 + quad*4;
    #pragma unroll
    for (int j=0;j<4;++j) {
      int n = n0 + wc*64 + j*16 + l16;
      float bv;
      if (flags & MF_SPLIT) {
        int sel = n >> 8;
        const float* bp = (sel==0) ? bias0 : (sel==1 ? bias1 : bias2);
        bv = bp[n & 255];
      } else bv = bias0[n];
      #pragma unroll
      for (int r=0;r<4;++r) {
        int mm = mbase + r;
        if (mm >= M) continue;
        float v = acc[i][j][r] + bv;
        if (flags & MF_GELU) v = 0.5f*v*(1.f + erff(v*0.70710678118654752f));
        if (Rp) {
          size_t ri = (size_t)mm*N + n;
          v += (flags & MF_RF32) ? ((const float*)Rp)[ri] : bf2f(((const bf16*)Rp)[ri]);
        }
        if (flags & MF_SPLIT) {
          size_t ci = (size_t)(n>>8)*splitStride + (size_t)mm*256 + (n & 255);
          ((bf16*)Cp)[ci] = __float2bfloat16(v);
        } else {
          size_t ci = (size_t)mm*N + n;
          if (flags & MF_CF32) ((float*)Cp)[ci] = v;
          else                 ((bf16*)Cp)[ci] = __float2bfloat16(v);
        }
      }
    }
  }
}

// ---------------------------------------------------------------------------
// Old fp32 VALU GEMM — tiny route GEMMs (M<=1920), fp32 in/out.
// ---------------------------------------------------------------------------
__global__ __launch_bounds__(256) void gemm_k(
    const void* __restrict__ Ap, const float* __restrict__ W,
    const float* __restrict__ bias, const void* __restrict__ Rp,
    void* __restrict__ Cp, int M, int N, int K, int flags)
{
  __shared__ float As[16][68];
  __shared__ float Ws[16][68];
  int tid = threadIdx.x;
  int tx = tid & 15, ty = tid >> 4;
  int m0 = blockIdx.y * 64, n0 = blockIdx.x * 64;
  float acc[4][4];
  #pragma unroll
  for (int i=0;i<4;i++)
    #pragma unroll
    for (int j=0;j<4;j++) acc[i][j]=0.f;

  for (int k0 = 0; k0 < K; k0 += 16) {
    #pragma unroll
    for (int i = 0; i < 4; ++i) {
      int idx = tid + i*256;
      int r = idx >> 4, c = idx & 15;
      int gr = m0 + r;
      float v = 0.f;
      if (gr < M) {
        size_t gi = (size_t)gr*K + (size_t)(k0 + c);
        v = (flags & GF_ABF16) ? bf2f(((const bf16*)Ap)[gi]) : ((const float*)Ap)[gi];
        if (flags & GF_LOGRELU) v = log1pf(fmaxf(v, 0.f));
      }
      As[c][r] = v;
    }
    #pragma unroll
    for (int i = 0; i < 4; ++i) {
      int idx = tid + i*256;
      int c = idx >> 6, j = idx & 63;
      Ws[c][j] = W[(size_t)(k0+c)*N + (size_t)(n0 + j)];
    }
    __syncthreads();
    #pragma unroll
    for (int k = 0; k < 16; ++k) {
      float a[4], b[4];
      #pragma unroll
      for (int i=0;i<4;i++) a[i] = As[k][ty*4+i];
      #pragma unroll
      for (int j=0;j<4;j++) b[j] = Ws[k][tx*4+j];
      #pragma unroll
      for (int i=0;i<4;i++)
        #pragma unroll
        for (int j=0;j<4;j++) acc[i][j] = fmaf(a[i], b[j], acc[i][j]);
    }
    __syncthreads();
  }
  #pragma unroll
  for (int i=0;i<4;i++) {
    int row = m0 + ty*4 + i;
    if (row >= M) continue;
    #pragma unroll
    for (int j=0;j<4;j++) {
      int col = n0 + tx*4 + j;
      float v = acc[i][j] + bias[col];
      if (flags & GF_GELU) v = 0.5f*v*(1.f + erff(v*0.70710678118654752f));
      if (Rp) {
        size_t ri = (size_t)row*N + col;
        v += (flags & GF_RBF16) ? bf2f(((const bf16*)Rp)[ri]) : ((const float*)Rp)[ri];
      }
      size_t ci = (size_t)row*N + col;
      if (flags & GF_CBF16) ((bf16*)Cp)[ci] = __float2bfloat16(v);
      else                  ((float*)Cp)[ci] = v;
    }
  }
}

// ---------------------------------------------------------------------------
// Temporal attention via MFMA. 4 waves/block, wave w owns pair p=bid*4+w
// (p = bv*8 + h). S=24 padded to 32, DH=32. In-place on Q.
// ---------------------------------------------------------------------------
__global__ __launch_bounds__(256) void attn1_k(bf16* __restrict__ Q,
                                               const bf16* __restrict__ Kb,
                                               const bf16* __restrict__ Vb)
{
  __shared__ __align__(16) unsigned short lds[4*4096];  // 32 KB
  int wave = threadIdx.x >> 6, lane = threadIdx.x & 63;
  int quad = lane >> 4, l16 = lane & 15;
  int p = blockIdx.x*4 + wave;          // bv*8 + h
  int bv = p >> 3, h = p & 7;
  const size_t base0 = ((size_t)bv*SS)*DD + h*32;

  int slab = wave*4096;
  int lQ = slab, lK = slab + 1024, lV = slab + 2048, lP = slab + 3072;

  // ---- stage Q,K,V (24 rows x 32 bf16 each) via global_load_lds w16 ----
  {
    int row0 = lane >> 2, c0 = (lane & 3)*8;          // it0: u = lane
    const bf16* gq = Q  + base0 + (size_t)row0*DD + c0;
    const bf16* gk = Kb + base0 + (size_t)row0*DD + c0;
    const bf16* gv = Vb + base0 + (size_t)row0*DD + c0;
    gl_lds16(gq, &lds[lQ]);
    gl_lds16(gk, &lds[lK]);
    gl_lds16(gv, &lds[lV]);
    if (lane < 32) {                                   // it1: u = 64+lane
      int row1 = 16 + (lane >> 2);
      const bf16* gq1 = Q  + base0 + (size_t)row1*DD + c0;
      const bf16* gk1 = Kb + base0 + (size_t)row1*DD + c0;
      const bf16* gv1 = Vb + base0 + (size_t)row1*DD + c0;
      gl_lds16(gq1, &lds[lQ + 512]);
      gl_lds16(gk1, &lds[lK + 512]);
      gl_lds16(gv1, &lds[lV + 512]);
    }
  }
  // zero V pad rows 24..31 (k-dim of PV MFMA must not contain NaN garbage)
  *(uint2*)&lds[lV + 768 + lane*4] = (uint2){0u,0u};

  asm volatile("s_waitcnt vmcnt(0)" ::: "memory");
  __builtin_amdgcn_sched_barrier(0);

  // ---- QK^T: 2x2 tiles of 16, K=32 ----
  short8 qa[2], kb[2];
  #pragma unroll
  for (int t=0;t<2;++t) {
    qa[t] = *(const short8*)&lds[lQ + (t*16 + l16)*32 + quad*8];
    kb[t] = *(const short8*)&lds[lK + (t*16 + l16)*32 + quad*8];
  }
  f32x4 scc[2][2];
  #pragma unroll
  for (int ti=0;ti<2;++ti)
    #pragma unroll
    for (int tj=0;tj<2;++tj)
      scc[ti][tj] = __builtin_amdgcn_mfma_f32_16x16x32_bf16(qa[ti], kb[tj],
                      (f32x4){0.f,0.f,0.f,0.f}, 0, 0, 0);
  // mask pad cols j=24..31 (tile tj=1, l16>=8) to -inf
  if (l16 >= 8) {
    scc[0][1] = (f32x4){-INFINITY,-INFINITY,-INFINITY,-INFINITY};
    scc[1][1] = (f32x4){-INFINITY,-INFINITY,-INFINITY,-INFINITY};
  }

  // ---- softmax over cols (row = quad*4+r+16*ti, cols across l16 x tj) ----
  #pragma unroll
  for (int ti=0;ti<2;++ti) {
    #pragma unroll
    for (int r=0;r<4;++r) {
      float mv = fmaxf(scc[ti][0][r], scc[ti][1][r]);
      #pragma unroll
      for (int off=1; off<16; off<<=1) mv = fmaxf(mv, __shfl_xor(mv, off));
      float e0 = expf((scc[ti][0][r]-mv)*SCALE);
      float e1 = expf((scc[ti][1][r]-mv)*SCALE);   // exp(-inf)=0 for pad cols
      float sm = e0 + e1;
      #pragma unroll
      for (int off=1; off<16; off<<=1) sm += __shfl_xor(sm, off);
      float inv = 1.f/sm;
      int row = ti*16 + quad*4 + r;
      lds[lP + row*32 + l16]      = f2bfbits(e0*inv);
      lds[lP + row*32 + 16 + l16] = f2bfbits(e1*inv);
    }
  }

  // ---- PV: O[24x32] = P[24x32pad] x V[32x32], 2x2 tiles ----
  f32x4 o[2][2];
  #pragma unroll
  for (int ti=0;ti<2;++ti) {
    short8 pa = *(const short8*)&lds[lP + (ti*16 + l16)*32 + quad*8];
    #pragma unroll
    for (int tn=0;tn<2;++tn) {
      unsigned short vt[8];
      #pragma unroll
      for (int e=0;e<8;++e) vt[e] = lds[lV + (quad*8+e)*32 + tn*16 + l16];
      short8 vb = *(short8*)vt;
      o[ti][tn] = __builtin_amdgcn_mfma_f32_16x16x32_bf16(pa, vb,
                    (f32x4){0.f,0.f,0.f,0.f}, 0, 0, 0);
    }
  }

  // ---- store (rows < 24 only), col = tn*16+l16 ----
  #pragma unroll
  for (int ti=0;ti<2;++ti) {
    #pragma unroll
    for (int r=0;r<4;++r) {
      int row = ti*16 + quad*4 + r;
      if (row < SS) {
        #pragma unroll
        for (int tn=0;tn<2;++tn)
          Q[base0 + (size_t)row*DD + tn*16 + l16] = __float2bfloat16(o[ti][tn][r]);
      }
    }
  }
}

// ---------------------------------------------------------------------------
// LayerNorm family
// ---------------------------------------------------------------------------
__global__ __launch_bounds__(256) void ln_k(const bf16* __restrict__ X, bf16* __restrict__ Y,
                                            const float* __restrict__ g, const float* __restrict__ b,
                                            int nrows)
{
  int row = blockIdx.x*4 + (threadIdx.x >> 6);
  int lane = threadIdx.x & 63;
  if (row >= nrows) return;
  const bf16* xr = X + (size_t)row*DD;
  int c = lane*4;
  float v0 = bf2f(xr[c+0]), v1 = bf2f(xr[c+1]), v2 = bf2f(xr[c+2]), v3 = bf2f(xr[c+3]);
  float s = v0+v1+v2+v3;
  #pragma unroll
  for (int off = 32; off; off >>= 1) s += __shfl_xor(s, off);
  float m = s * (1.f/256.f);
  float d0=v0-m, d1=v1-m, d2=v2-m, d3=v3-m;
  float q = d0*d0+d1*d1+d2*d2+d3*d3;
  #pragma unroll
  for (int off = 32; off; off >>= 1) q += __shfl_xor(q, off);
  float rstd = rsqrtf(q*(1.f/256.f) + 1e-5f);
  bf16* yr = Y + (size_t)row*DD;
  yr[c+0] = __float2bfloat16(d0*rstd*g[c+0] + b[c+0]);
  yr[c+1] = __float2bfloat16(d1*rstd*g[c+1] + b[c+1]);
  yr[c+2] = __float2bfloat16(d2*rstd*g[c+2] + b[c+2]);
  yr[c+3] = __float2bfloat16(d3*rstd*g[c+3] + b[c+3]);
}

// LN fused with (B,V,S,D)->(B,S,V,D) permute; also emits xl = log1p(relu(xd))
__global__ __launch_bounds__(256) void ln_t_k(const bf16* __restrict__ X, bf16* __restrict__ Y,
                                              bf16* __restrict__ Yl,
                                              const float* __restrict__ g, const float* __restrict__ b)
{
  int r1 = blockIdx.x*4 + (threadIdx.x >> 6);
  int lane = threadIdx.x & 63;
  if (r1 >= NROWS) return;
  const bf16* xr = X + (size_t)r1*DD;
  int c = lane*4;
  float v0 = bf2f(xr[c+0]), v1 = bf2f(xr[c+1]), v2 = bf2f(xr[c+2]), v3 = bf2f(xr[c+3]);
  float s = v0+v1+v2+v3;
  #pragma unroll
  for (int off = 32; off; off >>= 1) s += __shfl_xor(s, off);
  float m = s * (1.f/256.f);
  float d0=v0-m, d1=v1-m, d2=v2-m, d3=v3-m;
  float q = d0*d0+d1*d1+d2*d2+d3*d3;
  #pragma unroll
  for (int off = 32; off; off >>= 1) q += __shfl_xor(q, off);
  float rstd = rsqrtf(q*(1.f/256.f) + 1e-5f);
  int b_ = r1 / (VV*SS);
  int rem = r1 % (VV*SS);
  int v = rem / SS, ss = rem % SS;
  int r2 = (b_*SS + ss)*VV + v;
  float o0 = d0*rstd*g[c+0] + b[c+0];
  float o1 = d1*rstd*g[c+1] + b[c+1];
  float o2 = d2*rstd*g[c+2] + b[c+2];
  float o3 = d3*rstd*g[c+3] + b[c+3];
  bf16* yr = Y + (size_t)r2*DD;
  yr[c+0] = __float2bfloat16(o0);
  yr[c+1] = __float2bfloat16(o1);
  yr[c+2] = __float2bfloat16(o2);
  yr[c+3] = __float2bfloat16(o3);
  bf16* ylr = Yl + (size_t)r2*DD;
  ylr[c+0] = __float2bfloat16(log1pf(fmaxf(o0, 0.f)));
  ylr[c+1] = __float2bfloat16(log1pf(fmaxf(o1, 0.f)));
  ylr[c+2] = __float2bfloat16(log1pf(fmaxf(o2, 0.f)));
  ylr[c+3] = __float2bfloat16(log1pf(fmaxf(o3, 0.f)));
}

// Final LN + permute (B,S,V,D)->(B,V,S,D) + fp32 store
__global__ __launch_bounds__(256) void ln_out_k(const bf16* __restrict__ X, float* __restrict__ out,
                                                const float* __restrict__ g, const float* __restrict__ b)
{
  int row = blockIdx.x*4 + (threadIdx.x >> 6);
  int lane = threadIdx.x & 63;
  if (row >= NROWS) return;
  const bf16* xr = X + (size_t)row*DD;
  int c = lane*4;
  float v0 = bf2f(xr[c+0]), v1 = bf2f(xr[c+1]), v2 = bf2f(xr[c+2]), v3 = bf2f(xr[c+3]);
  float s = v0+v1+v2+v3;
  #pragma unroll
  for (int off = 32; off; off >>= 1) s += __shfl_xor(s, off);
  float m = s * (1.f/256.f);
  float d0=v0-m, d1=v1-m, d2=v2-m, d3=v3-m;
  float q = d0*d0+d1*d1+d2*d2+d3*d3;
  #pragma unroll
  for (int off = 32; off; off >>= 1) q += __shfl_xor(q, off);
  float rstd = rsqrtf(q*(1.f/256.f) + 1e-5f);
  int bs = row / VV, vv = row % VV;
  int bb = bs / SS, ss = bs % SS;
  float* op = out + (((size_t)bb*VV + vv)*SS + ss)*DD + c;
  op[0] = d0*rstd*g[c+0] + b[c+0];
  op[1] = d1*rstd*g[c+1] + b[c+1];
  op[2] = d2*rstd*g[c+2] + b[c+2];
  op[3] = d3*rstd*g[c+3] + b[c+3];
}

// ---------------------------------------------------------------------------
// Scores + top-33 (desc, ties -> lower index). One wave per (bs,h,g).
// ---------------------------------------------------------------------------
__global__ __launch_bounds__(64) void topk_k(const float* __restrict__ qS,
                                             const bf16* __restrict__ kS,
                                             int* __restrict__ idxOut)
{
  int bid = blockIdx.x;                // (bs*8+h)*10+g
  int g = bid % GG;
  int h = (bid / GG) % HH;
  int bs = bid / (GG*HH);
  int s = bs % SS;
  int lane = threadIdx.x;

  float qv[32];
  const float4* qp = (const float4*)(qS + ((size_t)(s*GG + g))*DD + h*32);
  #pragma unroll
  for (int e4 = 0; e4 < 8; ++e4) {
    float4 t = qp[e4];
    qv[e4*4+0]=t.x; qv[e4*4+1]=t.y; qv[e4*4+2]=t.z; qv[e4*4+3]=t.w;
  }

  float sc[6];
  #pragma unroll
  for (int j = 0; j < 6; ++j) {
    int v = lane + j*64;
    if (v < VV) {
      const uint4* kp = (const uint4*)(kS + ((size_t)bs*VV + v)*DD + h*32);
      float d = 0.f;
      #pragma unroll
      for (int cch = 0; cch < 4; ++cch) {
        uint4 u = kp[cch];
        const unsigned short* usp = (const unsigned short*)&u;
        #pragma unroll
        for (int e = 0; e < 8; ++e)
          d = fmaf(bfbits2f(usp[e]), qv[cch*8+e], d);
      }
      sc[j] = d * SCALE;
    } else sc[j] = -INFINITY;
  }

  for (int it = 0; it < KTOP; ++it) {
    float bv = sc[0]; int bj = 0;
    #pragma unroll
    for (int j = 1; j < 6; ++j) if (sc[j] > bv) { bv = sc[j]; bj = j; }
    int bi = lane + bj*64;
    #pragma unroll
    for (int off = 32; off; off >>= 1) {
      float ov = __shfl_down(bv, off);
      int   oi = __shfl_down(bi, off);
      if (ov > bv || (ov == bv && oi < bi)) { bv = ov; bi = oi; }
    }
    bi = __shfl(bi, 0);
    if (lane == 0) idxOut[(size_t)bid*KTOP + it] = bi;
    if ((bi & 63) == lane) {
      int jj = bi >> 6;
      #pragma unroll
      for (int j = 0; j < 6; ++j) if (jj == j) sc[j] = -INFINITY;
    }
  }
}

// ---------------------------------------------------------------------------
// Grouped conv + min/max/exp -> feat (bs,G,256) fp32
// ---------------------------------------------------------------------------
__global__ __launch_bounds__(256) void conv_k(const bf16* __restrict__ vS,
                                              const int* __restrict__ idx,
                                              const float* __restrict__ cw,
                                              const float* __restrict__ cb,
                                              float* __restrict__ feat)
{
  int bid = blockIdx.x;
  int bs = bid / GG, g = bid % GG;
  int tid = threadIdx.x;
  int h = tid >> 5, d = tid & 31;
  __shared__ float cws[KTOP];
  __shared__ int idl[HH][KTOP];
  __shared__ float ms[256];
  if (tid < KTOP) cws[tid] = cw[g*KTOP + tid];
  for (int i = tid; i < HH*KTOP; i += 256) {
    int hh = i / KTOP, k = i % KTOP;
    int ix = idx[(((size_t)bs*HH + hh)*GG + g)*KTOP + k];
    idl[hh][k] = (ix < 0) ? 0 : (ix >= VV ? VV-1 : ix);
  }
  __syncthreads();
  float acc = 0.f;
  #pragma unroll
  for (int k = 0; k < KTOP; ++k)
    acc += bf2f(vS[((size_t)bs*VV + idl[h][k])*DD + h*32 + d]) * cws[k];
  acc += cb[g];
  ms[tid] = acc;
  __syncthreads();
  float mn = acc, mx = acc;
  #pragma unroll
  for (int j = 0; j < 32; ++j) {
    float t = ms[h*32 + j];
    mn = fminf(mn, t); mx = fmaxf(mx, t);
  }
  float xn = expf((acc - mn) / fmaxf(mx - mn, 1e-6f));
  feat[((size_t)bs*GG + g)*DD + h*32 + d] = xn;
}

// ---------------------------------------------------------------------------
// Cross attention (route 2): 321 bf16 queries vs 10 fp32 keys per bs.
// ---------------------------------------------------------------------------
__global__ __launch_bounds__(256) void attn2_k(bf16* __restrict__ Q,
                                               const float* __restrict__ KR,
                                               const float* __restrict__ VR)
{
  int bs = blockIdx.x;
  int tid = threadIdx.x;
  __shared__ float kr[GG][DD], vr[GG][DD];
  for (int i = tid; i < GG*DD; i += 256) {
    int r = i >> 8, c = i & 255;
    kr[r][c] = KR[((size_t)bs*GG + r)*DD + c];
    vr[r][c] = VR[((size_t)bs*GG + r)*DD + c];
  }
  __syncthreads();
  for (int task = tid; task < VV*HH; task += 256) {
    int v = task >> 3, h = task & 7;
    bf16* qp = Q + ((size_t)bs*VV + v)*DD + h*32;
    float qr[32];
    #pragma unroll
    for (int d = 0; d < 32; ++d) qr[d] = bf2f(qp[d]);
    float sv[GG];
    float mx = -INFINITY;
    #pragma unroll
    for (int gi = 0; gi < GG; ++gi) {
      float dsum = 0.f;
      #pragma unroll
      for (int d = 0; d < 32; ++d) dsum += qr[d]*kr[gi][h*32+d];
      sv[gi] = dsum * SCALE;
      mx = fmaxf(mx, sv[gi]);
    }
    float ssum = 0.f;
    #pragma unroll
    for (int gi = 0; gi < GG; ++gi) { sv[gi] = expf(sv[gi]-mx); ssum += sv[gi]; }
    float inv = 1.f/ssum;
    float o[32];
    #pragma unroll
    for (int d = 0; d < 32; ++d) o[d] = 0.f;
    #pragma unroll
    for (int gi = 0; gi < GG; ++gi) {
      float p = sv[gi]*inv;
      #pragma unroll
      for (int d = 0; d < 32; ++d) o[d] += p*vr[gi][h*32+d];
    }
    #pragma unroll
    for (int d = 0; d < 32; ++d) qp[d] = __float2bfloat16(o[d]);
  }
}

// ---------------------------------------------------------------------------
extern "C" void kernel_launch(void* const* d_in, const int* in_sizes, int n_in,
                              void* d_out, int out_size, void* d_ws, size_t ws_size,
                              hipStream_t stream)
{
  const float* queries=(const float*)d_in[0];
  const float* t_wq=(const float*)d_in[1];  const float* t_bq=(const float*)d_in[2];
  const float* t_wk=(const float*)d_in[3];  const float* t_bk=(const float*)d_in[4];
  const float* t_wv=(const float*)d_in[5];  const float* t_bv=(const float*)d_in[6];
  const float* t_wo=(const float*)d_in[7];  const float* t_bo=(const float*)d_in[8];
  const float* s_wq=(const float*)d_in[9];  const float* s_bq=(const float*)d_in[10];
  const float* s_wk=(const float*)d_in[11]; const float* s_bk=(const float*)d_in[12];
  const float* s_wv=(const float*)d_in[13]; const float* s_bv=(const float*)d_in[14];
  const float* s_wo=(const float*)d_in[15]; const float* s_bo=(const float*)d_in[16];
  const float* cluster=(const float*)d_in[17];
  const float* conv_w=(const float*)d_in[18]; const float* conv_b=(const float*)d_in[19];
  const float* r_wq=(const float*)d_in[20]; const float* r_bq=(const float*)d_in[21];
  const float* r_wk=(const float*)d_in[22]; const float* r_bk=(const float*)d_in[23];
  const float* r_wv=(const float*)d_in[24]; const float* r_bv=(const float*)d_in[25];
  const float* r_wo=(const float*)d_in[26]; const float* r_bo=(const float*)d_in[27];
  const float* ln_t1_g=(const float*)d_in[28]; const float* ln_t1_b=(const float*)d_in[29];
  const float* ln_t2_g=(const float*)d_in[30]; const float* ln_t2_b=(const float*)d_in[31];
  const float* ln_d1_g=(const float*)d_in[32]; const float* ln_d1_b=(const float*)d_in[33];
  const float* ln_d2_g=(const float*)d_in[34]; const float* ln_d2_b=(const float*)d_in[35];
  const float* ft_w1=(const float*)d_in[36]; const float* ft_b1=(const float*)d_in[37];
  const float* ft_w2=(const float*)d_in[38]; const float* ft_b2=(const float*)d_in[39];
  const float* fd_w1=(const float*)d_in[40]; const float* fd_b1=(const float*)d_in[41];
  const float* fd_w2=(const float*)d_in[42]; const float* fd_b2=(const float*)d_in[43];

  // Workspace: 4 big bf16 buffers (126 MB) + W^T pool (3 MB) + smalls (~10 MB)
  bf16* Ab = (bf16*)d_ws;
  bf16* Bb = Ab + NE;
  bf16* Cb = Bb + NE;
  bf16* Db = Cb + NE;                       // queries-bf16 (route1) / xl (route2)
  bf16* WP = Db + NE;                       // 1572864 bf16
  float* QSf   = (float*)(WP + 1572864);
  float* FEATf = QSf + 240*256;
  float* ROUTEf= FEATf + 1920*256;
  float* KRf   = ROUTEf + 1920*256;
  float* VRf   = KRf + 1920*256;
  int*   IDXb  = (int*)(VRf + 1920*256);

  // ---- weight prep ----
  WPrep wp;
  const float* wsrc[12] = {t_wq,t_wk,t_wv,t_wo,s_wk,s_wv,r_wq,r_wo,ft_w1,ft_w2,fd_w1,fd_w2};
  int wK[12] = {256,256,256,256,256,256,256,256,256,1024,256,1024};
  int wN[12] = {256,256,256,256,256,256,256,256,1024,256,1024,256};
  int off = 0, toff = 0;
  for (int i=0;i<12;++i) {
    wp.src[i]=wsrc[i]; wp.K[i]=wK[i]; wp.N[i]=wN[i];
    wp.dstoff[i]=off; wp.tileoff[i]=toff;
    off += wK[i]*wN[i];
    toff += (wK[i]/32)*(wN[i]/32);
  }
  wp.tileoff[12]=toff;
  prep_w_k<<<toff, 256, 0, stream>>>(wp, WP);
  bf16* Wqkv=WP+wp.dstoff[0];               // [768][256]
  bf16* Wo=WP+wp.dstoff[3];
  bf16* Wskv=WP+wp.dstoff[4];               // [512][256]
  bf16* Wrq=WP+wp.dstoff[6]; bf16* Wro=WP+wp.dstoff[7];
  bf16* Wf1=WP+wp.dstoff[8]; bf16* Wf2=WP+wp.dstoff[9];
  bf16* Wd1=WP+wp.dstoff[10]; bf16* Wd2=WP+wp.dstoff[11];

  dim3 blk(256);
  const int STRIPE = NROWS/4;               // 15408
  dim3 gQKV(6, (NROWS+127)/128);
  dim3 gKV(4, (NROWS+127)/128);
  dim3 gBig(2, (NROWS+127)/128);
  dim3 gS1(8, (STRIPE+127)/128);
  dim3 gS2(2, (STRIPE+127)/128);
  dim3 gQ(4, 4);
  dim3 gSmall(4, 30);
  const int GCVT = (int)(NE/2048);          // 7704

  // ---- Route 1: temporal ----
  f2b_k<<<GCVT, blk, 0, stream>>>(queries, Db, NE);
  mgemm_k<<<gQKV, blk, 0, stream>>>(Db, Wqkv, t_bq, t_bk, t_bv, nullptr, Ab,
                                    NROWS, 768, 256, MF_SPLIT, NE);           // Q->Ab K->Bb V->Cb
  attn1_k<<<(BV*HH)/4, blk, 0, stream>>>(Ab, Bb, Cb);                         // O -> Ab
  mgemm_k<<<gBig, blk, 0, stream>>>(Ab, Wo, t_bo, nullptr, nullptr, queries, Bb,
                                    NROWS, 256, 256, MF_RF32, 0);
  ln_k<<<NROWS/4, blk, 0, stream>>>(Bb, Ab, ln_t1_g, ln_t1_b, NROWS);
  for (int st = 0; st < 4; ++st) {
    size_t ro = (size_t)st * STRIPE * DD;
    mgemm_k<<<gS1, blk, 0, stream>>>(Ab + ro, Wf1, ft_b1, nullptr, nullptr, nullptr, Cb,
                                     STRIPE, 1024, 256, MF_GELU, 0);
    mgemm_k<<<gS2, blk, 0, stream>>>(Cb, Wf2, ft_b2, nullptr, nullptr, Ab + ro, Bb + ro,
                                     STRIPE, 256, 1024, 0, 0);
  }
  ln_t_k<<<NROWS/4, blk, 0, stream>>>(Bb, Ab, Db, ln_t2_g, ln_t2_b);          // xd -> Ab, xl -> Db

  // ---- Route 2: dimensional ----
  mgemm_k<<<gKV, blk, 0, stream>>>(Db, Wskv, s_bk, s_bv, nullptr, nullptr, Bb,
                                   NROWS, 512, 256, MF_SPLIT, NE);            // kS->Bb vS->Cb
  gemm_k<<<gQ, blk, 0, stream>>>(cluster, s_wq, s_bq, nullptr, QSf, 240, 256, 256, 0);
  topk_k<<<BSEG*HH*GG, 64, 0, stream>>>(QSf, Bb, IDXb);
  conv_k<<<BSEG*GG, blk, 0, stream>>>(Cb, IDXb, conv_w, conv_b, FEATf);
  gemm_k<<<gSmall, blk, 0, stream>>>(FEATf, s_wo, s_bo, nullptr, ROUTEf, 1920, 256, 256, 0);
  gemm_k<<<gSmall, blk, 0, stream>>>(ROUTEf, r_wk, r_bk, nullptr, KRf, 1920, 256, 256, 0);
  gemm_k<<<gSmall, blk, 0, stream>>>(ROUTEf, r_wv, r_bv, nullptr, VRf, 1920, 256, 256, 0);
  mgemm_k<<<gBig, blk, 0, stream>>>(Ab, Wrq, r_bq, nullptr, nullptr, nullptr, Bb,
                                    NROWS, 256, 256, 0, 0);                   // qD -> Bb
  attn2_k<<<BSEG, blk, 0, stream>>>(Bb, KRf, VRf);                            // O -> Bb
  mgemm_k<<<gBig, blk, 0, stream>>>(Bb, Wro, r_bo, nullptr, nullptr, Ab, Cb,
                                    NROWS, 256, 256, 0, 0);                   // + xd -> Cb
  ln_k<<<NROWS/4, blk, 0, stream>>>(Cb, Ab, ln_d1_g, ln_d1_b, NROWS);
  for (int st = 0; st < 4; ++st) {
    size_t ro = (size_t)st * STRIPE * DD;
    mgemm_k<<<gS1, blk, 0, stream>>>(Ab + ro, Wd1, fd_b1, nullptr, nullptr, nullptr, Bb,
                                     STRIPE, 1024, 256, MF_GELU, 0);
    mgemm_k<<<gS2, blk, 0, stream>>>(Bb, Wd2, fd_b2, nullptr, nullptr, Ab + ro, Cb + ro,
                                     STRIPE, 256, 1024, 0, 0);
  }
  ln_out_k<<<NROWS/4, blk, 0, stream>>>(Cb, (float*)d_out, ln_d2_g, ln_d2_b);
}

// Round 9
// 1697.635 us; speedup vs baseline: 1.0239x; 1.0205x over previous
//
#include <hip/hip_runtime.h>
#include <hip/hip_bf16.h>
#include <cmath>

typedef __hip_bfloat16 bf16;
typedef __attribute__((ext_vector_type(8))) short short8;
typedef __attribute__((ext_vector_type(4))) float f32x4;
typedef unsigned int u32;
typedef __attribute__((address_space(3))) u32 lds_u32;
typedef const __attribute__((address_space(1))) u32 glob_u32;

#define BB 8
#define VV 321
#define SS 24
#define DD 256
#define HH 8
#define GG 10
#define KTOP 33
#define DFFN 1024
#define BV (BB*VV)            // 2568
#define BSEG (BB*SS)          // 192
#define NROWS (BV*SS)         // 61632
#define NE ((size_t)NROWS*DD) // 15777792
#define SCALE 0.17677669529663687f  // 1/sqrt(32)

enum { GF_GELU=1, GF_LOGRELU=2, GF_ABF16=4, GF_RBF16=8, GF_CBF16=16 };
enum { MF_GELU=1, MF_RF32=8, MF_CF32=16, MF_SPLIT=32, MF_SWZ=64 };

__device__ __forceinline__ float bf2f(bf16 x){ return __bfloat162float(x); }
__device__ __forceinline__ unsigned short f2bfbits(float f){
  bf16 h = __float2bfloat16(f);
  return *(unsigned short*)&h;
}
__device__ __forceinline__ float bfbits2f(unsigned int u){
  bf16 h; *(unsigned short*)&h = (unsigned short)u; return __bfloat162float(h);
}
__device__ __forceinline__ void ld4bf(const bf16* p, float* f){
  uint2 u = *(const uint2*)p;
  f[0]=bfbits2f(u.x&0xffff); f[1]=bfbits2f(u.x>>16);
  f[2]=bfbits2f(u.y&0xffff); f[3]=bfbits2f(u.y>>16);
}
__device__ __forceinline__ void st4bf(bf16* p, const float* f){
  uint2 u;
  u.x = (unsigned)f2bfbits(f[0]) | ((unsigned)f2bfbits(f[1])<<16);
  u.y = (unsigned)f2bfbits(f[2]) | ((unsigned)f2bfbits(f[3])<<16);
  *(uint2*)p = u;
}
// async 16B global -> LDS (wave-uniform LDS base + lane*16)
__device__ __forceinline__ void gl_lds16(const void* g, void* l){
  __builtin_amdgcn_global_load_lds((glob_u32*)g, (lds_u32*)l, 16, 0, 0);
}

// ---------------------------------------------------------------------------
// Weight prep: fp32 W[K][N] -> bf16 W^T[N][K] into pool. 32x32 tiles via LDS.
// ---------------------------------------------------------------------------
struct WPrep {
  const float* src[12];
  int K[12], N[12], dstoff[12], tileoff[13];
};

__global__ __launch_bounds__(256) void prep_w_k(WPrep p, bf16* __restrict__ pool)
{
  __shared__ float t[32][33];
  int b = blockIdx.x;
  int m = 0;
  while (b >= p.tileoff[m+1]) ++m;
  int tt = b - p.tileoff[m];
  int K = p.K[m], N = p.N[m];
  int nc = N >> 5;
  int tr = tt / nc, tc = tt % nc;
  const float* src = p.src[m];
  int tid = threadIdx.x;
  int r = tid >> 3, c = (tid & 7) * 4;
  float4 v = *(const float4*)&src[(size_t)(tr*32 + r)*N + tc*32 + c];
  t[r][c+0]=v.x; t[r][c+1]=v.y; t[r][c+2]=v.z; t[r][c+3]=v.w;
  __syncthreads();
  bf16* dst = pool + p.dstoff[m];
  size_t base = (size_t)(tc*32 + r)*K + tr*32 + c;
  #pragma unroll
  for (int i=0;i<4;++i) dst[base+i] = __float2bfloat16(t[c+i][r]);
}

// ---------------------------------------------------------------------------
// fp32 -> bf16 bulk convert (8 elems/thread)
// ---------------------------------------------------------------------------
__global__ __launch_bounds__(256) void f2b_k(const float* __restrict__ X, bf16* __restrict__ Y, size_t n)
{
  size_t i = ((size_t)blockIdx.x*256 + threadIdx.x)*8;
  if (i >= n) return;
  float4 a = *(const float4*)(X+i);
  float4 b = *(const float4*)(X+i+4);
  unsigned short v[8] = {f2bfbits(a.x),f2bfbits(a.y),f2bfbits(a.z),f2bfbits(a.w),
                         f2bfbits(b.x),f2bfbits(b.y),f2bfbits(b.z),f2bfbits(b.w)};
  *(uint4*)(Y+i) = *(uint4*)v;
}

// ---------------------------------------------------------------------------
// MFMA GEMM v7: BK=32 double-buffer (round-4 proven skeleton, 32 KB LDS)
// + CONDITIONAL XCD-bijective swizzle (MF_SWZ): measured r4-vs-r8 A/B shows
// swizzle HURTS the QKV shape (101->141us despite FETCH 95.8->20.6MB) but
// helps the other 12 mgemm dispatches by ~45us net. Flag-gated per call.
// ---------------------------------------------------------------------------
__global__ __launch_bounds__(256) void mgemm_k(
    const bf16* __restrict__ Ap, const bf16* __restrict__ Wt,
    const float* __restrict__ bias0, const float* __restrict__ bias1,
    const float* __restrict__ bias2, const void* __restrict__ Rp,
    void* __restrict__ Cp, int M, int N, int K, int flags, size_t splitStride)
{
  __shared__ __align__(16) unsigned short As[2][128*32];
  __shared__ __align__(16) unsigned short Bs[2][128*32];
  int tid = threadIdx.x;
  int wave = tid >> 6, lane = tid & 63;
  int quad = lane >> 4, l16 = lane & 15;
  int wr = wave >> 1, wc = wave & 1;

  int nwgx = gridDim.x;
  int b    = blockIdx.y * nwgx + blockIdx.x;
  int wgid = b;
  if (flags & MF_SWZ) {
    int nwg = nwgx * gridDim.y;
    int q8 = nwg >> 3, r8 = nwg & 7;
    int xcd = b & 7, slot = b >> 3;
    wgid = (xcd < r8 ? xcd*(q8+1) : r8*(q8+1) + (xcd-r8)*q8) + slot;
  }
  int m0 = (wgid / nwgx) * 128, n0 = (wgid % nwgx) * 128;

  f32x4 acc[4][4];
  #pragma unroll
  for (int i=0;i<4;++i)
    #pragma unroll
    for (int j=0;j<4;++j) acc[i][j] = (f32x4){0.f,0.f,0.f,0.f};

  // staging coords: wave w covers tile rows 32w..32w+31 (two 1KB chunks)
  int r0 = wave*32 + (lane>>2);            // chunk 0 row
  int r1 = r0 + 16;                        // chunk 1 row
  int kc = (lane&3)*8;                     // k elem offset within tile
  int gm0 = m0 + r0; if (gm0 >= M) gm0 = M-1;
  int gm1 = m0 + r1; if (gm1 >= M) gm1 = M-1;
  const bf16* gA0 = Ap + (size_t)gm0*K + kc;
  const bf16* gA1 = Ap + (size_t)gm1*K + kc;
  const bf16* gB0 = Wt + (size_t)(n0 + r0)*K + kc;
  const bf16* gB1 = Wt + (size_t)(n0 + r1)*K + kc;

  // prologue: stage tile 0 into buf 0, barrier (drains vmcnt)
  gl_lds16(gA0, &As[0][wave*1024]);
  gl_lds16(gA1, &As[0][wave*1024 + 512]);
  gl_lds16(gB0, &Bs[0][wave*1024]);
  gl_lds16(gB1, &Bs[0][wave*1024 + 512]);
  __syncthreads();

  int cur = 0;
  for (int k0 = 0; k0 < K; k0 += 32) {
    // issue next tile's loads first (overlap HBM latency with compute below)
    if (k0 + 32 < K) {
      int nxt = cur ^ 1;
      gl_lds16(gA0 + k0 + 32, &As[nxt][wave*1024]);
      gl_lds16(gA1 + k0 + 32, &As[nxt][wave*1024 + 512]);
      gl_lds16(gB0 + k0 + 32, &Bs[nxt][wave*1024]);
      gl_lds16(gB1 + k0 + 32, &Bs[nxt][wave*1024 + 512]);
    }
    short8 a[4], bb[4];
    #pragma unroll
    for (int i=0;i<4;++i)
      a[i] = *(const short8*)&As[cur][(wr*64 + i*16 + l16)*32 + quad*8];
    #pragma unroll
    for (int j=0;j<4;++j)
      bb[j] = *(const short8*)&Bs[cur][(wc*64 + j*16 + l16)*32 + quad*8];
    #pragma unroll
    for (int i=0;i<4;++i)
      #pragma unroll
      for (int j=0;j<4;++j)
        acc[i][j] = __builtin_amdgcn_mfma_f32_16x16x32_bf16(a[i], bb[j], acc[i][j], 0, 0, 0);
    __syncthreads();   // drains vmcnt (next tile landed) + all reads of buf[cur] done
    cur ^= 1;
  }

  // ---- epilogue: D[row=quad*4+r][col=l16] per 16x16 tile ----
  #pragma unroll
  for (int i=0;i<4;++i) {
    int mbase = m0 + wr*64 + i*16 + quad*4;
    #pragma unroll
    for (int j=0;j<4;++j) {
      int n = n0 + wc*64 + j*16 + l16;
      float bv;
      if (flags & MF_SPLIT) {
        int sel = n >> 8;
        const float* bp = (sel==0) ? bias0 : (sel==1 ? bias1 : bias2);
        bv = bp[n & 255];
      } else bv = bias0[n];
      #pragma unroll
      for (int r=0;r<4;++r) {
        int mm = mbase + r;
        if (mm >= M) continue;
        float v = acc[i][j][r] + bv;
        if (flags & MF_GELU) v = 0.5f*v*(1.f + erff(v*0.70710678118654752f));
        if (Rp) {
          size_t ri = (size_t)mm*N + n;
          v += (flags & MF_RF32) ? ((const float*)Rp)[ri] : bf2f(((const bf16*)Rp)[ri]);
        }
        if (flags & MF_SPLIT) {
          size_t ci = (size_t)(n>>8)*splitStride + (size_t)mm*256 + (n & 255);
          ((bf16*)Cp)[ci] = __float2bfloat16(v);
        } else {
          size_t ci = (size_t)mm*N + n;
          if (flags & MF_CF32) ((float*)Cp)[ci] = v;
          else                 ((bf16*)Cp)[ci] = __float2bfloat16(v);
        }
      }
    }
  }
}

// ---------------------------------------------------------------------------
// Old fp32 VALU GEMM — tiny route GEMMs (M<=1920), fp32 in/out.
// ---------------------------------------------------------------------------
__global__ __launch_bounds__(256) void gemm_k(
    const void* __restrict__ Ap, const float* __restrict__ W,
    const float* __restrict__ bias, const void* __restrict__ Rp,
    void* __restrict__ Cp, int M, int N, int K, int flags)
{
  __shared__ float As[16][68];
  __shared__ float Ws[16][68];
  int tid = threadIdx.x;
  int tx = tid & 15, ty = tid >> 4;
  int m0 = blockIdx.y * 64, n0 = blockIdx.x * 64;
  float acc[4][4];
  #pragma unroll
  for (int i=0;i<4;i++)
    #pragma unroll
    for (int j=0;j<4;j++) acc[i][j]=0.f;

  for (int k0 = 0; k0 < K; k0 += 16) {
    #pragma unroll
    for (int i = 0; i < 4; ++i) {
      int idx = tid + i*256;
      int r = idx >> 4, c = idx & 15;
      int gr = m0 + r;
      float v = 0.f;
      if (gr < M) {
        size_t gi = (size_t)gr*K + (size_t)(k0 + c);
        v = (flags & GF_ABF16) ? bf2f(((const bf16*)Ap)[gi]) : ((const float*)Ap)[gi];
        if (flags & GF_LOGRELU) v = log1pf(fmaxf(v, 0.f));
      }
      As[c][r] = v;
    }
    #pragma unroll
    for (int i = 0; i < 4; ++i) {
      int idx = tid + i*256;
      int c = idx >> 6, j = idx & 63;
      Ws[c][j] = W[(size_t)(k0+c)*N + (size_t)(n0 + j)];
    }
    __syncthreads();
    #pragma unroll
    for (int k = 0; k < 16; ++k) {
      float a[4], b[4];
      #pragma unroll
      for (int i=0;i<4;i++) a[i] = As[k][ty*4+i];
      #pragma unroll
      for (int j=0;j<4;j++) b[j] = Ws[k][tx*4+j];
      #pragma unroll
      for (int i=0;i<4;i++)
        #pragma unroll
        for (int j=0;j<4;j++) acc[i][j] = fmaf(a[i], b[j], acc[i][j]);
    }
    __syncthreads();
  }
  #pragma unroll
  for (int i=0;i<4;i++) {
    int row = m0 + ty*4 + i;
    if (row >= M) continue;
    #pragma unroll
    for (int j=0;j<4;j++) {
      int col = n0 + tx*4 + j;
      float v = acc[i][j] + bias[col];
      if (flags & GF_GELU) v = 0.5f*v*(1.f + erff(v*0.70710678118654752f));
      if (Rp) {
        size_t ri = (size_t)row*N + col;
        v += (flags & GF_RBF16) ? bf2f(((const bf16*)Rp)[ri]) : ((const float*)Rp)[ri];
      }
      size_t ci = (size_t)row*N + col;
      if (flags & GF_CBF16) ((bf16*)Cp)[ci] = __float2bfloat16(v);
      else                  ((float*)Cp)[ci] = v;
    }
  }
}

// ---------------------------------------------------------------------------
// Temporal attention via MFMA. 4 waves/block, wave w owns pair p=bid*4+w
// (p = bv*8 + h). S=24 padded to 32, DH=32. In-place on Q.
// ---------------------------------------------------------------------------
__global__ __launch_bounds__(256) void attn1_k(bf16* __restrict__ Q,
                                               const bf16* __restrict__ Kb,
                                               const bf16* __restrict__ Vb)
{
  __shared__ __align__(16) unsigned short lds[4*4096];  // 32 KB
  int wave = threadIdx.x >> 6, lane = threadIdx.x & 63;
  int quad = lane >> 4, l16 = lane & 15;
  int p = blockIdx.x*4 + wave;          // bv*8 + h
  int bv = p >> 3, h = p & 7;
  const size_t base0 = ((size_t)bv*SS)*DD + h*32;

  int slab = wave*4096;
  int lQ = slab, lK = slab + 1024, lV = slab + 2048, lP = slab + 3072;

  // ---- stage Q,K,V (24 rows x 32 bf16 each) via global_load_lds w16 ----
  {
    int row0 = lane >> 2, c0 = (lane & 3)*8;          // it0: u = lane
    const bf16* gq = Q  + base0 + (size_t)row0*DD + c0;
    const bf16* gk = Kb + base0 + (size_t)row0*DD + c0;
    const bf16* gv = Vb + base0 + (size_t)row0*DD + c0;
    gl_lds16(gq, &lds[lQ]);
    gl_lds16(gk, &lds[lK]);
    gl_lds16(gv, &lds[lV]);
    if (lane < 32) {                                   // it1: u = 64+lane
      int row1 = 16 + (lane >> 2);
      const bf16* gq1 = Q  + base0 + (size_t)row1*DD + c0;
      const bf16* gk1 = Kb + base0 + (size_t)row1*DD + c0;
      const bf16* gv1 = Vb + base0 + (size_t)row1*DD + c0;
      gl_lds16(gq1, &lds[lQ + 512]);
      gl_lds16(gk1, &lds[lK + 512]);
      gl_lds16(gv1, &lds[lV + 512]);
    }
  }
  // zero V pad rows 24..31 (k-dim of PV MFMA must not contain NaN garbage)
  *(uint2*)&lds[lV + 768 + lane*4] = (uint2){0u,0u};

  asm volatile("s_waitcnt vmcnt(0)" ::: "memory");
  __builtin_amdgcn_sched_barrier(0);

  // ---- QK^T: 2x2 tiles of 16, K=32 ----
  short8 qa[2], kb[2];
  #pragma unroll
  for (int t=0;t<2;++t) {
    qa[t] = *(const short8*)&lds[lQ + (t*16 + l16)*32 + quad*8];
    kb[t] = *(const short8*)&lds[lK + (t*16 + l16)*32 + quad*8];
  }
  f32x4 scc[2][2];
  #pragma unroll
  for (int ti=0;ti<2;++ti)
    #pragma unroll
    for (int tj=0;tj<2;++tj)
      scc[ti][tj] = __builtin_amdgcn_mfma_f32_16x16x32_bf16(qa[ti], kb[tj],
                      (f32x4){0.f,0.f,0.f,0.f}, 0, 0, 0);
  // mask pad cols j=24..31 (tile tj=1, l16>=8) to -inf
  if (l16 >= 8) {
    scc[0][1] = (f32x4){-INFINITY,-INFINITY,-INFINITY,-INFINITY};
    scc[1][1] = (f32x4){-INFINITY,-INFINITY,-INFINITY,-INFINITY};
  }

  // ---- softmax over cols (row = quad*4+r+16*ti, cols across l16 x tj) ----
  #pragma unroll
  for (int ti=0;ti<2;++ti) {
    #pragma unroll
    for (int r=0;r<4;++r) {
      float mv = fmaxf(scc[ti][0][r], scc[ti][1][r]);
      #pragma unroll
      for (int off=1; off<16; off<<=1) mv = fmaxf(mv, __shfl_xor(mv, off));
      float e0 = expf((scc[ti][0][r]-mv)*SCALE);
      float e1 = expf((scc[ti][1][r]-mv)*SCALE);   // exp(-inf)=0 for pad cols
      float sm = e0 + e1;
      #pragma unroll
      for (int off=1; off<16; off<<=1) sm += __shfl_xor(sm, off);
      float inv = 1.f/sm;
      int row = ti*16 + quad*4 + r;
      lds[lP + row*32 + l16]      = f2bfbits(e0*inv);
      lds[lP + row*32 + 16 + l16] = f2bfbits(e1*inv);
    }
  }

  // ---- PV: O[24x32] = P[24x32pad] x V[32x32], 2x2 tiles ----
  f32x4 o[2][2];
  #pragma unroll
  for (int ti=0;ti<2;++ti) {
    short8 pa = *(const short8*)&lds[lP + (ti*16 + l16)*32 + quad*8];
    #pragma unroll
    for (int tn=0;tn<2;++tn) {
      unsigned short vt[8];
      #pragma unroll
      for (int e=0;e<8;++e) vt[e] = lds[lV + (quad*8+e)*32 + tn*16 + l16];
      short8 vb = *(short8*)vt;
      o[ti][tn] = __builtin_amdgcn_mfma_f32_16x16x32_bf16(pa, vb,
                    (f32x4){0.f,0.f,0.f,0.f}, 0, 0, 0);
    }
  }

  // ---- store (rows < 24 only), col = tn*16+l16 ----
  #pragma unroll
  for (int ti=0;ti<2;++ti) {
    #pragma unroll
    for (int r=0;r<4;++r) {
      int row = ti*16 + quad*4 + r;
      if (row < SS) {
        #pragma unroll
        for (int tn=0;tn<2;++tn)
          Q[base0 + (size_t)row*DD + tn*16 + l16] = __float2bfloat16(o[ti][tn][r]);
      }
    }
  }
}

// ---------------------------------------------------------------------------
// LayerNorm family (G13: vectorized bf16 loads/stores, float4 g/b)
// ---------------------------------------------------------------------------
__global__ __launch_bounds__(256) void ln_k(const bf16* __restrict__ X, bf16* __restrict__ Y,
                                            const float* __restrict__ g, const float* __restrict__ b,
                                            int nrows)
{
  int row = blockIdx.x*4 + (threadIdx.x >> 6);
  int lane = threadIdx.x & 63;
  if (row >= nrows) return;
  const bf16* xr = X + (size_t)row*DD;
  int c = lane*4;
  float v[4]; ld4bf(xr + c, v);
  float s = v[0]+v[1]+v[2]+v[3];
  #pragma unroll
  for (int off = 32; off; off >>= 1) s += __shfl_xor(s, off);
  float m = s * (1.f/256.f);
  float d0=v[0]-m, d1=v[1]-m, d2=v[2]-m, d3=v[3]-m;
  float q = d0*d0+d1*d1+d2*d2+d3*d3;
  #pragma unroll
  for (int off = 32; off; off >>= 1) q += __shfl_xor(q, off);
  float rstd = rsqrtf(q*(1.f/256.f) + 1e-5f);
  float4 gv = *(const float4*)(g + c);
  float4 bv = *(const float4*)(b + c);
  float o[4] = {d0*rstd*gv.x + bv.x, d1*rstd*gv.y + bv.y,
                d2*rstd*gv.z + bv.z, d3*rstd*gv.w + bv.w};
  st4bf(Y + (size_t)row*DD + c, o);
}

// LN fused with (B,V,S,D)->(B,S,V,D) permute; also emits xl = log1p(relu(xd))
__global__ __launch_bounds__(256) void ln_t_k(const bf16* __restrict__ X, bf16* __restrict__ Y,
                                              bf16* __restrict__ Yl,
                                              const float* __restrict__ g, const float* __restrict__ b)
{
  int r1 = blockIdx.x*4 + (threadIdx.x >> 6);
  int lane = threadIdx.x & 63;
  if (r1 >= NROWS) return;
  const bf16* xr = X + (size_t)r1*DD;
  int c = lane*4;
  float v[4]; ld4bf(xr + c, v);
  float s = v[0]+v[1]+v[2]+v[3];
  #pragma unroll
  for (int off = 32; off; off >>= 1) s += __shfl_xor(s, off);
  float m = s * (1.f/256.f);
  float d0=v[0]-m, d1=v[1]-m, d2=v[2]-m, d3=v[3]-m;
  float q = d0*d0+d1*d1+d2*d2+d3*d3;
  #pragma unroll
  for (int off = 32; off; off >>= 1) q += __shfl_xor(q, off);
  float rstd = rsqrtf(q*(1.f/256.f) + 1e-5f);
  int b_ = r1 / (VV*SS);
  int rem = r1 % (VV*SS);
  int vv = rem / SS, ss = rem % SS;
  int r2 = (b_*SS + ss)*VV + vv;
  float4 gv = *(const float4*)(g + c);
  float4 bvv = *(const float4*)(b + c);
  float o[4] = {d0*rstd*gv.x + bvv.x, d1*rstd*gv.y + bvv.y,
                d2*rstd*gv.z + bvv.z, d3*rstd*gv.w + bvv.w};
  st4bf(Y + (size_t)r2*DD + c, o);
  float ol[4] = {log1pf(fmaxf(o[0],0.f)), log1pf(fmaxf(o[1],0.f)),
                 log1pf(fmaxf(o[2],0.f)), log1pf(fmaxf(o[3],0.f))};
  st4bf(Yl + (size_t)r2*DD + c, ol);
}

// Final LN + permute (B,S,V,D)->(B,V,S,D) + fp32 store
__global__ __launch_bounds__(256) void ln_out_k(const bf16* __restrict__ X, float* __restrict__ out,
                                                const float* __restrict__ g, const float* __restrict__ b)
{
  int row = blockIdx.x*4 + (threadIdx.x >> 6);
  int lane = threadIdx.x & 63;
  if (row >= NROWS) return;
  const bf16* xr = X + (size_t)row*DD;
  int c = lane*4;
  float v[4]; ld4bf(xr + c, v);
  float s = v[0]+v[1]+v[2]+v[3];
  #pragma unroll
  for (int off = 32; off; off >>= 1) s += __shfl_xor(s, off);
  float m = s * (1.f/256.f);
  float d0=v[0]-m, d1=v[1]-m, d2=v[2]-m, d3=v[3]-m;
  float q = d0*d0+d1*d1+d2*d2+d3*d3;
  #pragma unroll
  for (int off = 32; off; off >>= 1) q += __shfl_xor(q, off);
  float rstd = rsqrtf(q*(1.f/256.f) + 1e-5f);
  int bs = row / VV, vv = row % VV;
  int bb = bs / SS, ss = bs % SS;
  float* op = out + (((size_t)bb*VV + vv)*SS + ss)*DD + c;
  float4 gv = *(const float4*)(g + c);
  float4 bv = *(const float4*)(b + c);
  float4 ov = {d0*rstd*gv.x + bv.x, d1*rstd*gv.y + bv.y,
               d2*rstd*gv.z + bv.z, d3*rstd*gv.w + bv.w};
  *(float4*)op = ov;
}

// ---------------------------------------------------------------------------
// Scores + top-33 (desc, ties -> lower index). One wave per (bs,h,g).
// ---------------------------------------------------------------------------
__global__ __launch_bounds__(64) void topk_k(const float* __restrict__ qS,
                                             const bf16* __restrict__ kS,
                                             int* __restrict__ idxOut)
{
  int bid = blockIdx.x;                // (bs*8+h)*10+g
  int g = bid % GG;
  int h = (bid / GG) % HH;
  int bs = bid / (GG*HH);
  int s = bs % SS;
  int lane = threadIdx.x;

  float qv[32];
  const float4* qp = (const float4*)(qS + ((size_t)(s*GG + g))*DD + h*32);
  #pragma unroll
  for (int e4 = 0; e4 < 8; ++e4) {
    float4 t = qp[e4];
    qv[e4*4+0]=t.x; qv[e4*4+1]=t.y; qv[e4*4+2]=t.z; qv[e4*4+3]=t.w;
  }

  float sc[6];
  #pragma unroll
  for (int j = 0; j < 6; ++j) {
    int v = lane + j*64;
    if (v < VV) {
      const uint4* kp = (const uint4*)(kS + ((size_t)bs*VV + v)*DD + h*32);
      float d = 0.f;
      #pragma unroll
      for (int cch = 0; cch < 4; ++cch) {
        uint4 u = kp[cch];
        const unsigned short* usp = (const unsigned short*)&u;
        #pragma unroll
        for (int e = 0; e < 8; ++e)
          d = fmaf(bfbits2f(usp[e]), qv[cch*8+e], d);
      }
      sc[j] = d * SCALE;
    } else sc[j] = -INFINITY;
  }

  for (int it = 0; it < KTOP; ++it) {
    float bv = sc[0]; int bj = 0;
    #pragma unroll
    for (int j = 1; j < 6; ++j) if (sc[j] > bv) { bv = sc[j]; bj = j; }
    int bi = lane + bj*64;
    #pragma unroll
    for (int off = 32; off; off >>= 1) {
      float ov = __shfl_down(bv, off);
      int   oi = __shfl_down(bi, off);
      if (ov > bv || (ov == bv && oi < bi)) { bv = ov; bi = oi; }
    }
    bi = __shfl(bi, 0);
    if (lane == 0) idxOut[(size_t)bid*KTOP + it] = bi;
    if ((bi & 63) == lane) {
      int jj = bi >> 6;
      #pragma unroll
      for (int j = 0; j < 6; ++j) if (jj == j) sc[j] = -INFINITY;
    }
  }
}

// ---------------------------------------------------------------------------
// Grouped conv + min/max/exp -> feat (bs,G,256) fp32
// ---------------------------------------------------------------------------
__global__ __launch_bounds__(256) void conv_k(const bf16* __restrict__ vS,
                                              const int* __restrict__ idx,
                                              const float* __restrict__ cw,
                                              const float* __restrict__ cb,
                                              float* __restrict__ feat)
{
  int bid = blockIdx.x;
  int bs = bid / GG, g = bid % GG;
  int tid = threadIdx.x;
  int h = tid >> 5, d = tid & 31;
  __shared__ float cws[KTOP];
  __shared__ int idl[HH][KTOP];
  __shared__ float ms[256];
  if (tid < KTOP) cws[tid] = cw[g*KTOP + tid];
  for (int i = tid; i < HH*KTOP; i += 256) {
    int hh = i / KTOP, k = i % KTOP;
    int ix = idx[(((size_t)bs*HH + hh)*GG + g)*KTOP + k];
    idl[hh][k] = (ix < 0) ? 0 : (ix >= VV ? VV-1 : ix);
  }
  __syncthreads();
  float acc = 0.f;
  #pragma unroll
  for (int k = 0; k < KTOP; ++k)
    acc += bf2f(vS[((size_t)bs*VV + idl[h][k])*DD + h*32 + d]) * cws[k];
  acc += cb[g];
  ms[tid] = acc;
  __syncthreads();
  float mn = acc, mx = acc;
  #pragma unroll
  for (int j = 0; j < 32; ++j) {
    float t = ms[h*32 + j];
    mn = fminf(mn, t); mx = fmaxf(mx, t);
  }
  float xn = expf((acc - mn) / fmaxf(mx - mn, 1e-6f));
  feat[((size_t)bs*GG + g)*DD + h*32 + d] = xn;
}

// ---------------------------------------------------------------------------
// Cross attention (route 2): 321 bf16 queries vs 10 fp32 keys per bs.
// Vectorized q loads (uint4) and K/V staging (float4).
// ---------------------------------------------------------------------------
__global__ __launch_bounds__(256) void attn2_k(bf16* __restrict__ Q,
                                               const float* __restrict__ KR,
                                               const float* __restrict__ VR)
{
  int bs = blockIdx.x;
  int tid = threadIdx.x;
  __shared__ float kr[GG][DD], vr[GG][DD];
  for (int i = tid; i < GG*DD/4; i += 256) {
    int r = i >> 6, c4 = (i & 63)*4;      // DD/4 = 64
    *(float4*)&kr[r][c4] = *(const float4*)&KR[((size_t)bs*GG + r)*DD + c4];
    *(float4*)&vr[r][c4] = *(const float4*)&VR[((size_t)bs*GG + r)*DD + c4];
  }
  __syncthreads();
  for (int task = tid; task < VV*HH; task += 256) {
    int v = task >> 3, h = task & 7;
    bf16* qp = Q + ((size_t)bs*VV + v)*DD + h*32;
    float qr[32];
    {
      const uint4* qp4 = (const uint4*)qp;
      #pragma unroll
      for (int cch = 0; cch < 4; ++cch) {
        uint4 u = qp4[cch];
        const unsigned short* usp = (const unsigned short*)&u;
        #pragma unroll
        for (int e = 0; e < 8; ++e) qr[cch*8+e] = bfbits2f(usp[e]);
      }
    }
    float sv[GG];
    float mx = -INFINITY;
    #pragma unroll
    for (int gi = 0; gi < GG; ++gi) {
      float dsum = 0.f;
      #pragma unroll
      for (int d = 0; d < 32; ++d) dsum += qr[d]*kr[gi][h*32+d];
      sv[gi] = dsum * SCALE;
      mx = fmaxf(mx, sv[gi]);
    }
    float ssum = 0.f;
    #pragma unroll
    for (int gi = 0; gi < GG; ++gi) { sv[gi] = expf(sv[gi]-mx); ssum += sv[gi]; }
    float inv = 1.f/ssum;
    float o[32];
    #pragma unroll
    for (int d = 0; d < 32; ++d) o[d] = 0.f;
    #pragma unroll
    for (int gi = 0; gi < GG; ++gi) {
      float p = sv[gi]*inv;
      #pragma unroll
      for (int d = 0; d < 32; ++d) o[d] += p*vr[gi][h*32+d];
    }
    #pragma unroll
    for (int c4 = 0; c4 < 8; ++c4) st4bf(qp + c4*4, &o[c4*4]);
  }
}

// ---------------------------------------------------------------------------
extern "C" void kernel_launch(void* const* d_in, const int* in_sizes, int n_in,
                              void* d_out, int out_size, void* d_ws, size_t ws_size,
                              hipStream_t stream)
{
  const float* queries=(const float*)d_in[0];
  const float* t_wq=(const float*)d_in[1];  const float* t_bq=(const float*)d_in[2];
  const float* t_wk=(const float*)d_in[3];  const float* t_bk=(const float*)d_in[4];
  const float* t_wv=(const float*)d_in[5];  const float* t_bv=(const float*)d_in[6];
  const float* t_wo=(const float*)d_in[7];  const float* t_bo=(const float*)d_in[8];
  const float* s_wq=(const float*)d_in[9];  const float* s_bq=(const float*)d_in[10];
  const float* s_wk=(const float*)d_in[11]; const float* s_bk=(const float*)d_in[12];
  const float* s_wv=(const float*)d_in[13]; const float* s_bv=(const float*)d_in[14];
  const float* s_wo=(const float*)d_in[15]; const float* s_bo=(const float*)d_in[16];
  const float* cluster=(const float*)d_in[17];
  const float* conv_w=(const float*)d_in[18]; const float* conv_b=(const float*)d_in[19];
  const float* r_wq=(const float*)d_in[20]; const float* r_bq=(const float*)d_in[21];
  const float* r_wk=(const float*)d_in[22]; const float* r_bk=(const float*)d_in[23];
  const float* r_wv=(const float*)d_in[24]; const float* r_bv=(const float*)d_in[25];
  const float* r_wo=(const float*)d_in[26]; const float* r_bo=(const float*)d_in[27];
  const float* ln_t1_g=(const float*)d_in[28]; const float* ln_t1_b=(const float*)d_in[29];
  const float* ln_t2_g=(const float*)d_in[30]; const float* ln_t2_b=(const float*)d_in[31];
  const float* ln_d1_g=(const float*)d_in[32]; const float* ln_d1_b=(const float*)d_in[33];
  const float* ln_d2_g=(const float*)d_in[34]; const float* ln_d2_b=(const float*)d_in[35];
  const float* ft_w1=(const float*)d_in[36]; const float* ft_b1=(const float*)d_in[37];
  const float* ft_w2=(const float*)d_in[38]; const float* ft_b2=(const float*)d_in[39];
  const float* fd_w1=(const float*)d_in[40]; const float* fd_b1=(const float*)d_in[41];
  const float* fd_w2=(const float*)d_in[42]; const float* fd_b2=(const float*)d_in[43];

  // Workspace: 4 big bf16 buffers (126 MB) + W^T pool (3 MB) + smalls (~10 MB)
  bf16* Ab = (bf16*)d_ws;
  bf16* Bb = Ab + NE;
  bf16* Cb = Bb + NE;
  bf16* Db = Cb + NE;                       // queries-bf16 (route1) / xl (route2)
  bf16* WP = Db + NE;                       // 1572864 bf16
  float* QSf   = (float*)(WP + 1572864);
  float* FEATf = QSf + 240*256;
  float* ROUTEf= FEATf + 1920*256;
  float* KRf   = ROUTEf + 1920*256;
  float* VRf   = KRf + 1920*256;
  int*   IDXb  = (int*)(VRf + 1920*256);

  // ---- weight prep ----
  WPrep wp;
  const float* wsrc[12] = {t_wq,t_wk,t_wv,t_wo,s_wk,s_wv,r_wq,r_wo,ft_w1,ft_w2,fd_w1,fd_w2};
  int wK[12] = {256,256,256,256,256,256,256,256,256,1024,256,1024};
  int wN[12] = {256,256,256,256,256,256,256,256,1024,256,1024,256};
  int off = 0, toff = 0;
  for (int i=0;i<12;++i) {
    wp.src[i]=wsrc[i]; wp.K[i]=wK[i]; wp.N[i]=wN[i];
    wp.dstoff[i]=off; wp.tileoff[i]=toff;
    off += wK[i]*wN[i];
    toff += (wK[i]/32)*(wN[i]/32);
  }
  wp.tileoff[12]=toff;
  prep_w_k<<<toff, 256, 0, stream>>>(wp, WP);
  bf16* Wqkv=WP+wp.dstoff[0];               // [768][256]
  bf16* Wo=WP+wp.dstoff[3];
  bf16* Wskv=WP+wp.dstoff[4];               // [512][256]
  bf16* Wrq=WP+wp.dstoff[6]; bf16* Wro=WP+wp.dstoff[7];
  bf16* Wf1=WP+wp.dstoff[8]; bf16* Wf2=WP+wp.dstoff[9];
  bf16* Wd1=WP+wp.dstoff[10]; bf16* Wd2=WP+wp.dstoff[11];

  dim3 blk(256);
  const int STRIPE = NROWS/4;               // 15408
  dim3 gQKV(6, (NROWS+127)/128);
  dim3 gKV(4, (NROWS+127)/128);
  dim3 gBig(2, (NROWS+127)/128);
  dim3 gS1(8, (STRIPE+127)/128);
  dim3 gS2(2, (STRIPE+127)/128);
  dim3 gQ(4, 4);
  dim3 gSmall(4, 30);
  const int GCVT = (int)(NE/2048);          // 7704

  // ---- Route 1: temporal ----
  f2b_k<<<GCVT, blk, 0, stream>>>(queries, Db, NE);
  mgemm_k<<<gQKV, blk, 0, stream>>>(Db, Wqkv, t_bq, t_bk, t_bv, nullptr, Ab,
                                    NROWS, 768, 256, MF_SPLIT, NE);           // Q->Ab K->Bb V->Cb (no swz: r8 showed it hurts this shape)
  attn1_k<<<(BV*HH)/4, blk, 0, stream>>>(Ab, Bb, Cb);                         // O -> Ab
  mgemm_k<<<gBig, blk, 0, stream>>>(Ab, Wo, t_bo, nullptr, nullptr, queries, Bb,
                                    NROWS, 256, 256, MF_RF32|MF_SWZ, 0);
  ln_k<<<NROWS/4, blk, 0, stream>>>(Bb, Ab, ln_t1_g, ln_t1_b, NROWS);
  for (int st = 0; st < 4; ++st) {
    size_t ro = (size_t)st * STRIPE * DD;
    mgemm_k<<<gS1, blk, 0, stream>>>(Ab + ro, Wf1, ft_b1, nullptr, nullptr, nullptr, Cb,
                                     STRIPE, 1024, 256, MF_GELU|MF_SWZ, 0);
    mgemm_k<<<gS2, blk, 0, stream>>>(Cb, Wf2, ft_b2, nullptr, nullptr, Ab + ro, Bb + ro,
                                     STRIPE, 256, 1024, MF_SWZ, 0);
  }
  ln_t_k<<<NROWS/4, blk, 0, stream>>>(Bb, Ab, Db, ln_t2_g, ln_t2_b);          // xd -> Ab, xl -> Db

  // ---- Route 2: dimensional ----
  mgemm_k<<<gKV, blk, 0, stream>>>(Db, Wskv, s_bk, s_bv, nullptr, nullptr, Bb,
                                   NROWS, 512, 256, MF_SPLIT|MF_SWZ, NE);     // kS->Bb vS->Cb
  gemm_k<<<gQ, blk, 0, stream>>>(cluster, s_wq, s_bq, nullptr, QSf, 240, 256, 256, 0);
  topk_k<<<BSEG*HH*GG, 64, 0, stream>>>(QSf, Bb, IDXb);
  conv_k<<<BSEG*GG, blk, 0, stream>>>(Cb, IDXb, conv_w, conv_b, FEATf);
  gemm_k<<<gSmall, blk, 0, stream>>>(FEATf, s_wo, s_bo, nullptr, ROUTEf, 1920, 256, 256, 0);
  gemm_k<<<gSmall, blk, 0, stream>>>(ROUTEf, r_wk, r_bk, nullptr, KRf, 1920, 256, 256, 0);
  gemm_k<<<gSmall, blk, 0, stream>>>(ROUTEf, r_wv, r_bv, nullptr, VRf, 1920, 256, 256, 0);
  mgemm_k<<<gBig, blk, 0, stream>>>(Ab, Wrq, r_bq, nullptr, nullptr, nullptr, Bb,
                                    NROWS, 256, 256, MF_SWZ, 0);              // qD -> Bb
  attn2_k<<<BSEG, blk, 0, stream>>>(Bb, KRf, VRf);                            // O -> Bb
  mgemm_k<<<gBig, blk, 0, stream>>>(Bb, Wro, r_bo, nullptr, nullptr, Ab, Cb,
                                    NROWS, 256, 256, MF_SWZ, 0);              // + xd -> Cb
  ln_k<<<NROWS/4, blk, 0, stream>>>(Cb, Ab, ln_d1_g, ln_d1_b, NROWS);
  for (int st = 0; st < 4; ++st) {
    size_t ro = (size_t)st * STRIPE * DD;
    mgemm_k<<<gS1, blk, 0, stream>>>(Ab + ro, Wd1, fd_b1, nullptr, nullptr, nullptr, Bb,
                                     STRIPE, 1024, 256, MF_GELU|MF_SWZ, 0);
    mgemm_k<<<gS2, blk, 0, stream>>>(Bb, Wd2, fd_b2, nullptr, nullptr, Ab + ro, Cb + ro,
                                     STRIPE, 256, 1024, MF_SWZ, 0);
  }
  ln_out_k<<<NROWS/4, blk, 0, stream>>>(Cb, (float*)d_out, ln_d2_g, ln_d2_b);
}

// Round 10
// 1437.484 us; speedup vs baseline: 1.2092x; 1.1810x over previous
//
#include <hip/hip_runtime.h>
#include <hip/hip_bf16.h>
#include <cmath>

typedef __hip_bfloat16 bf16;
typedef __attribute__((ext_vector_type(8))) short short8;
typedef __attribute__((ext_vector_type(4))) float f32x4;
typedef unsigned int u32;
typedef __attribute__((address_space(3))) u32 lds_u32;
typedef const __attribute__((address_space(1))) u32 glob_u32;

#define BB 8
#define VV 321
#define SS 24
#define DD 256
#define HH 8
#define GG 10
#define KTOP 33
#define DFFN 1024
#define BV (BB*VV)            // 2568
#define BSEG (BB*SS)          // 192
#define NROWS (BV*SS)         // 61632
#define NE ((size_t)NROWS*DD) // 15777792
#define SCALE 0.17677669529663687f  // 1/sqrt(32)
#define A2CH 4                // attn2 task chunks per bs

enum { GF_GELU=1, GF_LOGRELU=2, GF_ABF16=4, GF_RBF16=8, GF_CBF16=16 };
enum { MF_GELU=1, MF_RF32=8, MF_CF32=16, MF_SPLIT=32, MF_SWZ=64 };

__device__ __forceinline__ float bf2f(bf16 x){ return __bfloat162float(x); }
__device__ __forceinline__ unsigned short f2bfbits(float f){
  bf16 h = __float2bfloat16(f);
  return *(unsigned short*)&h;
}
__device__ __forceinline__ float bfbits2f(unsigned int u){
  bf16 h; *(unsigned short*)&h = (unsigned short)u; return __bfloat162float(h);
}
__device__ __forceinline__ void ld4bf(const bf16* p, float* f){
  uint2 u = *(const uint2*)p;
  f[0]=bfbits2f(u.x&0xffff); f[1]=bfbits2f(u.x>>16);
  f[2]=bfbits2f(u.y&0xffff); f[3]=bfbits2f(u.y>>16);
}
__device__ __forceinline__ void st4bf(bf16* p, const float* f){
  uint2 u;
  u.x = (unsigned)f2bfbits(f[0]) | ((unsigned)f2bfbits(f[1])<<16);
  u.y = (unsigned)f2bfbits(f[2]) | ((unsigned)f2bfbits(f[3])<<16);
  *(uint2*)p = u;
}
// async 16B global -> LDS (wave-uniform LDS base + lane*16)
__device__ __forceinline__ void gl_lds16(const void* g, void* l){
  __builtin_amdgcn_global_load_lds((glob_u32*)g, (lds_u32*)l, 16, 0, 0);
}

// ---------------------------------------------------------------------------
// Weight prep: fp32 W[K][N] -> bf16 W^T[N][K] into pool. 32x32 tiles via LDS.
// ---------------------------------------------------------------------------
struct WPrep {
  const float* src[12];
  int K[12], N[12], dstoff[12], tileoff[13];
};

__global__ __launch_bounds__(256) void prep_w_k(WPrep p, bf16* __restrict__ pool)
{
  __shared__ float t[32][33];
  int b = blockIdx.x;
  int m = 0;
  while (b >= p.tileoff[m+1]) ++m;
  int tt = b - p.tileoff[m];
  int K = p.K[m], N = p.N[m];
  int nc = N >> 5;
  int tr = tt / nc, tc = tt % nc;
  const float* src = p.src[m];
  int tid = threadIdx.x;
  int r = tid >> 3, c = (tid & 7) * 4;
  float4 v = *(const float4*)&src[(size_t)(tr*32 + r)*N + tc*32 + c];
  t[r][c+0]=v.x; t[r][c+1]=v.y; t[r][c+2]=v.z; t[r][c+3]=v.w;
  __syncthreads();
  bf16* dst = pool + p.dstoff[m];
  size_t base = (size_t)(tc*32 + r)*K + tr*32 + c;
  #pragma unroll
  for (int i=0;i<4;++i) dst[base+i] = __float2bfloat16(t[c+i][r]);
}

// ---------------------------------------------------------------------------
// fp32 -> bf16 bulk convert (8 elems/thread)
// ---------------------------------------------------------------------------
__global__ __launch_bounds__(256) void f2b_k(const float* __restrict__ X, bf16* __restrict__ Y, size_t n)
{
  size_t i = ((size_t)blockIdx.x*256 + threadIdx.x)*8;
  if (i >= n) return;
  float4 a = *(const float4*)(X+i);
  float4 b = *(const float4*)(X+i+4);
  unsigned short v[8] = {f2bfbits(a.x),f2bfbits(a.y),f2bfbits(a.z),f2bfbits(a.w),
                         f2bfbits(b.x),f2bfbits(b.y),f2bfbits(b.z),f2bfbits(b.w)};
  *(uint4*)(Y+i) = *(uint4*)v;
}

// ---------------------------------------------------------------------------
// MFMA GEMM v7: BK=32 double-buffer (round-4 proven skeleton, 32 KB LDS)
// + CONDITIONAL XCD-bijective swizzle (MF_SWZ): r4-vs-r8 A/B: swizzle hurts
// the QKV shape but helps the rest (~45us net). Flag-gated per call.
// ---------------------------------------------------------------------------
__global__ __launch_bounds__(256) void mgemm_k(
    const bf16* __restrict__ Ap, const bf16* __restrict__ Wt,
    const float* __restrict__ bias0, const float* __restrict__ bias1,
    const float* __restrict__ bias2, const void* __restrict__ Rp,
    void* __restrict__ Cp, int M, int N, int K, int flags, size_t splitStride)
{
  __shared__ __align__(16) unsigned short As[2][128*32];
  __shared__ __align__(16) unsigned short Bs[2][128*32];
  int tid = threadIdx.x;
  int wave = tid >> 6, lane = tid & 63;
  int quad = lane >> 4, l16 = lane & 15;
  int wr = wave >> 1, wc = wave & 1;

  int nwgx = gridDim.x;
  int b    = blockIdx.y * nwgx + blockIdx.x;
  int wgid = b;
  if (flags & MF_SWZ) {
    int nwg = nwgx * gridDim.y;
    int q8 = nwg >> 3, r8 = nwg & 7;
    int xcd = b & 7, slot = b >> 3;
    wgid = (xcd < r8 ? xcd*(q8+1) : r8*(q8+1) + (xcd-r8)*q8) + slot;
  }
  int m0 = (wgid / nwgx) * 128, n0 = (wgid % nwgx) * 128;

  f32x4 acc[4][4];
  #pragma unroll
  for (int i=0;i<4;++i)
    #pragma unroll
    for (int j=0;j<4;++j) acc[i][j] = (f32x4){0.f,0.f,0.f,0.f};

  // staging coords: wave w covers tile rows 32w..32w+31 (two 1KB chunks)
  int r0 = wave*32 + (lane>>2);            // chunk 0 row
  int r1 = r0 + 16;                        // chunk 1 row
  int kc = (lane&3)*8;                     // k elem offset within tile
  int gm0 = m0 + r0; if (gm0 >= M) gm0 = M-1;
  int gm1 = m0 + r1; if (gm1 >= M) gm1 = M-1;
  const bf16* gA0 = Ap + (size_t)gm0*K + kc;
  const bf16* gA1 = Ap + (size_t)gm1*K + kc;
  const bf16* gB0 = Wt + (size_t)(n0 + r0)*K + kc;
  const bf16* gB1 = Wt + (size_t)(n0 + r1)*K + kc;

  // prologue: stage tile 0 into buf 0, barrier (drains vmcnt)
  gl_lds16(gA0, &As[0][wave*1024]);
  gl_lds16(gA1, &As[0][wave*1024 + 512]);
  gl_lds16(gB0, &Bs[0][wave*1024]);
  gl_lds16(gB1, &Bs[0][wave*1024 + 512]);
  __syncthreads();

  int cur = 0;
  for (int k0 = 0; k0 < K; k0 += 32) {
    // issue next tile's loads first (overlap HBM latency with compute below)
    if (k0 + 32 < K) {
      int nxt = cur ^ 1;
      gl_lds16(gA0 + k0 + 32, &As[nxt][wave*1024]);
      gl_lds16(gA1 + k0 + 32, &As[nxt][wave*1024 + 512]);
      gl_lds16(gB0 + k0 + 32, &Bs[nxt][wave*1024]);
      gl_lds16(gB1 + k0 + 32, &Bs[nxt][wave*1024 + 512]);
    }
    short8 a[4], bb[4];
    #pragma unroll
    for (int i=0;i<4;++i)
      a[i] = *(const short8*)&As[cur][(wr*64 + i*16 + l16)*32 + quad*8];
    #pragma unroll
    for (int j=0;j<4;++j)
      bb[j] = *(const short8*)&Bs[cur][(wc*64 + j*16 + l16)*32 + quad*8];
    #pragma unroll
    for (int i=0;i<4;++i)
      #pragma unroll
      for (int j=0;j<4;++j)
        acc[i][j] = __builtin_amdgcn_mfma_f32_16x16x32_bf16(a[i], bb[j], acc[i][j], 0, 0, 0);
    __syncthreads();   // drains vmcnt (next tile landed) + all reads of buf[cur] done
    cur ^= 1;
  }

  // ---- epilogue: D[row=quad*4+r][col=l16] per 16x16 tile ----
  #pragma unroll
  for (int i=0;i<4;++i) {
    int mbase = m0 + wr*64 + i*16 + quad*4;
    #pragma unroll
    for (int j=0;j<4;++j) {
      int n = n0 + wc*64 + j*16 + l16;
      float bv;
      if (flags & MF_SPLIT) {
        int sel = n >> 8;
        const float* bp = (sel==0) ? bias0 : (sel==1 ? bias1 : bias2);
        bv = bp[n & 255];
      } else bv = bias0[n];
      #pragma unroll
      for (int r=0;r<4;++r) {
        int mm = mbase + r;
        if (mm >= M) continue;
        float v = acc[i][j][r] + bv;
        if (flags & MF_GELU) v = 0.5f*v*(1.f + erff(v*0.70710678118654752f));
        if (Rp) {
          size_t ri = (size_t)mm*N + n;
          v += (flags & MF_RF32) ? ((const float*)Rp)[ri] : bf2f(((const bf16*)Rp)[ri]);
        }
        if (flags & MF_SPLIT) {
          size_t ci = (size_t)(n>>8)*splitStride + (size_t)mm*256 + (n & 255);
          ((bf16*)Cp)[ci] = __float2bfloat16(v);
        } else {
          size_t ci = (size_t)mm*N + n;
          if (flags & MF_CF32) ((float*)Cp)[ci] = v;
          else                 ((bf16*)Cp)[ci] = __float2bfloat16(v);
        }
      }
    }
  }
}

// ---------------------------------------------------------------------------
// Old fp32 VALU GEMM — tiny route GEMMs (M<=1920), fp32 in/out.
// ---------------------------------------------------------------------------
__global__ __launch_bounds__(256) void gemm_k(
    const void* __restrict__ Ap, const float* __restrict__ W,
    const float* __restrict__ bias, const void* __restrict__ Rp,
    void* __restrict__ Cp, int M, int N, int K, int flags)
{
  __shared__ float As[16][68];
  __shared__ float Ws[16][68];
  int tid = threadIdx.x;
  int tx = tid & 15, ty = tid >> 4;
  int m0 = blockIdx.y * 64, n0 = blockIdx.x * 64;
  float acc[4][4];
  #pragma unroll
  for (int i=0;i<4;i++)
    #pragma unroll
    for (int j=0;j<4;j++) acc[i][j]=0.f;

  for (int k0 = 0; k0 < K; k0 += 16) {
    #pragma unroll
    for (int i = 0; i < 4; ++i) {
      int idx = tid + i*256;
      int r = idx >> 4, c = idx & 15;
      int gr = m0 + r;
      float v = 0.f;
      if (gr < M) {
        size_t gi = (size_t)gr*K + (size_t)(k0 + c);
        v = (flags & GF_ABF16) ? bf2f(((const bf16*)Ap)[gi]) : ((const float*)Ap)[gi];
        if (flags & GF_LOGRELU) v = log1pf(fmaxf(v, 0.f));
      }
      As[c][r] = v;
    }
    #pragma unroll
    for (int i = 0; i < 4; ++i) {
      int idx = tid + i*256;
      int c = idx >> 6, j = idx & 63;
      Ws[c][j] = W[(size_t)(k0+c)*N + (size_t)(n0 + j)];
    }
    __syncthreads();
    #pragma unroll
    for (int k = 0; k < 16; ++k) {
      float a[4], b[4];
      #pragma unroll
      for (int i=0;i<4;i++) a[i] = As[k][ty*4+i];
      #pragma unroll
      for (int j=0;j<4;j++) b[j] = Ws[k][tx*4+j];
      #pragma unroll
      for (int i=0;i<4;i++)
        #pragma unroll
        for (int j=0;j<4;j++) acc[i][j] = fmaf(a[i], b[j], acc[i][j]);
    }
    __syncthreads();
  }
  #pragma unroll
  for (int i=0;i<4;i++) {
    int row = m0 + ty*4 + i;
    if (row >= M) continue;
    #pragma unroll
    for (int j=0;j<4;j++) {
      int col = n0 + tx*4 + j;
      float v = acc[i][j] + bias[col];
      if (flags & GF_GELU) v = 0.5f*v*(1.f + erff(v*0.70710678118654752f));
      if (Rp) {
        size_t ri = (size_t)row*N + col;
        v += (flags & GF_RBF16) ? bf2f(((const bf16*)Rp)[ri]) : ((const float*)Rp)[ri];
      }
      size_t ci = (size_t)row*N + col;
      if (flags & GF_CBF16) ((bf16*)Cp)[ci] = __float2bfloat16(v);
      else                  ((float*)Cp)[ci] = v;
    }
  }
}

// ---------------------------------------------------------------------------
// Temporal attention via MFMA. 4 waves/block, wave w owns pair p=bid*4+w
// (p = bv*8 + h). S=24 padded to 32, DH=32. In-place on Q.
// ---------------------------------------------------------------------------
__global__ __launch_bounds__(256) void attn1_k(bf16* __restrict__ Q,
                                               const bf16* __restrict__ Kb,
                                               const bf16* __restrict__ Vb)
{
  __shared__ __align__(16) unsigned short lds[4*4096];  // 32 KB
  int wave = threadIdx.x >> 6, lane = threadIdx.x & 63;
  int quad = lane >> 4, l16 = lane & 15;
  int p = blockIdx.x*4 + wave;          // bv*8 + h
  int bv = p >> 3, h = p & 7;
  const size_t base0 = ((size_t)bv*SS)*DD + h*32;

  int slab = wave*4096;
  int lQ = slab, lK = slab + 1024, lV = slab + 2048, lP = slab + 3072;

  // ---- stage Q,K,V (24 rows x 32 bf16 each) via global_load_lds w16 ----
  {
    int row0 = lane >> 2, c0 = (lane & 3)*8;          // it0: u = lane
    const bf16* gq = Q  + base0 + (size_t)row0*DD + c0;
    const bf16* gk = Kb + base0 + (size_t)row0*DD + c0;
    const bf16* gv = Vb + base0 + (size_t)row0*DD + c0;
    gl_lds16(gq, &lds[lQ]);
    gl_lds16(gk, &lds[lK]);
    gl_lds16(gv, &lds[lV]);
    if (lane < 32) {                                   // it1: u = 64+lane
      int row1 = 16 + (lane >> 2);
      const bf16* gq1 = Q  + base0 + (size_t)row1*DD + c0;
      const bf16* gk1 = Kb + base0 + (size_t)row1*DD + c0;
      const bf16* gv1 = Vb + base0 + (size_t)row1*DD + c0;
      gl_lds16(gq1, &lds[lQ + 512]);
      gl_lds16(gk1, &lds[lK + 512]);
      gl_lds16(gv1, &lds[lV + 512]);
    }
  }
  // zero V pad rows 24..31 (k-dim of PV MFMA must not contain NaN garbage)
  *(uint2*)&lds[lV + 768 + lane*4] = (uint2){0u,0u};

  asm volatile("s_waitcnt vmcnt(0)" ::: "memory");
  __builtin_amdgcn_sched_barrier(0);

  // ---- QK^T: 2x2 tiles of 16, K=32 ----
  short8 qa[2], kb[2];
  #pragma unroll
  for (int t=0;t<2;++t) {
    qa[t] = *(const short8*)&lds[lQ + (t*16 + l16)*32 + quad*8];
    kb[t] = *(const short8*)&lds[lK + (t*16 + l16)*32 + quad*8];
  }
  f32x4 scc[2][2];
  #pragma unroll
  for (int ti=0;ti<2;++ti)
    #pragma unroll
    for (int tj=0;tj<2;++tj)
      scc[ti][tj] = __builtin_amdgcn_mfma_f32_16x16x32_bf16(qa[ti], kb[tj],
                      (f32x4){0.f,0.f,0.f,0.f}, 0, 0, 0);
  // mask pad cols j=24..31 (tile tj=1, l16>=8) to -inf
  if (l16 >= 8) {
    scc[0][1] = (f32x4){-INFINITY,-INFINITY,-INFINITY,-INFINITY};
    scc[1][1] = (f32x4){-INFINITY,-INFINITY,-INFINITY,-INFINITY};
  }

  // ---- softmax over cols (row = quad*4+r+16*ti, cols across l16 x tj) ----
  #pragma unroll
  for (int ti=0;ti<2;++ti) {
    #pragma unroll
    for (int r=0;r<4;++r) {
      float mv = fmaxf(scc[ti][0][r], scc[ti][1][r]);
      #pragma unroll
      for (int off=1; off<16; off<<=1) mv = fmaxf(mv, __shfl_xor(mv, off));
      float e0 = expf((scc[ti][0][r]-mv)*SCALE);
      float e1 = expf((scc[ti][1][r]-mv)*SCALE);   // exp(-inf)=0 for pad cols
      float sm = e0 + e1;
      #pragma unroll
      for (int off=1; off<16; off<<=1) sm += __shfl_xor(sm, off);
      float inv = 1.f/sm;
      int row = ti*16 + quad*4 + r;
      lds[lP + row*32 + l16]      = f2bfbits(e0*inv);
      lds[lP + row*32 + 16 + l16] = f2bfbits(e1*inv);
    }
  }

  // ---- PV: O[24x32] = P[24x32pad] x V[32x32], 2x2 tiles ----
  f32x4 o[2][2];
  #pragma unroll
  for (int ti=0;ti<2;++ti) {
    short8 pa = *(const short8*)&lds[lP + (ti*16 + l16)*32 + quad*8];
    #pragma unroll
    for (int tn=0;tn<2;++tn) {
      unsigned short vt[8];
      #pragma unroll
      for (int e=0;e<8;++e) vt[e] = lds[lV + (quad*8+e)*32 + tn*16 + l16];
      short8 vb = *(short8*)vt;
      o[ti][tn] = __builtin_amdgcn_mfma_f32_16x16x32_bf16(pa, vb,
                    (f32x4){0.f,0.f,0.f,0.f}, 0, 0, 0);
    }
  }

  // ---- store (rows < 24 only), col = tn*16+l16 ----
  #pragma unroll
  for (int ti=0;ti<2;++ti) {
    #pragma unroll
    for (int r=0;r<4;++r) {
      int row = ti*16 + quad*4 + r;
      if (row < SS) {
        #pragma unroll
        for (int tn=0;tn<2;++tn)
          Q[base0 + (size_t)row*DD + tn*16 + l16] = __float2bfloat16(o[ti][tn][r]);
      }
    }
  }
}

// ---------------------------------------------------------------------------
// LayerNorm family (G13: vectorized bf16 loads/stores, float4 g/b)
// ---------------------------------------------------------------------------
__global__ __launch_bounds__(256) void ln_k(const bf16* __restrict__ X, bf16* __restrict__ Y,
                                            const float* __restrict__ g, const float* __restrict__ b,
                                            int nrows)
{
  int row = blockIdx.x*4 + (threadIdx.x >> 6);
  int lane = threadIdx.x & 63;
  if (row >= nrows) return;
  const bf16* xr = X + (size_t)row*DD;
  int c = lane*4;
  float v[4]; ld4bf(xr + c, v);
  float s = v[0]+v[1]+v[2]+v[3];
  #pragma unroll
  for (int off = 32; off; off >>= 1) s += __shfl_xor(s, off);
  float m = s * (1.f/256.f);
  float d0=v[0]-m, d1=v[1]-m, d2=v[2]-m, d3=v[3]-m;
  float q = d0*d0+d1*d1+d2*d2+d3*d3;
  #pragma unroll
  for (int off = 32; off; off >>= 1) q += __shfl_xor(q, off);
  float rstd = rsqrtf(q*(1.f/256.f) + 1e-5f);
  float4 gv = *(const float4*)(g + c);
  float4 bv = *(const float4*)(b + c);
  float o[4] = {d0*rstd*gv.x + bv.x, d1*rstd*gv.y + bv.y,
                d2*rstd*gv.z + bv.z, d3*rstd*gv.w + bv.w};
  st4bf(Y + (size_t)row*DD + c, o);
}

// LN fused with (B,V,S,D)->(B,S,V,D) permute; also emits xl = log1p(relu(xd))
__global__ __launch_bounds__(256) void ln_t_k(const bf16* __restrict__ X, bf16* __restrict__ Y,
                                              bf16* __restrict__ Yl,
                                              const float* __restrict__ g, const float* __restrict__ b)
{
  int r1 = blockIdx.x*4 + (threadIdx.x >> 6);
  int lane = threadIdx.x & 63;
  if (r1 >= NROWS) return;
  const bf16* xr = X + (size_t)r1*DD;
  int c = lane*4;
  float v[4]; ld4bf(xr + c, v);
  float s = v[0]+v[1]+v[2]+v[3];
  #pragma unroll
  for (int off = 32; off; off >>= 1) s += __shfl_xor(s, off);
  float m = s * (1.f/256.f);
  float d0=v[0]-m, d1=v[1]-m, d2=v[2]-m, d3=v[3]-m;
  float q = d0*d0+d1*d1+d2*d2+d3*d3;
  #pragma unroll
  for (int off = 32; off; off >>= 1) q += __shfl_xor(q, off);
  float rstd = rsqrtf(q*(1.f/256.f) + 1e-5f);
  int b_ = r1 / (VV*SS);
  int rem = r1 % (VV*SS);
  int vv = rem / SS, ss = rem % SS;
  int r2 = (b_*SS + ss)*VV + vv;
  float4 gv = *(const float4*)(g + c);
  float4 bvv = *(const float4*)(b + c);
  float o[4] = {d0*rstd*gv.x + bvv.x, d1*rstd*gv.y + bvv.y,
                d2*rstd*gv.z + bvv.z, d3*rstd*gv.w + bvv.w};
  st4bf(Y + (size_t)r2*DD + c, o);
  float ol[4] = {log1pf(fmaxf(o[0],0.f)), log1pf(fmaxf(o[1],0.f)),
                 log1pf(fmaxf(o[2],0.f)), log1pf(fmaxf(o[3],0.f))};
  st4bf(Yl + (size_t)r2*DD + c, ol);
}

// Final LN + permute (B,S,V,D)->(B,V,S,D) + fp32 store
__global__ __launch_bounds__(256) void ln_out_k(const bf16* __restrict__ X, float* __restrict__ out,
                                                const float* __restrict__ g, const float* __restrict__ b)
{
  int row = blockIdx.x*4 + (threadIdx.x >> 6);
  int lane = threadIdx.x & 63;
  if (row >= NROWS) return;
  const bf16* xr = X + (size_t)row*DD;
  int c = lane*4;
  float v[4]; ld4bf(xr + c, v);
  float s = v[0]+v[1]+v[2]+v[3];
  #pragma unroll
  for (int off = 32; off; off >>= 1) s += __shfl_xor(s, off);
  float m = s * (1.f/256.f);
  float d0=v[0]-m, d1=v[1]-m, d2=v[2]-m, d3=v[3]-m;
  float q = d0*d0+d1*d1+d2*d2+d3*d3;
  #pragma unroll
  for (int off = 32; off; off >>= 1) q += __shfl_xor(q, off);
  float rstd = rsqrtf(q*(1.f/256.f) + 1e-5f);
  int bs = row / VV, vv = row % VV;
  int bb = bs / SS, ss = bs % SS;
  float* op = out + (((size_t)bb*VV + vv)*SS + ss)*DD + c;
  float4 gv = *(const float4*)(g + c);
  float4 bv = *(const float4*)(b + c);
  float4 ov = {d0*rstd*gv.x + bv.x, d1*rstd*gv.y + bv.y,
               d2*rstd*gv.z + bv.z, d3*rstd*gv.w + bv.w};
  *(float4*)op = ov;
}

// ---------------------------------------------------------------------------
// Scores + top-33 (desc, ties -> lower index). One wave per (bs,h,g).
// ---------------------------------------------------------------------------
__global__ __launch_bounds__(64) void topk_k(const float* __restrict__ qS,
                                             const bf16* __restrict__ kS,
                                             int* __restrict__ idxOut)
{
  int bid = blockIdx.x;                // (bs*8+h)*10+g
  int g = bid % GG;
  int h = (bid / GG) % HH;
  int bs = bid / (GG*HH);
  int s = bs % SS;
  int lane = threadIdx.x;

  float qv[32];
  const float4* qp = (const float4*)(qS + ((size_t)(s*GG + g))*DD + h*32);
  #pragma unroll
  for (int e4 = 0; e4 < 8; ++e4) {
    float4 t = qp[e4];
    qv[e4*4+0]=t.x; qv[e4*4+1]=t.y; qv[e4*4+2]=t.z; qv[e4*4+3]=t.w;
  }

  float sc[6];
  #pragma unroll
  for (int j = 0; j < 6; ++j) {
    int v = lane + j*64;
    if (v < VV) {
      const uint4* kp = (const uint4*)(kS + ((size_t)bs*VV + v)*DD + h*32);
      float d = 0.f;
      #pragma unroll
      for (int cch = 0; cch < 4; ++cch) {
        uint4 u = kp[cch];
        const unsigned short* usp = (const unsigned short*)&u;
        #pragma unroll
        for (int e = 0; e < 8; ++e)
          d = fmaf(bfbits2f(usp[e]), qv[cch*8+e], d);
      }
      sc[j] = d * SCALE;
    } else sc[j] = -INFINITY;
  }

  for (int it = 0; it < KTOP; ++it) {
    float bv = sc[0]; int bj = 0;
    #pragma unroll
    for (int j = 1; j < 6; ++j) if (sc[j] > bv) { bv = sc[j]; bj = j; }
    int bi = lane + bj*64;
    #pragma unroll
    for (int off = 32; off; off >>= 1) {
      float ov = __shfl_down(bv, off);
      int   oi = __shfl_down(bi, off);
      if (ov > bv || (ov == bv && oi < bi)) { bv = ov; bi = oi; }
    }
    bi = __shfl(bi, 0);
    if (lane == 0) idxOut[(size_t)bid*KTOP + it] = bi;
    if ((bi & 63) == lane) {
      int jj = bi >> 6;
      #pragma unroll
      for (int j = 0; j < 6; ++j) if (jj == j) sc[j] = -INFINITY;
    }
  }
}

// ---------------------------------------------------------------------------
// Grouped conv + min/max/exp -> feat (bs,G,256) fp32
// ---------------------------------------------------------------------------
__global__ __launch_bounds__(256) void conv_k(const bf16* __restrict__ vS,
                                              const int* __restrict__ idx,
                                              const float* __restrict__ cw,
                                              const float* __restrict__ cb,
                                              float* __restrict__ feat)
{
  int bid = blockIdx.x;
  int bs = bid / GG, g = bid % GG;
  int tid = threadIdx.x;
  int h = tid >> 5, d = tid & 31;
  __shared__ float cws[KTOP];
  __shared__ int idl[HH][KTOP];
  __shared__ float ms[256];
  if (tid < KTOP) cws[tid] = cw[g*KTOP + tid];
  for (int i = tid; i < HH*KTOP; i += 256) {
    int hh = i / KTOP, k = i % KTOP;
    int ix = idx[(((size_t)bs*HH + hh)*GG + g)*KTOP + k];
    idl[hh][k] = (ix < 0) ? 0 : (ix >= VV ? VV-1 : ix);
  }
  __syncthreads();
  float acc = 0.f;
  #pragma unroll
  for (int k = 0; k < KTOP; ++k)
    acc += bf2f(vS[((size_t)bs*VV + idl[h][k])*DD + h*32 + d]) * cws[k];
  acc += cb[g];
  ms[tid] = acc;
  __syncthreads();
  float mn = acc, mx = acc;
  #pragma unroll
  for (int j = 0; j < 32; ++j) {
    float t = ms[h*32 + j];
    mn = fminf(mn, t); mx = fmaxf(mx, t);
  }
  float xn = expf((acc - mn) / fmaxf(mx - mn, 1e-6f));
  feat[((size_t)bs*GG + g)*DD + h*32 + d] = xn;
}

// ---------------------------------------------------------------------------
// Cross attention (route 2): 321 bf16 queries vs 10 fp32 keys per bs.
// Grid = BSEG*A2CH: block (bs, chunk) handles tasks [chunk*TPC, ...) —
// 4x machine fill vs one block per bs (192 blocks underfilled 256 CUs).
// ---------------------------------------------------------------------------
__global__ __launch_bounds__(256) void attn2_k(bf16* __restrict__ Q,
                                               const float* __restrict__ KR,
                                               const float* __restrict__ VR)
{
  const int TPC = (VV*HH + A2CH - 1) / A2CH;   // 642
  int bs = blockIdx.x / A2CH;
  int chunk = blockIdx.x % A2CH;
  int tid = threadIdx.x;
  __shared__ float kr[GG][DD], vr[GG][DD];
  for (int i = tid; i < GG*DD/4; i += 256) {
    int r = i >> 6, c4 = (i & 63)*4;      // DD/4 = 64
    *(float4*)&kr[r][c4] = *(const float4*)&KR[((size_t)bs*GG + r)*DD + c4];
    *(float4*)&vr[r][c4] = *(const float4*)&VR[((size_t)bs*GG + r)*DD + c4];
  }
  __syncthreads();
  int tend = min(VV*HH, (chunk+1)*TPC);
  for (int task = chunk*TPC + tid; task < tend; task += 256) {
    int v = task >> 3, h = task & 7;
    bf16* qp = Q + ((size_t)bs*VV + v)*DD + h*32;
    float qr[32];
    {
      const uint4* qp4 = (const uint4*)qp;
      #pragma unroll
      for (int cch = 0; cch < 4; ++cch) {
        uint4 u = qp4[cch];
        const unsigned short* usp = (const unsigned short*)&u;
        #pragma unroll
        for (int e = 0; e < 8; ++e) qr[cch*8+e] = bfbits2f(usp[e]);
      }
    }
    float sv[GG];
    float mx = -INFINITY;
    #pragma unroll
    for (int gi = 0; gi < GG; ++gi) {
      float dsum = 0.f;
      #pragma unroll
      for (int d = 0; d < 32; ++d) dsum += qr[d]*kr[gi][h*32+d];
      sv[gi] = dsum * SCALE;
      mx = fmaxf(mx, sv[gi]);
    }
    float ssum = 0.f;
    #pragma unroll
    for (int gi = 0; gi < GG; ++gi) { sv[gi] = expf(sv[gi]-mx); ssum += sv[gi]; }
    float inv = 1.f/ssum;
    float o[32];
    #pragma unroll
    for (int d = 0; d < 32; ++d) o[d] = 0.f;
    #pragma unroll
    for (int gi = 0; gi < GG; ++gi) {
      float p = sv[gi]*inv;
      #pragma unroll
      for (int d = 0; d < 32; ++d) o[d] += p*vr[gi][h*32+d];
    }
    #pragma unroll
    for (int c4 = 0; c4 < 8; ++c4) st4bf(qp + c4*4, &o[c4*4]);
  }
}

// ---------------------------------------------------------------------------
extern "C" void kernel_launch(void* const* d_in, const int* in_sizes, int n_in,
                              void* d_out, int out_size, void* d_ws, size_t ws_size,
                              hipStream_t stream)
{
  const float* queries=(const float*)d_in[0];
  const float* t_wq=(const float*)d_in[1];  const float* t_bq=(const float*)d_in[2];
  const float* t_wk=(const float*)d_in[3];  const float* t_bk=(const float*)d_in[4];
  const float* t_wv=(const float*)d_in[5];  const float* t_bv=(const float*)d_in[6];
  const float* t_wo=(const float*)d_in[7];  const float* t_bo=(const float*)d_in[8];
  const float* s_wq=(const float*)d_in[9];  const float* s_bq=(const float*)d_in[10];
  const float* s_wk=(const float*)d_in[11]; const float* s_bk=(const float*)d_in[12];
  const float* s_wv=(const float*)d_in[13]; const float* s_bv=(const float*)d_in[14];
  const float* s_wo=(const float*)d_in[15]; const float* s_bo=(const float*)d_in[16];
  const float* cluster=(const float*)d_in[17];
  const float* conv_w=(const float*)d_in[18]; const float* conv_b=(const float*)d_in[19];
  const float* r_wq=(const float*)d_in[20]; const float* r_bq=(const float*)d_in[21];
  const float* r_wk=(const float*)d_in[22]; const float* r_bk=(const float*)d_in[23];
  const float* r_wv=(const float*)d_in[24]; const float* r_bv=(const float*)d_in[25];
  const float* r_wo=(const float*)d_in[26]; const float* r_bo=(const float*)d_in[27];
  const float* ln_t1_g=(const float*)d_in[28]; const float* ln_t1_b=(const float*)d_in[29];
  const float* ln_t2_g=(const float*)d_in[30]; const float* ln_t2_b=(const float*)d_in[31];
  const float* ln_d1_g=(const float*)d_in[32]; const float* ln_d1_b=(const float*)d_in[33];
  const float* ln_d2_g=(const float*)d_in[34]; const float* ln_d2_b=(const float*)d_in[35];
  const float* ft_w1=(const float*)d_in[36]; const float* ft_b1=(const float*)d_in[37];
  const float* ft_w2=(const float*)d_in[38]; const float* ft_b2=(const float*)d_in[39];
  const float* fd_w1=(const float*)d_in[40]; const float* fd_b1=(const float*)d_in[41];
  const float* fd_w2=(const float*)d_in[42]; const float* fd_b2=(const float*)d_in[43];

  // Workspace: 4 big bf16 buffers (126 MB) + W^T pool (3 MB) + smalls (~10 MB)
  bf16* Ab = (bf16*)d_ws;
  bf16* Bb = Ab + NE;
  bf16* Cb = Bb + NE;
  bf16* Db = Cb + NE;                       // queries-bf16 (route1) / xl (route2)
  bf16* WP = Db + NE;                       // 1572864 bf16
  float* QSf   = (float*)(WP + 1572864);
  float* FEATf = QSf + 240*256;
  float* ROUTEf= FEATf + 1920*256;
  float* KRf   = ROUTEf + 1920*256;
  float* VRf   = KRf + 1920*256;
  int*   IDXb  = (int*)(VRf + 1920*256);

  // ---- weight prep ----
  WPrep wp;
  const float* wsrc[12] = {t_wq,t_wk,t_wv,t_wo,s_wk,s_wv,r_wq,r_wo,ft_w1,ft_w2,fd_w1,fd_w2};
  int wK[12] = {256,256,256,256,256,256,256,256,256,1024,256,1024};
  int wN[12] = {256,256,256,256,256,256,256,256,1024,256,1024,256};
  int off = 0, toff = 0;
  for (int i=0;i<12;++i) {
    wp.src[i]=wsrc[i]; wp.K[i]=wK[i]; wp.N[i]=wN[i];
    wp.dstoff[i]=off; wp.tileoff[i]=toff;
    off += wK[i]*wN[i];
    toff += (wK[i]/32)*(wN[i]/32);
  }
  wp.tileoff[12]=toff;
  prep_w_k<<<toff, 256, 0, stream>>>(wp, WP);
  bf16* Wqkv=WP+wp.dstoff[0];               // [768][256]
  bf16* Wo=WP+wp.dstoff[3];
  bf16* Wskv=WP+wp.dstoff[4];               // [512][256]
  bf16* Wrq=WP+wp.dstoff[6]; bf16* Wro=WP+wp.dstoff[7];
  bf16* Wf1=WP+wp.dstoff[8]; bf16* Wf2=WP+wp.dstoff[9];
  bf16* Wd1=WP+wp.dstoff[10]; bf16* Wd2=WP+wp.dstoff[11];

  dim3 blk(256);
  const int STRIPE2 = NROWS/2;              // 30816 (2-way FF striping: 2x fill for FF2)
  dim3 gQKV(6, (NROWS+127)/128);
  dim3 gKV(4, (NROWS+127)/128);
  dim3 gBig(2, (NROWS+127)/128);
  dim3 gF1(8, (STRIPE2+127)/128);           // FF1: 8x241
  dim3 gF2(2, (STRIPE2+127)/128);           // FF2: 2x241 = 482 blocks (was 242)
  dim3 gQ(4, 4);
  dim3 gSmall(4, 30);
  const int GCVT = (int)(NE/2048);          // 7704

  // ---- Route 1: temporal ----
  f2b_k<<<GCVT, blk, 0, stream>>>(queries, Db, NE);
  mgemm_k<<<gQKV, blk, 0, stream>>>(Db, Wqkv, t_bq, t_bk, t_bv, nullptr, Ab,
                                    NROWS, 768, 256, MF_SPLIT, NE);           // Q->Ab K->Bb V->Cb (no swz)
  attn1_k<<<(BV*HH)/4, blk, 0, stream>>>(Ab, Bb, Cb);                         // O -> Ab
  mgemm_k<<<gBig, blk, 0, stream>>>(Ab, Wo, t_bo, nullptr, nullptr, queries, Bb,
                                    NROWS, 256, 256, MF_RF32|MF_SWZ, 0);
  ln_k<<<NROWS/4, blk, 0, stream>>>(Bb, Ab, ln_t1_g, ln_t1_b, NROWS);
  // FF: 2 stripes; FF1 scratch = Cb..Db (2xNE contiguous, both free here)
  for (int st = 0; st < 2; ++st) {
    size_t ro = (size_t)st * STRIPE2 * DD;
    mgemm_k<<<gF1, blk, 0, stream>>>(Ab + ro, Wf1, ft_b1, nullptr, nullptr, nullptr, Cb,
                                     STRIPE2, 1024, 256, MF_GELU|MF_SWZ, 0);
    mgemm_k<<<gF2, blk, 0, stream>>>(Cb, Wf2, ft_b2, nullptr, nullptr, Ab + ro, Bb + ro,
                                     STRIPE2, 256, 1024, MF_SWZ, 0);
  }
  ln_t_k<<<NROWS/4, blk, 0, stream>>>(Bb, Ab, Db, ln_t2_g, ln_t2_b);          // xd -> Ab, xl -> Db

  // ---- Route 2: dimensional ----
  mgemm_k<<<gKV, blk, 0, stream>>>(Db, Wskv, s_bk, s_bv, nullptr, nullptr, Bb,
                                   NROWS, 512, 256, MF_SPLIT|MF_SWZ, NE);     // kS->Bb vS->Cb
  gemm_k<<<gQ, blk, 0, stream>>>(cluster, s_wq, s_bq, nullptr, QSf, 240, 256, 256, 0);
  topk_k<<<BSEG*HH*GG, 64, 0, stream>>>(QSf, Bb, IDXb);
  conv_k<<<BSEG*GG, blk, 0, stream>>>(Cb, IDXb, conv_w, conv_b, FEATf);
  gemm_k<<<gSmall, blk, 0, stream>>>(FEATf, s_wo, s_bo, nullptr, ROUTEf, 1920, 256, 256, 0);
  gemm_k<<<gSmall, blk, 0, stream>>>(ROUTEf, r_wk, r_bk, nullptr, KRf, 1920, 256, 256, 0);
  gemm_k<<<gSmall, blk, 0, stream>>>(ROUTEf, r_wv, r_bv, nullptr, VRf, 1920, 256, 256, 0);
  mgemm_k<<<gBig, blk, 0, stream>>>(Ab, Wrq, r_bq, nullptr, nullptr, nullptr, Bb,
                                    NROWS, 256, 256, MF_SWZ, 0);              // qD -> Bb
  attn2_k<<<BSEG*A2CH, blk, 0, stream>>>(Bb, KRf, VRf);                       // O -> Bb (4x fill)
  mgemm_k<<<gBig, blk, 0, stream>>>(Bb, Wro, r_bo, nullptr, nullptr, Ab, Cb,
                                    NROWS, 256, 256, MF_SWZ, 0);              // + xd -> Cb
  ln_k<<<NROWS/4, blk, 0, stream>>>(Cb, Ab, ln_d1_g, ln_d1_b, NROWS);
  // FF: 2 stripes; FF1 scratch = Bb..Cb (2xNE contiguous, both free here); out -> Db
  for (int st = 0; st < 2; ++st) {
    size_t ro = (size_t)st * STRIPE2 * DD;
    mgemm_k<<<gF1, blk, 0, stream>>>(Ab + ro, Wd1, fd_b1, nullptr, nullptr, nullptr, Bb,
                                     STRIPE2, 1024, 256, MF_GELU|MF_SWZ, 0);
    mgemm_k<<<gF2, blk, 0, stream>>>(Bb, Wd2, fd_b2, nullptr, nullptr, Ab + ro, Db + ro,
                                     STRIPE2, 256, 1024, MF_SWZ, 0);
  }
  ln_out_k<<<NROWS/4, blk, 0, stream>>>(Db, (float*)d_out, ln_d2_g, ln_d2_b);
}

// Round 11
// 1279.399 us; speedup vs baseline: 1.3586x; 1.1236x over previous
//
#include <hip/hip_runtime.h>
#include <hip/hip_bf16.h>
#include <cmath>

typedef __hip_bfloat16 bf16;
typedef __attribute__((ext_vector_type(8))) short short8;
typedef __attribute__((ext_vector_type(4))) float f32x4;
typedef unsigned int u32;
typedef __attribute__((address_space(3))) u32 lds_u32;
typedef const __attribute__((address_space(1))) u32 glob_u32;

#define BB 8
#define VV 321
#define SS 24
#define DD 256
#define HH 8
#define GG 10
#define KTOP 33
#define DFFN 1024
#define BV (BB*VV)            // 2568
#define BSEG (BB*SS)          // 192
#define NROWS (BV*SS)         // 61632
#define NE ((size_t)NROWS*DD) // 15777792
#define SCALE 0.17677669529663687f  // 1/sqrt(32)
#define A2CH 4                // attn2 task chunks per bs

enum { GF_GELU=1, GF_LOGRELU=2, GF_ABF16=4, GF_RBF16=8, GF_CBF16=16 };
enum { MF_GELU=1, MF_RF32=8, MF_CF32=16, MF_SPLIT=32, MF_SWZ=64 };

__device__ __forceinline__ float bf2f(bf16 x){ return __bfloat162float(x); }
__device__ __forceinline__ unsigned short f2bfbits(float f){
  bf16 h = __float2bfloat16(f);
  return *(unsigned short*)&h;
}
__device__ __forceinline__ float bfbits2f(unsigned int u){
  bf16 h; *(unsigned short*)&h = (unsigned short)u; return __bfloat162float(h);
}
__device__ __forceinline__ void ld4bf(const bf16* p, float* f){
  uint2 u = *(const uint2*)p;
  f[0]=bfbits2f(u.x&0xffff); f[1]=bfbits2f(u.x>>16);
  f[2]=bfbits2f(u.y&0xffff); f[3]=bfbits2f(u.y>>16);
}
__device__ __forceinline__ void st4bf(bf16* p, const float* f){
  uint2 u;
  u.x = (unsigned)f2bfbits(f[0]) | ((unsigned)f2bfbits(f[1])<<16);
  u.y = (unsigned)f2bfbits(f[2]) | ((unsigned)f2bfbits(f[3])<<16);
  *(uint2*)p = u;
}
// async 16B global -> LDS (wave-uniform LDS base + lane*16)
__device__ __forceinline__ void gl_lds16(const void* g, void* l){
  __builtin_amdgcn_global_load_lds((glob_u32*)g, (lds_u32*)l, 16, 0, 0);
}

// ---------------------------------------------------------------------------
// Weight prep: fp32 W[K][N] -> bf16 W^T[N][K] into pool. 32x32 tiles via LDS.
// ---------------------------------------------------------------------------
struct WPrep {
  const float* src[12];
  int K[12], N[12], dstoff[12], tileoff[13];
};

__global__ __launch_bounds__(256) void prep_w_k(WPrep p, bf16* __restrict__ pool)
{
  __shared__ float t[32][33];
  int b = blockIdx.x;
  int m = 0;
  while (b >= p.tileoff[m+1]) ++m;
  int tt = b - p.tileoff[m];
  int K = p.K[m], N = p.N[m];
  int nc = N >> 5;
  int tr = tt / nc, tc = tt % nc;
  const float* src = p.src[m];
  int tid = threadIdx.x;
  int r = tid >> 3, c = (tid & 7) * 4;
  float4 v = *(const float4*)&src[(size_t)(tr*32 + r)*N + tc*32 + c];
  t[r][c+0]=v.x; t[r][c+1]=v.y; t[r][c+2]=v.z; t[r][c+3]=v.w;
  __syncthreads();
  bf16* dst = pool + p.dstoff[m];
  size_t base = (size_t)(tc*32 + r)*K + tr*32 + c;
  #pragma unroll
  for (int i=0;i<4;++i) dst[base+i] = __float2bfloat16(t[c+i][r]);
}

// ---------------------------------------------------------------------------
// fp32 -> bf16 bulk convert (8 elems/thread)
// ---------------------------------------------------------------------------
__global__ __launch_bounds__(256) void f2b_k(const float* __restrict__ X, bf16* __restrict__ Y, size_t n)
{
  size_t i = ((size_t)blockIdx.x*256 + threadIdx.x)*8;
  if (i >= n) return;
  float4 a = *(const float4*)(X+i);
  float4 b = *(const float4*)(X+i+4);
  unsigned short v[8] = {f2bfbits(a.x),f2bfbits(a.y),f2bfbits(a.z),f2bfbits(a.w),
                         f2bfbits(b.x),f2bfbits(b.y),f2bfbits(b.z),f2bfbits(b.w)};
  *(uint4*)(Y+i) = *(uint4*)v;
}

// ---------------------------------------------------------------------------
// MFMA GEMM v8: 256x128 tile, BK=32 double-buffer, 512 threads (8 waves 4x2).
// Same proven __syncthreads skeleton as v7; 2x MFMA per barrier pair (128 vs
// 64), staged bytes/output -25% (B reused across 2x M-rows). LDS 48 KB
// (A 2x256x32, B 2x128x32) -> 3 blocks/CU ceiling (BK=64's 64 KB -> 2 lost).
// + CONDITIONAL XCD-bijective swizzle (MF_SWZ), per-shape gated (r8 A/B).
// ---------------------------------------------------------------------------
__global__ __launch_bounds__(512) void mgemm_k(
    const bf16* __restrict__ Ap, const bf16* __restrict__ Wt,
    const float* __restrict__ bias0, const float* __restrict__ bias1,
    const float* __restrict__ bias2, const void* __restrict__ Rp,
    void* __restrict__ Cp, int M, int N, int K, int flags, size_t splitStride)
{
  __shared__ __align__(16) unsigned short As[2][256*32];   // 32 KB
  __shared__ __align__(16) unsigned short Bs[2][128*32];   // 16 KB
  int tid = threadIdx.x;
  int wave = tid >> 6, lane = tid & 63;
  int quad = lane >> 4, l16 = lane & 15;
  int wr = wave >> 1, wc = wave & 1;       // 4x2 wave grid: 64x64 out each

  int nwgx = gridDim.x;
  int b    = blockIdx.y * nwgx + blockIdx.x;
  int wgid = b;
  if (flags & MF_SWZ) {
    int nwg = nwgx * gridDim.y;
    int q8 = nwg >> 3, r8 = nwg & 7;
    int xcd = b & 7, slot = b >> 3;
    wgid = (xcd < r8 ? xcd*(q8+1) : r8*(q8+1) + (xcd-r8)*q8) + slot;
  }
  int m0 = (wgid / nwgx) * 256, n0 = (wgid % nwgx) * 128;

  f32x4 acc[4][4];
  #pragma unroll
  for (int i=0;i<4;++i)
    #pragma unroll
    for (int j=0;j<4;++j) acc[i][j] = (f32x4){0.f,0.f,0.f,0.f};

  // staging: wave w covers A rows 32w..32w+31 (2 chunks) + B rows 16w..16w+15
  int rA0 = wave*32 + (lane>>2);
  int rA1 = rA0 + 16;
  int rB  = wave*16 + (lane>>2);
  int kc = (lane&3)*8;                     // k elem offset within tile
  int gm0 = m0 + rA0; if (gm0 >= M) gm0 = M-1;
  int gm1 = m0 + rA1; if (gm1 >= M) gm1 = M-1;
  const bf16* gA0 = Ap + (size_t)gm0*K + kc;
  const bf16* gA1 = Ap + (size_t)gm1*K + kc;
  const bf16* gB  = Wt + (size_t)(n0 + rB)*K + kc;

  // prologue: stage tile 0 into buf 0, barrier (drains vmcnt)
  gl_lds16(gA0, &As[0][wave*1024]);
  gl_lds16(gA1, &As[0][wave*1024 + 512]);
  gl_lds16(gB,  &Bs[0][wave*512]);
  __syncthreads();

  int cur = 0;
  for (int k0 = 0; k0 < K; k0 += 32) {
    // issue next tile's loads first (overlap HBM latency with compute below)
    if (k0 + 32 < K) {
      int nxt = cur ^ 1;
      gl_lds16(gA0 + k0 + 32, &As[nxt][wave*1024]);
      gl_lds16(gA1 + k0 + 32, &As[nxt][wave*1024 + 512]);
      gl_lds16(gB  + k0 + 32, &Bs[nxt][wave*512]);
    }
    short8 a[4], bb[4];
    #pragma unroll
    for (int i=0;i<4;++i)
      a[i] = *(const short8*)&As[cur][(wr*64 + i*16 + l16)*32 + quad*8];
    #pragma unroll
    for (int j=0;j<4;++j)
      bb[j] = *(const short8*)&Bs[cur][(wc*64 + j*16 + l16)*32 + quad*8];
    #pragma unroll
    for (int i=0;i<4;++i)
      #pragma unroll
      for (int j=0;j<4;++j)
        acc[i][j] = __builtin_amdgcn_mfma_f32_16x16x32_bf16(a[i], bb[j], acc[i][j], 0, 0, 0);
    __syncthreads();   // drains vmcnt (next tile landed) + all reads of buf[cur] done
    cur ^= 1;
  }

  // ---- epilogue: D[row=quad*4+r][col=l16] per 16x16 tile ----
  #pragma unroll
  for (int i=0;i<4;++i) {
    int mbase = m0 + wr*64 + i*16 + quad*4;
    #pragma unroll
    for (int j=0;j<4;++j) {
      int n = n0 + wc*64 + j*16 + l16;
      float bv;
      if (flags & MF_SPLIT) {
        int sel = n >> 8;
        const float* bp = (sel==0) ? bias0 : (sel==1 ? bias1 : bias2);
        bv = bp[n & 255];
      } else bv = bias0[n];
      #pragma unroll
      for (int r=0;r<4;++r) {
        int mm = mbase + r;
        if (mm >= M) continue;
        float v = acc[i][j][r] + bv;
        if (flags & MF_GELU) v = 0.5f*v*(1.f + erff(v*0.70710678118654752f));
        if (Rp) {
          size_t ri = (size_t)mm*N + n;
          v += (flags & MF_RF32) ? ((const float*)Rp)[ri] : bf2f(((const bf16*)Rp)[ri]);
        }
        if (flags & MF_SPLIT) {
          size_t ci = (size_t)(n>>8)*splitStride + (size_t)mm*256 + (n & 255);
          ((bf16*)Cp)[ci] = __float2bfloat16(v);
        } else {
          size_t ci = (size_t)mm*N + n;
          if (flags & MF_CF32) ((float*)Cp)[ci] = v;
          else                 ((bf16*)Cp)[ci] = __float2bfloat16(v);
        }
      }
    }
  }
}

// ---------------------------------------------------------------------------
// Old fp32 VALU GEMM — tiny route GEMMs (M<=1920), fp32 in/out.
// ---------------------------------------------------------------------------
__global__ __launch_bounds__(256) void gemm_k(
    const void* __restrict__ Ap, const float* __restrict__ W,
    const float* __restrict__ bias, const void* __restrict__ Rp,
    void* __restrict__ Cp, int M, int N, int K, int flags)
{
  __shared__ float As[16][68];
  __shared__ float Ws[16][68];
  int tid = threadIdx.x;
  int tx = tid & 15, ty = tid >> 4;
  int m0 = blockIdx.y * 64, n0 = blockIdx.x * 64;
  float acc[4][4];
  #pragma unroll
  for (int i=0;i<4;i++)
    #pragma unroll
    for (int j=0;j<4;j++) acc[i][j]=0.f;

  for (int k0 = 0; k0 < K; k0 += 16) {
    #pragma unroll
    for (int i = 0; i < 4; ++i) {
      int idx = tid + i*256;
      int r = idx >> 4, c = idx & 15;
      int gr = m0 + r;
      float v = 0.f;
      if (gr < M) {
        size_t gi = (size_t)gr*K + (size_t)(k0 + c);
        v = (flags & GF_ABF16) ? bf2f(((const bf16*)Ap)[gi]) : ((const float*)Ap)[gi];
        if (flags & GF_LOGRELU) v = log1pf(fmaxf(v, 0.f));
      }
      As[c][r] = v;
    }
    #pragma unroll
    for (int i = 0; i < 4; ++i) {
      int idx = tid + i*256;
      int c = idx >> 6, j = idx & 63;
      Ws[c][j] = W[(size_t)(k0+c)*N + (size_t)(n0 + j)];
    }
    __syncthreads();
    #pragma unroll
    for (int k = 0; k < 16; ++k) {
      float a[4], b[4];
      #pragma unroll
      for (int i=0;i<4;i++) a[i] = As[k][ty*4+i];
      #pragma unroll
      for (int j=0;j<4;j++) b[j] = Ws[k][tx*4+j];
      #pragma unroll
      for (int i=0;i<4;i++)
        #pragma unroll
        for (int j=0;j<4;j++) acc[i][j] = fmaf(a[i], b[j], acc[i][j]);
    }
    __syncthreads();
  }
  #pragma unroll
  for (int i=0;i<4;i++) {
    int row = m0 + ty*4 + i;
    if (row >= M) continue;
    #pragma unroll
    for (int j=0;j<4;j++) {
      int col = n0 + tx*4 + j;
      float v = acc[i][j] + bias[col];
      if (flags & GF_GELU) v = 0.5f*v*(1.f + erff(v*0.70710678118654752f));
      if (Rp) {
        size_t ri = (size_t)row*N + col;
        v += (flags & GF_RBF16) ? bf2f(((const bf16*)Rp)[ri]) : ((const float*)Rp)[ri];
      }
      size_t ci = (size_t)row*N + col;
      if (flags & GF_CBF16) ((bf16*)Cp)[ci] = __float2bfloat16(v);
      else                  ((float*)Cp)[ci] = v;
    }
  }
}

// ---------------------------------------------------------------------------
// Temporal attention via MFMA. 4 waves/block, wave w owns pair p=bid*4+w
// (p = bv*8 + h). S=24 padded to 32, DH=32. In-place on Q.
// ---------------------------------------------------------------------------
__global__ __launch_bounds__(256) void attn1_k(bf16* __restrict__ Q,
                                               const bf16* __restrict__ Kb,
                                               const bf16* __restrict__ Vb)
{
  __shared__ __align__(16) unsigned short lds[4*4096];  // 32 KB
  int wave = threadIdx.x >> 6, lane = threadIdx.x & 63;
  int quad = lane >> 4, l16 = lane & 15;
  int p = blockIdx.x*4 + wave;          // bv*8 + h
  int bv = p >> 3, h = p & 7;
  const size_t base0 = ((size_t)bv*SS)*DD + h*32;

  int slab = wave*4096;
  int lQ = slab, lK = slab + 1024, lV = slab + 2048, lP = slab + 3072;

  // ---- stage Q,K,V (24 rows x 32 bf16 each) via global_load_lds w16 ----
  {
    int row0 = lane >> 2, c0 = (lane & 3)*8;          // it0: u = lane
    const bf16* gq = Q  + base0 + (size_t)row0*DD + c0;
    const bf16* gk = Kb + base0 + (size_t)row0*DD + c0;
    const bf16* gv = Vb + base0 + (size_t)row0*DD + c0;
    gl_lds16(gq, &lds[lQ]);
    gl_lds16(gk, &lds[lK]);
    gl_lds16(gv, &lds[lV]);
    if (lane < 32) {                                   // it1: u = 64+lane
      int row1 = 16 + (lane >> 2);
      const bf16* gq1 = Q  + base0 + (size_t)row1*DD + c0;
      const bf16* gk1 = Kb + base0 + (size_t)row1*DD + c0;
      const bf16* gv1 = Vb + base0 + (size_t)row1*DD + c0;
      gl_lds16(gq1, &lds[lQ + 512]);
      gl_lds16(gk1, &lds[lK + 512]);
      gl_lds16(gv1, &lds[lV + 512]);
    }
  }
  // zero V pad rows 24..31 (k-dim of PV MFMA must not contain NaN garbage)
  *(uint2*)&lds[lV + 768 + lane*4] = (uint2){0u,0u};

  asm volatile("s_waitcnt vmcnt(0)" ::: "memory");
  __builtin_amdgcn_sched_barrier(0);

  // ---- QK^T: 2x2 tiles of 16, K=32 ----
  short8 qa[2], kb[2];
  #pragma unroll
  for (int t=0;t<2;++t) {
    qa[t] = *(const short8*)&lds[lQ + (t*16 + l16)*32 + quad*8];
    kb[t] = *(const short8*)&lds[lK + (t*16 + l16)*32 + quad*8];
  }
  f32x4 scc[2][2];
  #pragma unroll
  for (int ti=0;ti<2;++ti)
    #pragma unroll
    for (int tj=0;tj<2;++tj)
      scc[ti][tj] = __builtin_amdgcn_mfma_f32_16x16x32_bf16(qa[ti], kb[tj],
                      (f32x4){0.f,0.f,0.f,0.f}, 0, 0, 0);
  // mask pad cols j=24..31 (tile tj=1, l16>=8) to -inf
  if (l16 >= 8) {
    scc[0][1] = (f32x4){-INFINITY,-INFINITY,-INFINITY,-INFINITY};
    scc[1][1] = (f32x4){-INFINITY,-INFINITY,-INFINITY,-INFINITY};
  }

  // ---- softmax over cols (row = quad*4+r+16*ti, cols across l16 x tj) ----
  #pragma unroll
  for (int ti=0;ti<2;++ti) {
    #pragma unroll
    for (int r=0;r<4;++r) {
      float mv = fmaxf(scc[ti][0][r], scc[ti][1][r]);
      #pragma unroll
      for (int off=1; off<16; off<<=1) mv = fmaxf(mv, __shfl_xor(mv, off));
      float e0 = expf((scc[ti][0][r]-mv)*SCALE);
      float e1 = expf((scc[ti][1][r]-mv)*SCALE);   // exp(-inf)=0 for pad cols
      float sm = e0 + e1;
      #pragma unroll
      for (int off=1; off<16; off<<=1) sm += __shfl_xor(sm, off);
      float inv = 1.f/sm;
      int row = ti*16 + quad*4 + r;
      lds[lP + row*32 + l16]      = f2bfbits(e0*inv);
      lds[lP + row*32 + 16 + l16] = f2bfbits(e1*inv);
    }
  }

  // ---- PV: O[24x32] = P[24x32pad] x V[32x32], 2x2 tiles ----
  f32x4 o[2][2];
  #pragma unroll
  for (int ti=0;ti<2;++ti) {
    short8 pa = *(const short8*)&lds[lP + (ti*16 + l16)*32 + quad*8];
    #pragma unroll
    for (int tn=0;tn<2;++tn) {
      unsigned short vt[8];
      #pragma unroll
      for (int e=0;e<8;++e) vt[e] = lds[lV + (quad*8+e)*32 + tn*16 + l16];
      short8 vb = *(short8*)vt;
      o[ti][tn] = __builtin_amdgcn_mfma_f32_16x16x32_bf16(pa, vb,
                    (f32x4){0.f,0.f,0.f,0.f}, 0, 0, 0);
    }
  }

  // ---- store (rows < 24 only), col = tn*16+l16 ----
  #pragma unroll
  for (int ti=0;ti<2;++ti) {
    #pragma unroll
    for (int r=0;r<4;++r) {
      int row = ti*16 + quad*4 + r;
      if (row < SS) {
        #pragma unroll
        for (int tn=0;tn<2;++tn)
          Q[base0 + (size_t)row*DD + tn*16 + l16] = __float2bfloat16(o[ti][tn][r]);
      }
    }
  }
}

// ---------------------------------------------------------------------------
// LayerNorm family (G13: vectorized bf16 loads/stores, float4 g/b)
// ---------------------------------------------------------------------------
__global__ __launch_bounds__(256) void ln_k(const bf16* __restrict__ X, bf16* __restrict__ Y,
                                            const float* __restrict__ g, const float* __restrict__ b,
                                            int nrows)
{
  int row = blockIdx.x*4 + (threadIdx.x >> 6);
  int lane = threadIdx.x & 63;
  if (row >= nrows) return;
  const bf16* xr = X + (size_t)row*DD;
  int c = lane*4;
  float v[4]; ld4bf(xr + c, v);
  float s = v[0]+v[1]+v[2]+v[3];
  #pragma unroll
  for (int off = 32; off; off >>= 1) s += __shfl_xor(s, off);
  float m = s * (1.f/256.f);
  float d0=v[0]-m, d1=v[1]-m, d2=v[2]-m, d3=v[3]-m;
  float q = d0*d0+d1*d1+d2*d2+d3*d3;
  #pragma unroll
  for (int off = 32; off; off >>= 1) q += __shfl_xor(q, off);
  float rstd = rsqrtf(q*(1.f/256.f) + 1e-5f);
  float4 gv = *(const float4*)(g + c);
  float4 bv = *(const float4*)(b + c);
  float o[4] = {d0*rstd*gv.x + bv.x, d1*rstd*gv.y + bv.y,
                d2*rstd*gv.z + bv.z, d3*rstd*gv.w + bv.w};
  st4bf(Y + (size_t)row*DD + c, o);
}

// LN fused with (B,V,S,D)->(B,S,V,D) permute; also emits xl = log1p(relu(xd))
__global__ __launch_bounds__(256) void ln_t_k(const bf16* __restrict__ X, bf16* __restrict__ Y,
                                              bf16* __restrict__ Yl,
                                              const float* __restrict__ g, const float* __restrict__ b)
{
  int r1 = blockIdx.x*4 + (threadIdx.x >> 6);
  int lane = threadIdx.x & 63;
  if (r1 >= NROWS) return;
  const bf16* xr = X + (size_t)r1*DD;
  int c = lane*4;
  float v[4]; ld4bf(xr + c, v);
  float s = v[0]+v[1]+v[2]+v[3];
  #pragma unroll
  for (int off = 32; off; off >>= 1) s += __shfl_xor(s, off);
  float m = s * (1.f/256.f);
  float d0=v[0]-m, d1=v[1]-m, d2=v[2]-m, d3=v[3]-m;
  float q = d0*d0+d1*d1+d2*d2+d3*d3;
  #pragma unroll
  for (int off = 32; off; off >>= 1) q += __shfl_xor(q, off);
  float rstd = rsqrtf(q*(1.f/256.f) + 1e-5f);
  int b_ = r1 / (VV*SS);
  int rem = r1 % (VV*SS);
  int vv = rem / SS, ss = rem % SS;
  int r2 = (b_*SS + ss)*VV + vv;
  float4 gv = *(const float4*)(g + c);
  float4 bvv = *(const float4*)(b + c);
  float o[4] = {d0*rstd*gv.x + bvv.x, d1*rstd*gv.y + bvv.y,
                d2*rstd*gv.z + bvv.z, d3*rstd*gv.w + bvv.w};
  st4bf(Y + (size_t)r2*DD + c, o);
  float ol[4] = {log1pf(fmaxf(o[0],0.f)), log1pf(fmaxf(o[1],0.f)),
                 log1pf(fmaxf(o[2],0.f)), log1pf(fmaxf(o[3],0.f))};
  st4bf(Yl + (size_t)r2*DD + c, ol);
}

// Final LN + permute (B,S,V,D)->(B,V,S,D) + fp32 store
__global__ __launch_bounds__(256) void ln_out_k(const bf16* __restrict__ X, float* __restrict__ out,
                                                const float* __restrict__ g, const float* __restrict__ b)
{
  int row = blockIdx.x*4 + (threadIdx.x >> 6);
  int lane = threadIdx.x & 63;
  if (row >= NROWS) return;
  const bf16* xr = X + (size_t)row*DD;
  int c = lane*4;
  float v[4]; ld4bf(xr + c, v);
  float s = v[0]+v[1]+v[2]+v[3];
  #pragma unroll
  for (int off = 32; off; off >>= 1) s += __shfl_xor(s, off);
  float m = s * (1.f/256.f);
  float d0=v[0]-m, d1=v[1]-m, d2=v[2]-m, d3=v[3]-m;
  float q = d0*d0+d1*d1+d2*d2+d3*d3;
  #pragma unroll
  for (int off = 32; off; off >>= 1) q += __shfl_xor(q, off);
  float rstd = rsqrtf(q*(1.f/256.f) + 1e-5f);
  int bs = row / VV, vv = row % VV;
  int bb = bs / SS, ss = bs % SS;
  float* op = out + (((size_t)bb*VV + vv)*SS + ss)*DD + c;
  float4 gv = *(const float4*)(g + c);
  float4 bv = *(const float4*)(b + c);
  float4 ov = {d0*rstd*gv.x + bv.x, d1*rstd*gv.y + bv.y,
               d2*rstd*gv.z + bv.z, d3*rstd*gv.w + bv.w};
  *(float4*)op = ov;
}

// ---------------------------------------------------------------------------
// Scores + top-33 (desc, ties -> lower index). One wave per (bs,h,g).
// ---------------------------------------------------------------------------
__global__ __launch_bounds__(64) void topk_k(const float* __restrict__ qS,
                                             const bf16* __restrict__ kS,
                                             int* __restrict__ idxOut)
{
  int bid = blockIdx.x;                // (bs*8+h)*10+g
  int g = bid % GG;
  int h = (bid / GG) % HH;
  int bs = bid / (GG*HH);
  int s = bs % SS;
  int lane = threadIdx.x;

  float qv[32];
  const float4* qp = (const float4*)(qS + ((size_t)(s*GG + g))*DD + h*32);
  #pragma unroll
  for (int e4 = 0; e4 < 8; ++e4) {
    float4 t = qp[e4];
    qv[e4*4+0]=t.x; qv[e4*4+1]=t.y; qv[e4*4+2]=t.z; qv[e4*4+3]=t.w;
  }

  float sc[6];
  #pragma unroll
  for (int j = 0; j < 6; ++j) {
    int v = lane + j*64;
    if (v < VV) {
      const uint4* kp = (const uint4*)(kS + ((size_t)bs*VV + v)*DD + h*32);
      float d = 0.f;
      #pragma unroll
      for (int cch = 0; cch < 4; ++cch) {
        uint4 u = kp[cch];
        const unsigned short* usp = (const unsigned short*)&u;
        #pragma unroll
        for (int e = 0; e < 8; ++e)
          d = fmaf(bfbits2f(usp[e]), qv[cch*8+e], d);
      }
      sc[j] = d * SCALE;
    } else sc[j] = -INFINITY;
  }

  for (int it = 0; it < KTOP; ++it) {
    float bv = sc[0]; int bj = 0;
    #pragma unroll
    for (int j = 1; j < 6; ++j) if (sc[j] > bv) { bv = sc[j]; bj = j; }
    int bi = lane + bj*64;
    #pragma unroll
    for (int off = 32; off; off >>= 1) {
      float ov = __shfl_down(bv, off);
      int   oi = __shfl_down(bi, off);
      if (ov > bv || (ov == bv && oi < bi)) { bv = ov; bi = oi; }
    }
    bi = __shfl(bi, 0);
    if (lane == 0) idxOut[(size_t)bid*KTOP + it] = bi;
    if ((bi & 63) == lane) {
      int jj = bi >> 6;
      #pragma unroll
      for (int j = 0; j < 6; ++j) if (jj == j) sc[j] = -INFINITY;
    }
  }
}

// ---------------------------------------------------------------------------
// Grouped conv + min/max/exp -> feat (bs,G,256) fp32
// ---------------------------------------------------------------------------
__global__ __launch_bounds__(256) void conv_k(const bf16* __restrict__ vS,
                                              const int* __restrict__ idx,
                                              const float* __restrict__ cw,
                                              const float* __restrict__ cb,
                                              float* __restrict__ feat)
{
  int bid = blockIdx.x;
  int bs = bid / GG, g = bid % GG;
  int tid = threadIdx.x;
  int h = tid >> 5, d = tid & 31;
  __shared__ float cws[KTOP];
  __shared__ int idl[HH][KTOP];
  __shared__ float ms[256];
  if (tid < KTOP) cws[tid] = cw[g*KTOP + tid];
  for (int i = tid; i < HH*KTOP; i += 256) {
    int hh = i / KTOP, k = i % KTOP;
    int ix = idx[(((size_t)bs*HH + hh)*GG + g)*KTOP + k];
    idl[hh][k] = (ix < 0) ? 0 : (ix >= VV ? VV-1 : ix);
  }
  __syncthreads();
  float acc = 0.f;
  #pragma unroll
  for (int k = 0; k < KTOP; ++k)
    acc += bf2f(vS[((size_t)bs*VV + idl[h][k])*DD + h*32 + d]) * cws[k];
  acc += cb[g];
  ms[tid] = acc;
  __syncthreads();
  float mn = acc, mx = acc;
  #pragma unroll
  for (int j = 0; j < 32; ++j) {
    float t = ms[h*32 + j];
    mn = fminf(mn, t); mx = fmaxf(mx, t);
  }
  float xn = expf((acc - mn) / fmaxf(mx - mn, 1e-6f));
  feat[((size_t)bs*GG + g)*DD + h*32 + d] = xn;
}

// ---------------------------------------------------------------------------
// Cross attention (route 2): 321 bf16 queries vs 10 fp32 keys per bs.
// Grid = BSEG*A2CH for 4x machine fill.
// ---------------------------------------------------------------------------
__global__ __launch_bounds__(256) void attn2_k(bf16* __restrict__ Q,
                                               const float* __restrict__ KR,
                                               const float* __restrict__ VR)
{
  const int TPC = (VV*HH + A2CH - 1) / A2CH;   // 642
  int bs = blockIdx.x / A2CH;
  int chunk = blockIdx.x % A2CH;
  int tid = threadIdx.x;
  __shared__ float kr[GG][DD], vr[GG][DD];
  for (int i = tid; i < GG*DD/4; i += 256) {
    int r = i >> 6, c4 = (i & 63)*4;      // DD/4 = 64
    *(float4*)&kr[r][c4] = *(const float4*)&KR[((size_t)bs*GG + r)*DD + c4];
    *(float4*)&vr[r][c4] = *(const float4*)&VR[((size_t)bs*GG + r)*DD + c4];
  }
  __syncthreads();
  int tend = min(VV*HH, (chunk+1)*TPC);
  for (int task = chunk*TPC + tid; task < tend; task += 256) {
    int v = task >> 3, h = task & 7;
    bf16* qp = Q + ((size_t)bs*VV + v)*DD + h*32;
    float qr[32];
    {
      const uint4* qp4 = (const uint4*)qp;
      #pragma unroll
      for (int cch = 0; cch < 4; ++cch) {
        uint4 u = qp4[cch];
        const unsigned short* usp = (const unsigned short*)&u;
        #pragma unroll
        for (int e = 0; e < 8; ++e) qr[cch*8+e] = bfbits2f(usp[e]);
      }
    }
    float sv[GG];
    float mx = -INFINITY;
    #pragma unroll
    for (int gi = 0; gi < GG; ++gi) {
      float dsum = 0.f;
      #pragma unroll
      for (int d = 0; d < 32; ++d) dsum += qr[d]*kr[gi][h*32+d];
      sv[gi] = dsum * SCALE;
      mx = fmaxf(mx, sv[gi]);
    }
    float ssum = 0.f;
    #pragma unroll
    for (int gi = 0; gi < GG; ++gi) { sv[gi] = expf(sv[gi]-mx); ssum += sv[gi]; }
    float inv = 1.f/ssum;
    float o[32];
    #pragma unroll
    for (int d = 0; d < 32; ++d) o[d] = 0.f;
    #pragma unroll
    for (int gi = 0; gi < GG; ++gi) {
      float p = sv[gi]*inv;
      #pragma unroll
      for (int d = 0; d < 32; ++d) o[d] += p*vr[gi][h*32+d];
    }
    #pragma unroll
    for (int c4 = 0; c4 < 8; ++c4) st4bf(qp + c4*4, &o[c4*4]);
  }
}

// ---------------------------------------------------------------------------
extern "C" void kernel_launch(void* const* d_in, const int* in_sizes, int n_in,
                              void* d_out, int out_size, void* d_ws, size_t ws_size,
                              hipStream_t stream)
{
  const float* queries=(const float*)d_in[0];
  const float* t_wq=(const float*)d_in[1];  const float* t_bq=(const float*)d_in[2];
  const float* t_wk=(const float*)d_in[3];  const float* t_bk=(const float*)d_in[4];
  const float* t_wv=(const float*)d_in[5];  const float* t_bv=(const float*)d_in[6];
  const float* t_wo=(const float*)d_in[7];  const float* t_bo=(const float*)d_in[8];
  const float* s_wq=(const float*)d_in[9];  const float* s_bq=(const float*)d_in[10];
  const float* s_wk=(const float*)d_in[11]; const float* s_bk=(const float*)d_in[12];
  const float* s_wv=(const float*)d_in[13]; const float* s_bv=(const float*)d_in[14];
  const float* s_wo=(const float*)d_in[15]; const float* s_bo=(const float*)d_in[16];
  const float* cluster=(const float*)d_in[17];
  const float* conv_w=(const float*)d_in[18]; const float* conv_b=(const float*)d_in[19];
  const float* r_wq=(const float*)d_in[20]; const float* r_bq=(const float*)d_in[21];
  const float* r_wk=(const float*)d_in[22]; const float* r_bk=(const float*)d_in[23];
  const float* r_wv=(const float*)d_in[24]; const float* r_bv=(const float*)d_in[25];
  const float* r_wo=(const float*)d_in[26]; const float* r_bo=(const float*)d_in[27];
  const float* ln_t1_g=(const float*)d_in[28]; const float* ln_t1_b=(const float*)d_in[29];
  const float* ln_t2_g=(const float*)d_in[30]; const float* ln_t2_b=(const float*)d_in[31];
  const float* ln_d1_g=(const float*)d_in[32]; const float* ln_d1_b=(const float*)d_in[33];
  const float* ln_d2_g=(const float*)d_in[34]; const float* ln_d2_b=(const float*)d_in[35];
  const float* ft_w1=(const float*)d_in[36]; const float* ft_b1=(const float*)d_in[37];
  const float* ft_w2=(const float*)d_in[38]; const float* ft_b2=(const float*)d_in[39];
  const float* fd_w1=(const float*)d_in[40]; const float* fd_b1=(const float*)d_in[41];
  const float* fd_w2=(const float*)d_in[42]; const float* fd_b2=(const float*)d_in[43];

  // Workspace: 4 big bf16 buffers (126 MB) + W^T pool (3 MB) + smalls (~10 MB)
  bf16* Ab = (bf16*)d_ws;
  bf16* Bb = Ab + NE;
  bf16* Cb = Bb + NE;
  bf16* Db = Cb + NE;                       // queries-bf16 (route1) / xl (route2)
  bf16* WP = Db + NE;                       // 1572864 bf16
  float* QSf   = (float*)(WP + 1572864);
  float* FEATf = QSf + 240*256;
  float* ROUTEf= FEATf + 1920*256;
  float* KRf   = ROUTEf + 1920*256;
  float* VRf   = KRf + 1920*256;
  int*   IDXb  = (int*)(VRf + 1920*256);

  // ---- weight prep ----
  WPrep wp;
  const float* wsrc[12] = {t_wq,t_wk,t_wv,t_wo,s_wk,s_wv,r_wq,r_wo,ft_w1,ft_w2,fd_w1,fd_w2};
  int wK[12] = {256,256,256,256,256,256,256,256,256,1024,256,1024};
  int wN[12] = {256,256,256,256,256,256,256,256,1024,256,1024,256};
  int off = 0, toff = 0;
  for (int i=0;i<12;++i) {
    wp.src[i]=wsrc[i]; wp.K[i]=wK[i]; wp.N[i]=wN[i];
    wp.dstoff[i]=off; wp.tileoff[i]=toff;
    off += wK[i]*wN[i];
    toff += (wK[i]/32)*(wN[i]/32);
  }
  wp.tileoff[12]=toff;
  prep_w_k<<<toff, 256, 0, stream>>>(wp, WP);
  bf16* Wqkv=WP+wp.dstoff[0];               // [768][256]
  bf16* Wo=WP+wp.dstoff[3];
  bf16* Wskv=WP+wp.dstoff[4];               // [512][256]
  bf16* Wrq=WP+wp.dstoff[6]; bf16* Wro=WP+wp.dstoff[7];
  bf16* Wf1=WP+wp.dstoff[8]; bf16* Wf2=WP+wp.dstoff[9];
  bf16* Wd1=WP+wp.dstoff[10]; bf16* Wd2=WP+wp.dstoff[11];

  dim3 blk(256);
  dim3 blkG(512);
  const int STRIPE2 = NROWS/2;              // 30816
  dim3 gQKV(6, (NROWS+255)/256);            // 6x241
  dim3 gKV(4, (NROWS+255)/256);
  dim3 gBig(2, (NROWS+255)/256);
  dim3 gF1(8, (STRIPE2+255)/256);           // 8x121
  dim3 gF2(2, (STRIPE2+255)/256);           // 2x121
  dim3 gQ(4, 4);
  dim3 gSmall(4, 30);
  const int GCVT = (int)(NE/2048);          // 7704

  // ---- Route 1: temporal ----
  f2b_k<<<GCVT, blk, 0, stream>>>(queries, Db, NE);
  mgemm_k<<<gQKV, blkG, 0, stream>>>(Db, Wqkv, t_bq, t_bk, t_bv, nullptr, Ab,
                                     NROWS, 768, 256, MF_SPLIT, NE);          // Q->Ab K->Bb V->Cb (no swz)
  attn1_k<<<(BV*HH)/4, blk, 0, stream>>>(Ab, Bb, Cb);                         // O -> Ab
  mgemm_k<<<gBig, blkG, 0, stream>>>(Ab, Wo, t_bo, nullptr, nullptr, queries, Bb,
                                     NROWS, 256, 256, MF_RF32|MF_SWZ, 0);
  ln_k<<<NROWS/4, blk, 0, stream>>>(Bb, Ab, ln_t1_g, ln_t1_b, NROWS);
  // FF: 2 stripes; FF1 scratch = Cb..Db (2xNE contiguous, both free here)
  for (int st = 0; st < 2; ++st) {
    size_t ro = (size_t)st * STRIPE2 * DD;
    mgemm_k<<<gF1, blkG, 0, stream>>>(Ab + ro, Wf1, ft_b1, nullptr, nullptr, nullptr, Cb,
                                      STRIPE2, 1024, 256, MF_GELU|MF_SWZ, 0);
    mgemm_k<<<gF2, blkG, 0, stream>>>(Cb, Wf2, ft_b2, nullptr, nullptr, Ab + ro, Bb + ro,
                                      STRIPE2, 256, 1024, MF_SWZ, 0);
  }
  ln_t_k<<<NROWS/4, blk, 0, stream>>>(Bb, Ab, Db, ln_t2_g, ln_t2_b);          // xd -> Ab, xl -> Db

  // ---- Route 2: dimensional ----
  mgemm_k<<<gKV, blkG, 0, stream>>>(Db, Wskv, s_bk, s_bv, nullptr, nullptr, Bb,
                                    NROWS, 512, 256, MF_SPLIT|MF_SWZ, NE);    // kS->Bb vS->Cb
  gemm_k<<<gQ, blk, 0, stream>>>(cluster, s_wq, s_bq, nullptr, QSf, 240, 256, 256, 0);
  topk_k<<<BSEG*HH*GG, 64, 0, stream>>>(QSf, Bb, IDXb);
  conv_k<<<BSEG*GG, blk, 0, stream>>>(Cb, IDXb, conv_w, conv_b, FEATf);
  gemm_k<<<gSmall, blk, 0, stream>>>(FEATf, s_wo, s_bo, nullptr, ROUTEf, 1920, 256, 256, 0);
  gemm_k<<<gSmall, blk, 0, stream>>>(ROUTEf, r_wk, r_bk, nullptr, KRf, 1920, 256, 256, 0);
  gemm_k<<<gSmall, blk, 0, stream>>>(ROUTEf, r_wv, r_bv, nullptr, VRf, 1920, 256, 256, 0);
  mgemm_k<<<gBig, blkG, 0, stream>>>(Ab, Wrq, r_bq, nullptr, nullptr, nullptr, Bb,
                                     NROWS, 256, 256, MF_SWZ, 0);             // qD -> Bb
  attn2_k<<<BSEG*A2CH, blk, 0, stream>>>(Bb, KRf, VRf);                       // O -> Bb (4x fill)
  mgemm_k<<<gBig, blkG, 0, stream>>>(Bb, Wro, r_bo, nullptr, nullptr, Ab, Cb,
                                     NROWS, 256, 256, MF_SWZ, 0);             // + xd -> Cb
  ln_k<<<NROWS/4, blk, 0, stream>>>(Cb, Ab, ln_d1_g, ln_d1_b, NROWS);
  // FF: 2 stripes; FF1 scratch = Bb..Cb (2xNE contiguous, both free here); out -> Db
  for (int st = 0; st < 2; ++st) {
    size_t ro = (size_t)st * STRIPE2 * DD;
    mgemm_k<<<gF1, blkG, 0, stream>>>(Ab + ro, Wd1, fd_b1, nullptr, nullptr, nullptr, Bb,
                                      STRIPE2, 1024, 256, MF_GELU|MF_SWZ, 0);
    mgemm_k<<<gF2, blkG, 0, stream>>>(Bb, Wd2, fd_b2, nullptr, nullptr, Ab + ro, Db + ro,
                                      STRIPE2, 256, 1024, MF_SWZ, 0);
  }
  ln_out_k<<<NROWS/4, blk, 0, stream>>>(Db, (float*)d_out, ln_d2_g, ln_d2_b);
}